// Round 3
// baseline (6495.056 us; speedup 1.0000x reference)
//
#include <hip/hip_runtime.h>
#include <hip/hip_bf16.h>

constexpr int kB   = 4;
constexpr int kCin = 256;
constexpr int kDim = 256;
constexpr int kNq  = 2048;
constexpr int kNk  = 2048;
constexpr int kK   = 16;
constexpr int kPosH= 64;
constexpr int kHid = 1024;
#define EPSF 1e-5f

// ---------------- K1: projection GEMM  Y[b,d,n] = bias[d] + sum_c W[d,c] X[b,c,n]
__global__ __launch_bounds__(256) void proj_gemm(
    const float* __restrict__ W, const float* __restrict__ bias,
    const float* __restrict__ X, float* __restrict__ Y, int Ncols)
{
    __shared__ float sW[16][64];  // [kk][i]
    __shared__ float sX[16][64];  // [kk][j]
    int b  = blockIdx.z;
    int d0 = blockIdx.y * 64;
    int n0 = blockIdx.x * 64;
    int t  = threadIdx.x;
    int ty = t >> 4, tx = t & 15;
    float acc[4][4] = {};
    for (int k0 = 0; k0 < kCin; k0 += 16) {
        {
            int i = t >> 2, ks = (t & 3) * 4;
            float4 w4 = *reinterpret_cast<const float4*>(
                W + (size_t)(d0 + i) * kCin + k0 + ks);
            sW[ks + 0][i] = w4.x; sW[ks + 1][i] = w4.y;
            sW[ks + 2][i] = w4.z; sW[ks + 3][i] = w4.w;
        }
        {
            int r = t >> 4, cs = (t & 15) * 4;
            float4 x4 = *reinterpret_cast<const float4*>(
                X + ((size_t)b * kCin + k0 + r) * Ncols + n0 + cs);
            *reinterpret_cast<float4*>(&sX[r][cs]) = x4;
        }
        __syncthreads();
        #pragma unroll
        for (int kk = 0; kk < 16; ++kk) {
            float4 av = *reinterpret_cast<const float4*>(&sW[kk][ty * 4]);
            float4 bv = *reinterpret_cast<const float4*>(&sX[kk][tx * 4]);
            float a[4] = {av.x, av.y, av.z, av.w};
            float bb[4] = {bv.x, bv.y, bv.z, bv.w};
            #pragma unroll
            for (int i = 0; i < 4; ++i)
                #pragma unroll
                for (int j = 0; j < 4; ++j)
                    acc[i][j] = fmaf(a[i], bb[j], acc[i][j]);
        }
        __syncthreads();
    }
    #pragma unroll
    for (int i = 0; i < 4; ++i) {
        int d = d0 + ty * 4 + i;
        float bb = bias[d];
        float* yp = Y + ((size_t)b * kDim + d) * Ncols + n0 + tx * 4;
        #pragma unroll
        for (int j = 0; j < 4; ++j) yp[j] = acc[i][j] + bb;
    }
}

// ---------------- K2: KNN top-16 (lexicographic (dist, idx) == lax.top_k tiebreak)
// Distances computed with explicit round-to-nearest ops (no fma contraction)
// to match the reference's unfused sequential f32 arithmetic.
__global__ __launch_bounds__(256) void knn_kernel(
    const float* __restrict__ query_pos, const float* __restrict__ key_pos,
    int* __restrict__ idx_out)
{
    __shared__ float skx[kNk], sky[kNk], skz[kNk], skk[kNk];
    int b = blockIdx.y;
    int q = blockIdx.x * 256 + threadIdx.x;
    for (int m = threadIdx.x; m < kNk; m += 256) {
        float x = key_pos[((size_t)b * 3 + 0) * kNk + m];
        float y = key_pos[((size_t)b * 3 + 1) * kNk + m];
        float z = key_pos[((size_t)b * 3 + 2) * kNk + m];
        skx[m] = x; sky[m] = y; skz[m] = z;
        skk[m] = __fadd_rn(__fadd_rn(__fmul_rn(x, x), __fmul_rn(y, y)), __fmul_rn(z, z));
    }
    __syncthreads();
    float qx = query_pos[((size_t)b * 3 + 0) * kNq + q];
    float qy = query_pos[((size_t)b * 3 + 1) * kNq + q];
    float qz = query_pos[((size_t)b * 3 + 2) * kNq + q];
    float qq = __fadd_rn(__fadd_rn(__fmul_rn(qx, qx), __fmul_rn(qy, qy)), __fmul_rn(qz, qz));
    float td[kK]; int ti[kK];
    #pragma unroll
    for (int i = 0; i < kK; ++i) { td[i] = 3.4e38f; ti[i] = 0; }
    for (int m = 0; m < kNk; ++m) {
        float dot = __fadd_rn(__fadd_rn(__fmul_rn(qx, skx[m]), __fmul_rn(qy, sky[m])),
                              __fmul_rn(qz, skz[m]));
        float d = __fsub_rn(__fadd_rn(qq, skk[m]), __fmul_rn(2.0f, dot));
        bool better = (d < td[kK - 1]) || (d == td[kK - 1] && m < ti[kK - 1]);
        if (better) {
            td[kK - 1] = d; ti[kK - 1] = m;
            #pragma unroll
            for (int s = kK - 1; s > 0; --s) {
                bool sw = (td[s] < td[s - 1]) || (td[s] == td[s - 1] && ti[s] < ti[s - 1]);
                if (sw) {
                    float tf = td[s]; td[s] = td[s - 1]; td[s - 1] = tf;
                    int tt = ti[s]; ti[s] = ti[s - 1]; ti[s - 1] = tt;
                }
            }
        }
    }
    int* op = idx_out + ((size_t)b * kNq + q) * kK;
    #pragma unroll
    for (int i = 0; i < kK; ++i) op[i] = ti[i];
}

// ---------------- K3: fused pos-MLP + attention-MLP + softmax + aggregate
__global__ __launch_bounds__(256) void fused_attn(
    const float* __restrict__ query_pos, const float* __restrict__ key_pos,
    const float* __restrict__ query, const float* __restrict__ keyf,
    const float* __restrict__ value, const int* __restrict__ idx,
    const float* __restrict__ wp1, const float* __restrict__ bp1,
    const float* __restrict__ g1, const float* __restrict__ be1,
    const float* __restrict__ m1, const float* __restrict__ v1,
    const float* __restrict__ wp2, const float* __restrict__ bp2,
    const float* __restrict__ wa1, const float* __restrict__ ba1,
    const float* __restrict__ g2, const float* __restrict__ be2,
    const float* __restrict__ m2, const float* __restrict__ v2,
    const float* __restrict__ wa2, const float* __restrict__ ba2,
    float* __restrict__ aggT)
{
    __shared__ int   s_idx[kK];
    __shared__ float s_rel[3][kK];
    __shared__ float s_pe[kPosH][kK];
    __shared__ float s_P[kDim][kK];   // pos_emb, then value_with_pos
    __shared__ float s_X[kDim][kK];   // qk_rel + pos_emb
    __shared__ float s_h[64][kK];     // hidden superchunk
    int q = blockIdx.x;
    int b = blockIdx.y;
    int tid = threadIdx.x;

    if (tid < kK) s_idx[tid] = idx[((size_t)b * kNq + q) * kK + tid];
    __syncthreads();
    if (tid < kK) {
        int m = s_idx[tid];
        #pragma unroll
        for (int c = 0; c < 3; ++c) {
            float qp = query_pos[((size_t)b * 3 + c) * kNq + q];
            float kp = key_pos[((size_t)b * 3 + c) * kNk + m];
            s_rel[c][tid] = qp - kp;
        }
    }
    __syncthreads();
    // pe = relu(bn1(wp1 . pos_rel + bp1))   (64 x 16)
    for (int t = tid; t < kPosH * kK; t += 256) {
        int h = t >> 4, k = t & 15;
        float acc = bp1[h];
        #pragma unroll
        for (int c = 0; c < 3; ++c) acc = fmaf(wp1[h * 3 + c], s_rel[c][k], acc);
        float inv = g1[h] * (1.0f / sqrtf(v1[h] + EPSF));
        float val = acc * inv + (be1[h] - m1[h] * inv);
        s_pe[h][k] = fmaxf(val, 0.0f);
    }
    __syncthreads();
    // pos_emb = wp2 . pe + bp2   (256 x 16) -> s_P
    for (int t = tid; t < kDim * kK; t += 256) {
        int c = t >> 4, k = t & 15;
        float acc = bp2[c];
        const float* wr = wp2 + (size_t)c * kPosH;
        #pragma unroll
        for (int h = 0; h < kPosH; ++h) acc = fmaf(wr[h], s_pe[h][k], acc);
        s_P[c][k] = acc;
    }
    __syncthreads();
    // x = (query - key_grouped) + pos_emb ; vwp = value_grouped + pos_emb
    for (int t = tid; t < kDim * kK; t += 256) {
        int c = t >> 4, k = t & 15;
        int m = s_idx[k];
        float pe = s_P[c][k];
        float qv = query[((size_t)b * kDim + c) * kNq + q];
        float kv = keyf[((size_t)b * kDim + c) * kNk + m];
        float vv = value[((size_t)b * kDim + c) * kNk + m];
        s_X[c][k] = (qv - kv) + pe;
        s_P[c][k] = vv + pe;
    }
    __syncthreads();

    // attention MLP: att[c,k] = ba2[c] + sum_d wa2[c,d]*relu(bn2(wa1[d,:]x[:,k]+ba1[d]))
    float att[kK];
    #pragma unroll
    for (int i = 0; i < kK; ++i) att[i] = 0.f;
    int dl = tid >> 2;   // 0..63
    int kq = tid & 3;    // 0..3 (k quad)
    const float4* X4 = reinterpret_cast<const float4*>(&s_X[0][0]);

    for (int d0 = 0; d0 < kHid; d0 += 64) {
        int d = d0 + dl;
        float inv2 = g2[d] * (1.0f / sqrtf(v2[d] + EPSF));
        float sh2  = be2[d] - m2[d] * inv2;
        float ba   = ba1[d];
        float4 acc4 = {ba, ba, ba, ba};
        const float* wr = wa1 + (size_t)d * kDim;
        for (int c2 = 0; c2 < kDim; c2 += 4) {
            float4 w4 = *reinterpret_cast<const float4*>(wr + c2);
            float wv[4] = {w4.x, w4.y, w4.z, w4.w};
            #pragma unroll
            for (int j = 0; j < 4; ++j) {
                float4 xv = X4[(c2 + j) * 4 + kq];
                acc4.x = fmaf(wv[j], xv.x, acc4.x);
                acc4.y = fmaf(wv[j], xv.y, acc4.y);
                acc4.z = fmaf(wv[j], xv.z, acc4.z);
                acc4.w = fmaf(wv[j], xv.w, acc4.w);
            }
        }
        acc4.x = fmaxf(fmaf(acc4.x, inv2, sh2), 0.f);
        acc4.y = fmaxf(fmaf(acc4.y, inv2, sh2), 0.f);
        acc4.z = fmaxf(fmaf(acc4.z, inv2, sh2), 0.f);
        acc4.w = fmaxf(fmaf(acc4.w, inv2, sh2), 0.f);
        *reinterpret_cast<float4*>(&s_h[dl][kq * 4]) = acc4;
        __syncthreads();
        // phase B: c = tid accumulates over these 64 hidden dims
        {
            const float* w2r = wa2 + (size_t)tid * kHid + d0;
            #pragma unroll
            for (int u = 0; u < 16; ++u) {
                float4 w4 = *reinterpret_cast<const float4*>(w2r + u * 4);
                float wv[4] = {w4.x, w4.y, w4.z, w4.w};
                #pragma unroll
                for (int j = 0; j < 4; ++j) {
                    const float4* h4 = reinterpret_cast<const float4*>(&s_h[u * 4 + j][0]);
                    #pragma unroll
                    for (int g = 0; g < 4; ++g) {
                        float4 hv = h4[g];
                        att[g * 4 + 0] = fmaf(wv[j], hv.x, att[g * 4 + 0]);
                        att[g * 4 + 1] = fmaf(wv[j], hv.y, att[g * 4 + 1]);
                        att[g * 4 + 2] = fmaf(wv[j], hv.z, att[g * 4 + 2]);
                        att[g * 4 + 3] = fmaf(wv[j], hv.w, att[g * 4 + 3]);
                    }
                }
            }
        }
        __syncthreads();
    }
    // softmax over k, aggregate with value_with_pos, store transposed
    {
        int c = tid;
        float bb = ba2[c];
        float mx = -3.4e38f;
        #pragma unroll
        for (int i = 0; i < kK; ++i) { att[i] += bb; mx = fmaxf(mx, att[i]); }
        float s = 0.f;
        #pragma unroll
        for (int i = 0; i < kK; ++i) { att[i] = __expf(att[i] - mx); s += att[i]; }
        float rs = 1.0f / s;
        float agg = 0.f;
        #pragma unroll
        for (int i = 0; i < kK; ++i) agg = fmaf(att[i] * rs, s_P[c][i], agg);
        aggT[((size_t)b * kNq + q) * kDim + c] = agg;
    }
}

// ---------------- K4: y = we . agg + bE + identity  -> float32 out
__global__ __launch_bounds__(256) void final_gemm(
    const float* __restrict__ we, const float* __restrict__ bE,
    const float* __restrict__ aggT, const float* __restrict__ identity,
    float* __restrict__ out)
{
    __shared__ float sA[16][64];
    __shared__ float sB[16][64];
    int b  = blockIdx.z;
    int c0 = blockIdx.y * 64;
    int n0 = blockIdx.x * 64;
    int t  = threadIdx.x;
    int ty = t >> 4, tx = t & 15;
    float acc[4][4] = {};
    for (int k0 = 0; k0 < kDim; k0 += 16) {
        {
            int i = t >> 2, ks = (t & 3) * 4;
            float4 w4 = *reinterpret_cast<const float4*>(
                we + (size_t)(c0 + i) * kDim + k0 + ks);
            sA[ks + 0][i] = w4.x; sA[ks + 1][i] = w4.y;
            sA[ks + 2][i] = w4.z; sA[ks + 3][i] = w4.w;
        }
        {
            int j = t >> 2, ks = (t & 3) * 4;
            float4 v = *reinterpret_cast<const float4*>(
                &aggT[((size_t)b * kNq + n0 + j) * kDim + k0 + ks]);
            sB[ks + 0][j] = v.x; sB[ks + 1][j] = v.y;
            sB[ks + 2][j] = v.z; sB[ks + 3][j] = v.w;
        }
        __syncthreads();
        #pragma unroll
        for (int kk = 0; kk < 16; ++kk) {
            float4 av = *reinterpret_cast<const float4*>(&sA[kk][ty * 4]);
            float4 bv = *reinterpret_cast<const float4*>(&sB[kk][tx * 4]);
            float a[4] = {av.x, av.y, av.z, av.w};
            float bb[4] = {bv.x, bv.y, bv.z, bv.w};
            #pragma unroll
            for (int i = 0; i < 4; ++i)
                #pragma unroll
                for (int j = 0; j < 4; ++j)
                    acc[i][j] = fmaf(a[i], bb[j], acc[i][j]);
        }
        __syncthreads();
    }
    #pragma unroll
    for (int i = 0; i < 4; ++i) {
        int c = c0 + ty * 4 + i;
        float bb = bE[c];
        size_t base = ((size_t)b * kCin + c) * kNq + n0 + tx * 4;
        #pragma unroll
        for (int j = 0; j < 4; ++j) {
            out[base + j] = acc[i][j] + bb + identity[base + j];
        }
    }
}

extern "C" void kernel_launch(void* const* d_in, const int* in_sizes, int n_in,
                              void* d_out, int out_size, void* d_ws, size_t ws_size,
                              hipStream_t stream) {
    const float* query_pos = (const float*)d_in[0];
    const float* query_feat= (const float*)d_in[1];
    const float* key_pos   = (const float*)d_in[2];
    const float* key_feat  = (const float*)d_in[3];
    const float* wq = (const float*)d_in[4];  const float* bq = (const float*)d_in[5];
    const float* wk = (const float*)d_in[6];  const float* bk = (const float*)d_in[7];
    const float* wv = (const float*)d_in[8];  const float* bv = (const float*)d_in[9];
    const float* wp1= (const float*)d_in[10]; const float* bp1= (const float*)d_in[11];
    const float* g1 = (const float*)d_in[12]; const float* be1= (const float*)d_in[13];
    const float* m1 = (const float*)d_in[14]; const float* v1 = (const float*)d_in[15];
    const float* wp2= (const float*)d_in[16]; const float* bp2= (const float*)d_in[17];
    const float* wa1= (const float*)d_in[18]; const float* ba1= (const float*)d_in[19];
    const float* g2 = (const float*)d_in[20]; const float* be2= (const float*)d_in[21];
    const float* m2 = (const float*)d_in[22]; const float* v2 = (const float*)d_in[23];
    const float* wa2= (const float*)d_in[24]; const float* ba2= (const float*)d_in[25];
    const float* we = (const float*)d_in[26]; const float* bE = (const float*)d_in[27];

    float* wsf    = (float*)d_ws;
    float* q_proj = wsf;
    float* k_proj = q_proj + (size_t)kB * kDim * kNq;
    float* v_proj = k_proj + (size_t)kB * kDim * kNk;
    float* aggT   = v_proj + (size_t)kB * kDim * kNk;
    int*   idx    = (int*)(aggT + (size_t)kB * kNq * kDim);

    dim3 blk(256);
    proj_gemm<<<dim3(kNq / 64, kDim / 64, kB), blk, 0, stream>>>(wq, bq, query_feat, q_proj, kNq);
    proj_gemm<<<dim3(kNk / 64, kDim / 64, kB), blk, 0, stream>>>(wk, bk, key_feat, k_proj, kNk);
    proj_gemm<<<dim3(kNk / 64, kDim / 64, kB), blk, 0, stream>>>(wv, bv, key_feat, v_proj, kNk);
    knn_kernel<<<dim3(kNq / 256, kB), blk, 0, stream>>>(query_pos, key_pos, idx);
    fused_attn<<<dim3(kNq, kB), blk, 0, stream>>>(query_pos, key_pos,
        q_proj, k_proj, v_proj, idx,
        wp1, bp1, g1, be1, m1, v1, wp2, bp2,
        wa1, ba1, g2, be2, m2, v2, wa2, ba2, aggT);
    final_gemm<<<dim3(kNq / 64, kCin / 64, kB), blk, 0, stream>>>(
        we, bE, aggT, query_feat, (float*)d_out);
}

// Round 4
// 1653.423 us; speedup vs baseline: 3.9282x; 3.9282x over previous
//
#include <hip/hip_runtime.h>
#include <hip/hip_bf16.h>

typedef __attribute__((ext_vector_type(8))) short s16x8;
typedef __attribute__((ext_vector_type(4))) float f32x4;

constexpr int kB   = 4;
constexpr int kCin = 256;
constexpr int kDim = 256;
constexpr int kNq  = 2048;
constexpr int kNk  = 2048;
constexpr int kK   = 16;
constexpr int kPosH= 64;
constexpr int kHid = 1024;
#define EPSF 1e-5f

__device__ __forceinline__ unsigned short f2bu(float f) {
    __hip_bfloat16 h = __float2bfloat16(f);
    return *reinterpret_cast<unsigned short*>(&h);
}
__device__ __forceinline__ float bu2f(unsigned short u) {
    union { unsigned int i; float f; } x; x.i = ((unsigned int)u) << 16; return x.f;
}

union U8 { s16x8 v; short s[8]; unsigned short u[8]; };

// ---------------- prep: W1' = wa1 * inv2 (bn2 folded), bf16 A-frag layout; b1' = ba1*inv2+sh2
__global__ __launch_bounds__(256) void prep_w1(
    const float* __restrict__ wa1, const float* __restrict__ ba1,
    const float* __restrict__ g2, const float* __restrict__ be2,
    const float* __restrict__ m2, const float* __restrict__ v2,
    unsigned short* __restrict__ W1s, float* __restrict__ b1p)
{
    int g = blockIdx.x * 256 + threadIdx.x;          // 32768 frag-lanes
    int mt = g >> 9, ks = (g >> 6) & 7, lane = g & 63;
    int row = mt * 16 + (lane & 15);
    int col = ks * 32 + (lane >> 4) * 8;
    float iv = g2[row] * (1.0f / sqrtf(v2[row] + EPSF));
    U8 o;
    #pragma unroll
    for (int j = 0; j < 8; ++j) o.u[j] = f2bu(wa1[row * 256 + col + j] * iv);
    *reinterpret_cast<s16x8*>(W1s + (size_t)g * 8) = o.v;
    if (ks == 0 && (lane >> 4) == 0)
        b1p[row] = ba1[row] * iv + (be2[row] - m2[row] * iv);
}

__global__ __launch_bounds__(256) void prep_w2(
    const float* __restrict__ wa2, unsigned short* __restrict__ W2s)
{
    int g = blockIdx.x * 256 + threadIdx.x;          // 32768
    int mt = g >> 11, ks = (g >> 6) & 31, lane = g & 63;
    int row = mt * 16 + (lane & 15);
    int col = ks * 32 + (lane >> 4) * 8;
    U8 o;
    #pragma unroll
    for (int j = 0; j < 8; ++j) o.u[j] = f2bu(wa2[row * 1024 + col + j]);
    *reinterpret_cast<s16x8*>(W2s + (size_t)g * 8) = o.v;
}

__global__ __launch_bounds__(256) void prep_wp2(
    const float* __restrict__ wp2, unsigned short* __restrict__ WP2s)
{
    int g = blockIdx.x * 256 + threadIdx.x;          // 2048
    int mt = g >> 7, ks = (g >> 6) & 1, lane = g & 63;
    int row = mt * 16 + (lane & 15);
    int col = ks * 32 + (lane >> 4) * 8;
    U8 o;
    #pragma unroll
    for (int j = 0; j < 8; ++j) o.u[j] = f2bu(wp2[row * 64 + col + j]);
    *reinterpret_cast<s16x8*>(WP2s + (size_t)g * 8) = o.v;
}

// ---------------- K1: projection GEMM -> bf16 transposed  YT[b][n][d]
__global__ __launch_bounds__(256) void proj_gemmT(
    const float* __restrict__ W, const float* __restrict__ bias,
    const float* __restrict__ X, unsigned short* __restrict__ YT, int Ncols)
{
    __shared__ float sW[16][64];
    __shared__ float sX[16][64];
    int b  = blockIdx.z;
    int d0 = blockIdx.y * 64;
    int n0 = blockIdx.x * 64;
    int t  = threadIdx.x;
    int ty = t >> 4, tx = t & 15;
    float acc[4][4] = {};
    for (int k0 = 0; k0 < kCin; k0 += 16) {
        {
            int i = t >> 2, ks = (t & 3) * 4;
            float4 w4 = *reinterpret_cast<const float4*>(
                W + (size_t)(d0 + i) * kCin + k0 + ks);
            sW[ks + 0][i] = w4.x; sW[ks + 1][i] = w4.y;
            sW[ks + 2][i] = w4.z; sW[ks + 3][i] = w4.w;
        }
        {
            int r = t >> 4, cs = (t & 15) * 4;
            float4 x4 = *reinterpret_cast<const float4*>(
                X + ((size_t)b * kCin + k0 + r) * Ncols + n0 + cs);
            *reinterpret_cast<float4*>(&sX[r][cs]) = x4;
        }
        __syncthreads();
        #pragma unroll
        for (int kk = 0; kk < 16; ++kk) {
            float4 av = *reinterpret_cast<const float4*>(&sW[kk][ty * 4]);
            float4 bv = *reinterpret_cast<const float4*>(&sX[kk][tx * 4]);
            float a[4] = {av.x, av.y, av.z, av.w};
            float bb[4] = {bv.x, bv.y, bv.z, bv.w};
            #pragma unroll
            for (int i = 0; i < 4; ++i)
                #pragma unroll
                for (int j = 0; j < 4; ++j)
                    acc[i][j] = fmaf(a[i], bb[j], acc[i][j]);
        }
        __syncthreads();
    }
    float bi[4];
    #pragma unroll
    for (int i = 0; i < 4; ++i) bi[i] = bias[d0 + ty * 4 + i];
    #pragma unroll
    for (int j = 0; j < 4; ++j) {
        int n = n0 + tx * 4 + j;
        ushort4 pk;
        pk.x = f2bu(acc[0][j] + bi[0]);
        pk.y = f2bu(acc[1][j] + bi[1]);
        pk.z = f2bu(acc[2][j] + bi[2]);
        pk.w = f2bu(acc[3][j] + bi[3]);
        *reinterpret_cast<ushort4*>(
            &YT[((size_t)b * Ncols + n) * 256 + d0 + ty * 4]) = pk;
    }
}

// ---------------- K2: KNN, wave-per-query. Distance math bit-identical to round-3 (passed).
__global__ __launch_bounds__(256) void knn2(
    const float* __restrict__ query_pos, const float* __restrict__ key_pos,
    int* __restrict__ idx_out)
{
    __shared__ float4 sk[kNk];
    int gq0 = blockIdx.x * 4;
    int b = gq0 >> 11;
    for (int m = threadIdx.x; m < kNk; m += 256) {
        float x = key_pos[((size_t)b * 3 + 0) * kNk + m];
        float y = key_pos[((size_t)b * 3 + 1) * kNk + m];
        float z = key_pos[((size_t)b * 3 + 2) * kNk + m];
        float kk = __fadd_rn(__fadd_rn(__fmul_rn(x, x), __fmul_rn(y, y)), __fmul_rn(z, z));
        sk[m] = make_float4(x, y, z, kk);
    }
    __syncthreads();
    int w = threadIdx.x >> 6, lane = threadIdx.x & 63;
    int gq = gq0 + w;
    int q = gq & 2047;
    float qx = query_pos[((size_t)b * 3 + 0) * kNq + q];
    float qy = query_pos[((size_t)b * 3 + 1) * kNq + q];
    float qz = query_pos[((size_t)b * 3 + 2) * kNq + q];
    float qq = __fadd_rn(__fadd_rn(__fmul_rn(qx, qx), __fmul_rn(qy, qy)), __fmul_rn(qz, qz));
    float td[kK]; int ti[kK];
    #pragma unroll
    for (int i = 0; i < kK; ++i) { td[i] = 3.4e38f; ti[i] = 0x7fffffff; }
    #pragma unroll 1
    for (int i = 0; i < 32; ++i) {
        int m = i * 64 + lane;
        float4 kv = sk[m];
        float dot = __fadd_rn(__fadd_rn(__fmul_rn(qx, kv.x), __fmul_rn(qy, kv.y)),
                              __fmul_rn(qz, kv.z));
        float d = __fsub_rn(__fadd_rn(qq, kv.w), __fmul_rn(2.0f, dot));
        bool better = (d < td[kK - 1]) || (d == td[kK - 1] && m < ti[kK - 1]);
        if (better) {
            td[kK - 1] = d; ti[kK - 1] = m;
            #pragma unroll
            for (int s = kK - 1; s > 0; --s) {
                bool sw = (td[s] < td[s - 1]) || (td[s] == td[s - 1] && ti[s] < ti[s - 1]);
                if (sw) {
                    float tf = td[s]; td[s] = td[s - 1]; td[s - 1] = tf;
                    int tt = ti[s]; ti[s] = ti[s - 1]; ti[s - 1] = tt;
                }
            }
        }
    }
    // 16-round cross-lane min-extract merge
    int outi = 0;
    #pragma unroll 1
    for (int r = 0; r < kK; ++r) {
        float dmin = td[0]; int imin = ti[0];
        #pragma unroll
        for (int msk = 1; msk < 64; msk <<= 1) {
            float od = __shfl_xor(dmin, msk);
            int   oi = __shfl_xor(imin, msk);
            if (od < dmin || (od == dmin && oi < imin)) { dmin = od; imin = oi; }
        }
        if (ti[0] == imin) {  // unique winner pops its head
            #pragma unroll
            for (int s = 0; s < kK - 1; ++s) { td[s] = td[s + 1]; ti[s] = ti[s + 1]; }
            td[kK - 1] = 3.4e38f; ti[kK - 1] = 0x7fffffff;
        }
        if (lane == r) outi = imin;
    }
    if (lane < 16) idx_out[((size_t)gq << 4) + lane] = outi;
}

// ---------------- K3: MFMA attention. One wave per query.
__global__ __launch_bounds__(256) void attn_mfma(
    const float* __restrict__ qpos, const float* __restrict__ kpos,
    const unsigned short* __restrict__ qTb, const unsigned short* __restrict__ kTb,
    const unsigned short* __restrict__ vTb, const int* __restrict__ idxb,
    const float* __restrict__ wp1, const float* __restrict__ bp1,
    const float* __restrict__ g1, const float* __restrict__ be1,
    const float* __restrict__ m1, const float* __restrict__ v1,
    const unsigned short* __restrict__ WP2s, const float* __restrict__ bp2,
    const unsigned short* __restrict__ W1s, const float* __restrict__ b1p,
    const unsigned short* __restrict__ W2s,
    float* __restrict__ aggT)
{
    __shared__ unsigned short vwpL[4][16][264];   // value+pos_emb, bf16, padded rows
    __shared__ unsigned short tileL[4][16][40];   // pos_emb staging tile (32 c at a time)
    __shared__ unsigned short hL[4][16][72];      // hidden chunk (64 h), padded rows
    const int tid = threadIdx.x;
    const int w = tid >> 6, lane = tid & 63;
    const int lo = lane & 15, hi = lane >> 4;
    const int gq = blockIdx.x * 4 + w;
    const int b = gq >> 11, q = gq & 2047;

    const int m = idxb[((size_t)gq << 4) + lo];
    // relative position for this lane's neighbor
    float rx = qpos[((size_t)b * 3 + 0) * kNq + q] - kpos[((size_t)b * 3 + 0) * kNk + m];
    float ry = qpos[((size_t)b * 3 + 1) * kNq + q] - kpos[((size_t)b * 3 + 1) * kNk + m];
    float rz = qpos[((size_t)b * 3 + 2) * kNq + q] - kpos[((size_t)b * 3 + 2) * kNk + m];

    // pe B-fragments (K=64 -> 2 ksteps); lane holds pe[h] for h = s*32+hi*8+j, n=lo
    U8 pef[2];
    #pragma unroll
    for (int s = 0; s < 2; ++s) {
        #pragma unroll
        for (int j = 0; j < 8; ++j) {
            int h = s * 32 + hi * 8 + j;
            float iv = g1[h] * (1.0f / sqrtf(v1[h] + EPSF));
            float pre = bp1[h] + wp1[h * 3 + 0] * rx + wp1[h * 3 + 1] * ry + wp1[h * 3 + 2] * rz;
            float pe = fmaxf(pre * iv + (be1[h] - m1[h] * iv), 0.0f);
            pef[s].u[j] = f2bu(pe);
        }
    }

    // X build (registers) + vwp (LDS), interleaved with pos_emb MFMA per 32-c slab
    U8 xf[8];
    const size_t qrow = (size_t)(b * kNq + q) * 256;
    const size_t krow = (size_t)(b * kNk + m) * 256;
    #pragma unroll 1
    for (int s = 0; s < 8; ++s) {
        #pragma unroll
        for (int t = 0; t < 2; ++t) {
            int mt = s * 2 + t;
            f32x4 acc = {0.f, 0.f, 0.f, 0.f};
            acc = __builtin_amdgcn_mfma_f32_16x16x32_bf16(
                *reinterpret_cast<const s16x8*>(WP2s + ((size_t)(mt * 2 + 0) * 64 + lane) * 8),
                pef[0].v, acc, 0, 0, 0);
            acc = __builtin_amdgcn_mfma_f32_16x16x32_bf16(
                *reinterpret_cast<const s16x8*>(WP2s + ((size_t)(mt * 2 + 1) * 64 + lane) * 8),
                pef[1].v, acc, 0, 0, 0);
            ushort4 pk;
            pk.x = f2bu(acc[0] + bp2[mt * 16 + hi * 4 + 0]);
            pk.y = f2bu(acc[1] + bp2[mt * 16 + hi * 4 + 1]);
            pk.z = f2bu(acc[2] + bp2[mt * 16 + hi * 4 + 2]);
            pk.w = f2bu(acc[3] + bp2[mt * 16 + hi * 4 + 3]);
            *reinterpret_cast<ushort4*>(&tileL[w][lo][t * 16 + hi * 4]) = pk;
        }
        __builtin_amdgcn_sched_barrier(0);   // writes before reads (DS is in-order per wave)
        int c0 = s * 32 + hi * 8;
        U8 pe8, q8, k8, v8, vw;
        pe8.v = *reinterpret_cast<const s16x8*>(&tileL[w][lo][hi * 8]);
        q8.v = *reinterpret_cast<const s16x8*>(qTb + qrow + c0);
        k8.v = *reinterpret_cast<const s16x8*>(kTb + krow + c0);
        v8.v = *reinterpret_cast<const s16x8*>(vTb + krow + c0);
        #pragma unroll
        for (int j = 0; j < 8; ++j) {
            float pe = bu2f(pe8.u[j]);
            xf[s].u[j] = f2bu((bu2f(q8.u[j]) - bu2f(k8.u[j])) + pe);
            vw.u[j]    = f2bu(bu2f(v8.u[j]) + pe);
        }
        *reinterpret_cast<s16x8*>(&vwpL[w][lo][c0]) = vw.v;
        __builtin_amdgcn_sched_barrier(0);   // keep next-iter writes after this read
    }

    // main MLP loop: 16 chunks of 64 hidden
    f32x4 acc2[16];
    #pragma unroll
    for (int i = 0; i < 16; ++i) acc2[i] = (f32x4){0.f, 0.f, 0.f, 0.f};
    #pragma unroll 1
    for (int cc = 0; cc < 16; ++cc) {
        __syncthreads();   // keep the 4 waves lockstep -> L1 reuse of W1/W2 fragments
        f32x4 a1[4];
        #pragma unroll
        for (int mt = 0; mt < 4; ++mt) a1[mt] = (f32x4){0.f, 0.f, 0.f, 0.f};
        #pragma unroll
        for (int mt = 0; mt < 4; ++mt) {
            const s16x8* wp = reinterpret_cast<const s16x8*>(W1s) +
                              (size_t)((cc * 4 + mt) * 8) * 64 + lane;
            #pragma unroll
            for (int s = 0; s < 8; ++s)
                a1[mt] = __builtin_amdgcn_mfma_f32_16x16x32_bf16(
                    wp[(size_t)s * 64], xf[s].v, a1[mt], 0, 0, 0);
        }
        #pragma unroll
        for (int mt = 0; mt < 4; ++mt) {
            int hb = cc * 64 + mt * 16 + hi * 4;
            ushort4 hp;
            hp.x = f2bu(fmaxf(a1[mt][0] + b1p[hb + 0], 0.f));
            hp.y = f2bu(fmaxf(a1[mt][1] + b1p[hb + 1], 0.f));
            hp.z = f2bu(fmaxf(a1[mt][2] + b1p[hb + 2], 0.f));
            hp.w = f2bu(fmaxf(a1[mt][3] + b1p[hb + 3], 0.f));
            *reinterpret_cast<ushort4*>(&hL[w][lo][mt * 16 + hi * 4]) = hp;
        }
        __builtin_amdgcn_sched_barrier(0);
        s16x8 b20 = *reinterpret_cast<const s16x8*>(&hL[w][lo][hi * 8]);
        s16x8 b21 = *reinterpret_cast<const s16x8*>(&hL[w][lo][32 + hi * 8]);
        #pragma unroll
        for (int mt2 = 0; mt2 < 16; ++mt2) {
            const s16x8* w2p = reinterpret_cast<const s16x8*>(W2s) +
                               (size_t)(mt2 * 32 + cc * 2) * 64 + lane;
            acc2[mt2] = __builtin_amdgcn_mfma_f32_16x16x32_bf16(w2p[0],  b20, acc2[mt2], 0, 0, 0);
            acc2[mt2] = __builtin_amdgcn_mfma_f32_16x16x32_bf16(w2p[64], b21, acc2[mt2], 0, 0, 0);
        }
    }

    // softmax over the 16 neighbors (lanes lo=0..15 within each hi group) + aggregation
    #pragma unroll 1
    for (int mt2 = 0; mt2 < 16; ++mt2) {
        #pragma unroll
        for (int r = 0; r < 4; ++r) {
            float a = acc2[mt2][r];
            float mx = a;
            mx = fmaxf(mx, __shfl_xor(mx, 1));
            mx = fmaxf(mx, __shfl_xor(mx, 2));
            mx = fmaxf(mx, __shfl_xor(mx, 4));
            mx = fmaxf(mx, __shfl_xor(mx, 8));
            float e = __expf(a - mx);
            float sm = e;
            sm += __shfl_xor(sm, 1); sm += __shfl_xor(sm, 2);
            sm += __shfl_xor(sm, 4); sm += __shfl_xor(sm, 8);
            int c = mt2 * 16 + hi * 4 + r;
            float vv = bu2f(vwpL[w][lo][c]);
            float p = e * vv;
            p += __shfl_xor(p, 1); p += __shfl_xor(p, 2);
            p += __shfl_xor(p, 4); p += __shfl_xor(p, 8);
            if (lo == 0) aggT[qrow + c] = p / sm;
        }
    }
}

// ---------------- K4: y = we . agg + bE + identity  (f32 out)
__global__ __launch_bounds__(256) void final_gemm(
    const float* __restrict__ we, const float* __restrict__ bE,
    const float* __restrict__ aggT, const float* __restrict__ identity,
    float* __restrict__ out)
{
    __shared__ float sA[16][64];
    __shared__ float sB[16][64];
    int b  = blockIdx.z;
    int c0 = blockIdx.y * 64;
    int n0 = blockIdx.x * 64;
    int t  = threadIdx.x;
    int ty = t >> 4, tx = t & 15;
    float acc[4][4] = {};
    for (int k0 = 0; k0 < kDim; k0 += 16) {
        {
            int i = t >> 2, ks = (t & 3) * 4;
            float4 w4 = *reinterpret_cast<const float4*>(
                we + (size_t)(c0 + i) * kDim + k0 + ks);
            sA[ks + 0][i] = w4.x; sA[ks + 1][i] = w4.y;
            sA[ks + 2][i] = w4.z; sA[ks + 3][i] = w4.w;
        }
        {
            int j = t >> 2, ks = (t & 3) * 4;
            float4 v = *reinterpret_cast<const float4*>(
                &aggT[((size_t)b * kNq + n0 + j) * kDim + k0 + ks]);
            sB[ks + 0][j] = v.x; sB[ks + 1][j] = v.y;
            sB[ks + 2][j] = v.z; sB[ks + 3][j] = v.w;
        }
        __syncthreads();
        #pragma unroll
        for (int kk = 0; kk < 16; ++kk) {
            float4 av = *reinterpret_cast<const float4*>(&sA[kk][ty * 4]);
            float4 bv = *reinterpret_cast<const float4*>(&sB[kk][tx * 4]);
            float a[4] = {av.x, av.y, av.z, av.w};
            float bb[4] = {bv.x, bv.y, bv.z, bv.w};
            #pragma unroll
            for (int i = 0; i < 4; ++i)
                #pragma unroll
                for (int j = 0; j < 4; ++j)
                    acc[i][j] = fmaf(a[i], bb[j], acc[i][j]);
        }
        __syncthreads();
    }
    #pragma unroll
    for (int i = 0; i < 4; ++i) {
        int c = c0 + ty * 4 + i;
        float bb = bE[c];
        size_t base = ((size_t)b * kCin + c) * kNq + n0 + tx * 4;
        #pragma unroll
        for (int j = 0; j < 4; ++j) {
            out[base + j] = acc[i][j] + bb + identity[base + j];
        }
    }
}

extern "C" void kernel_launch(void* const* d_in, const int* in_sizes, int n_in,
                              void* d_out, int out_size, void* d_ws, size_t ws_size,
                              hipStream_t stream) {
    const float* query_pos = (const float*)d_in[0];
    const float* query_feat= (const float*)d_in[1];
    const float* key_pos   = (const float*)d_in[2];
    const float* key_feat  = (const float*)d_in[3];
    const float* wq = (const float*)d_in[4];  const float* bq = (const float*)d_in[5];
    const float* wk = (const float*)d_in[6];  const float* bk = (const float*)d_in[7];
    const float* wv = (const float*)d_in[8];  const float* bv = (const float*)d_in[9];
    const float* wp1= (const float*)d_in[10]; const float* bp1= (const float*)d_in[11];
    const float* g1 = (const float*)d_in[12]; const float* be1= (const float*)d_in[13];
    const float* m1 = (const float*)d_in[14]; const float* v1 = (const float*)d_in[15];
    const float* wp2= (const float*)d_in[16]; const float* bp2= (const float*)d_in[17];
    const float* wa1= (const float*)d_in[18]; const float* ba1= (const float*)d_in[19];
    const float* g2 = (const float*)d_in[20]; const float* be2= (const float*)d_in[21];
    const float* m2 = (const float*)d_in[22]; const float* v2 = (const float*)d_in[23];
    const float* wa2= (const float*)d_in[24]; const float* ba2= (const float*)d_in[25];
    const float* we = (const float*)d_in[26]; const float* bE = (const float*)d_in[27];
    (void)ba2; // constant over k -> cancels in softmax

    float* wsf  = (float*)d_ws;
    float* aggT = wsf;                                   // 2M f32
    float* b1p  = aggT + 2097152;                        // 1024
    int*   idxb = (int*)(b1p + 1024);                    // 131072
    unsigned short* qTb = (unsigned short*)(idxb + 131072);  // 2M u16
    unsigned short* kTb = qTb + 2097152;
    unsigned short* vTb = kTb + 2097152;
    unsigned short* W1s = vTb + 2097152;                 // 262144 u16
    unsigned short* W2s = W1s + 262144;                  // 262144 u16
    unsigned short* WP2s= W2s + 262144;                  // 16384 u16

    dim3 blk(256);
    prep_w1<<<dim3(128), blk, 0, stream>>>(wa1, ba1, g2, be2, m2, v2, W1s, b1p);
    prep_w2<<<dim3(128), blk, 0, stream>>>(wa2, W2s);
    prep_wp2<<<dim3(8), blk, 0, stream>>>(wp2, WP2s);
    proj_gemmT<<<dim3(kNq / 64, kDim / 64, kB), blk, 0, stream>>>(wq, bq, query_feat, qTb, kNq);
    proj_gemmT<<<dim3(kNk / 64, kDim / 64, kB), blk, 0, stream>>>(wk, bk, key_feat, kTb, kNk);
    proj_gemmT<<<dim3(kNk / 64, kDim / 64, kB), blk, 0, stream>>>(wv, bv, key_feat, vTb, kNk);
    knn2<<<dim3(kB * kNq / 4), blk, 0, stream>>>(query_pos, key_pos, idxb);
    attn_mfma<<<dim3(kB * kNq / 4), blk, 0, stream>>>(query_pos, key_pos,
        qTb, kTb, vTb, idxb,
        wp1, bp1, g1, be1, m1, v1, WP2s, bp2, W1s, b1p, W2s, aggT);
    final_gemm<<<dim3(kNq / 64, kCin / 64, kB), blk, 0, stream>>>(
        we, bE, aggT, query_feat, (float*)d_out);
}

// Round 5
// 1055.782 us; speedup vs baseline: 6.1519x; 1.5661x over previous
//
#include <hip/hip_runtime.h>
#include <hip/hip_bf16.h>

typedef __attribute__((ext_vector_type(8))) short s16x8;
typedef __attribute__((ext_vector_type(4))) float f32x4;

constexpr int kB   = 4;
constexpr int kCin = 256;
constexpr int kDim = 256;
constexpr int kNq  = 2048;
constexpr int kNk  = 2048;
constexpr int kK   = 16;
constexpr int kPosH= 64;
constexpr int kHid = 1024;
#define EPSF 1e-5f

__device__ __forceinline__ unsigned short f2bu(float f) {
    __hip_bfloat16 h = __float2bfloat16(f);
    return *reinterpret_cast<unsigned short*>(&h);
}
__device__ __forceinline__ float bu2f(unsigned short u) {
    union { unsigned int i; float f; } x; x.i = ((unsigned int)u) << 16; return x.f;
}

union U8 { s16x8 v; short s[8]; unsigned short u[8]; };

// ---------------- prep: W1' = wa1 * inv2 (bn2 folded), bf16 A-frag layout; b1' = ba1*inv2+sh2
__global__ __launch_bounds__(256) void prep_w1(
    const float* __restrict__ wa1, const float* __restrict__ ba1,
    const float* __restrict__ g2, const float* __restrict__ be2,
    const float* __restrict__ m2, const float* __restrict__ v2,
    unsigned short* __restrict__ W1s, float* __restrict__ b1p)
{
    int g = blockIdx.x * 256 + threadIdx.x;          // 32768 frag-lanes
    int mt = g >> 9, ks = (g >> 6) & 7, lane = g & 63;
    int row = mt * 16 + (lane & 15);
    int col = ks * 32 + (lane >> 4) * 8;
    float iv = g2[row] * (1.0f / sqrtf(v2[row] + EPSF));
    U8 o;
    #pragma unroll
    for (int j = 0; j < 8; ++j) o.u[j] = f2bu(wa1[row * 256 + col + j] * iv);
    *reinterpret_cast<s16x8*>(W1s + (size_t)g * 8) = o.v;
    if (ks == 0 && (lane >> 4) == 0)
        b1p[row] = ba1[row] * iv + (be2[row] - m2[row] * iv);
}

__global__ __launch_bounds__(256) void prep_w2(
    const float* __restrict__ wa2, unsigned short* __restrict__ W2s)
{
    int g = blockIdx.x * 256 + threadIdx.x;          // 32768
    int mt = g >> 11, ks = (g >> 6) & 31, lane = g & 63;
    int row = mt * 16 + (lane & 15);
    int col = ks * 32 + (lane >> 4) * 8;
    U8 o;
    #pragma unroll
    for (int j = 0; j < 8; ++j) o.u[j] = f2bu(wa2[row * 1024 + col + j]);
    *reinterpret_cast<s16x8*>(W2s + (size_t)g * 8) = o.v;
}

__global__ __launch_bounds__(256) void prep_wp2(
    const float* __restrict__ wp2, unsigned short* __restrict__ WP2s)
{
    int g = blockIdx.x * 256 + threadIdx.x;          // 2048
    int mt = g >> 7, ks = (g >> 6) & 1, lane = g & 63;
    int row = mt * 16 + (lane & 15);
    int col = ks * 32 + (lane >> 4) * 8;
    U8 o;
    #pragma unroll
    for (int j = 0; j < 8; ++j) o.u[j] = f2bu(wp2[row * 64 + col + j]);
    *reinterpret_cast<s16x8*>(WP2s + (size_t)g * 8) = o.v;
}

// ---------------- K1: projection GEMM -> bf16 transposed  YT[b][n][d]
__global__ __launch_bounds__(256) void proj_gemmT(
    const float* __restrict__ W, const float* __restrict__ bias,
    const float* __restrict__ X, unsigned short* __restrict__ YT, int Ncols)
{
    __shared__ float sW[16][64];
    __shared__ float sX[16][64];
    int b  = blockIdx.z;
    int d0 = blockIdx.y * 64;
    int n0 = blockIdx.x * 64;
    int t  = threadIdx.x;
    int ty = t >> 4, tx = t & 15;
    float acc[4][4] = {};
    for (int k0 = 0; k0 < kCin; k0 += 16) {
        {
            int i = t >> 2, ks = (t & 3) * 4;
            float4 w4 = *reinterpret_cast<const float4*>(
                W + (size_t)(d0 + i) * kCin + k0 + ks);
            sW[ks + 0][i] = w4.x; sW[ks + 1][i] = w4.y;
            sW[ks + 2][i] = w4.z; sW[ks + 3][i] = w4.w;
        }
        {
            int r = t >> 4, cs = (t & 15) * 4;
            float4 x4 = *reinterpret_cast<const float4*>(
                X + ((size_t)b * kCin + k0 + r) * Ncols + n0 + cs);
            *reinterpret_cast<float4*>(&sX[r][cs]) = x4;
        }
        __syncthreads();
        #pragma unroll
        for (int kk = 0; kk < 16; ++kk) {
            float4 av = *reinterpret_cast<const float4*>(&sW[kk][ty * 4]);
            float4 bv = *reinterpret_cast<const float4*>(&sX[kk][tx * 4]);
            float a[4] = {av.x, av.y, av.z, av.w};
            float bb[4] = {bv.x, bv.y, bv.z, bv.w};
            #pragma unroll
            for (int i = 0; i < 4; ++i)
                #pragma unroll
                for (int j = 0; j < 4; ++j)
                    acc[i][j] = fmaf(a[i], bb[j], acc[i][j]);
        }
        __syncthreads();
    }
    float bi[4];
    #pragma unroll
    for (int i = 0; i < 4; ++i) bi[i] = bias[d0 + ty * 4 + i];
    #pragma unroll
    for (int j = 0; j < 4; ++j) {
        int n = n0 + tx * 4 + j;
        ushort4 pk;
        pk.x = f2bu(acc[0][j] + bi[0]);
        pk.y = f2bu(acc[1][j] + bi[1]);
        pk.z = f2bu(acc[2][j] + bi[2]);
        pk.w = f2bu(acc[3][j] + bi[3]);
        *reinterpret_cast<ushort4*>(
            &YT[((size_t)b * Ncols + n) * 256 + d0 + ty * 4]) = pk;
    }
}

// ---------------- K2: KNN, wave-per-query. Distance math bit-identical to round-3 (passed).
__global__ __launch_bounds__(256) void knn2(
    const float* __restrict__ query_pos, const float* __restrict__ key_pos,
    int* __restrict__ idx_out)
{
    __shared__ float4 sk[kNk];
    int gq0 = blockIdx.x * 4;
    int b = gq0 >> 11;
    for (int m = threadIdx.x; m < kNk; m += 256) {
        float x = key_pos[((size_t)b * 3 + 0) * kNk + m];
        float y = key_pos[((size_t)b * 3 + 1) * kNk + m];
        float z = key_pos[((size_t)b * 3 + 2) * kNk + m];
        float kk = __fadd_rn(__fadd_rn(__fmul_rn(x, x), __fmul_rn(y, y)), __fmul_rn(z, z));
        sk[m] = make_float4(x, y, z, kk);
    }
    __syncthreads();
    int w = threadIdx.x >> 6, lane = threadIdx.x & 63;
    int gq = gq0 + w;
    int q = gq & 2047;
    float qx = query_pos[((size_t)b * 3 + 0) * kNq + q];
    float qy = query_pos[((size_t)b * 3 + 1) * kNq + q];
    float qz = query_pos[((size_t)b * 3 + 2) * kNq + q];
    float qq = __fadd_rn(__fadd_rn(__fmul_rn(qx, qx), __fmul_rn(qy, qy)), __fmul_rn(qz, qz));
    float td[kK]; int ti[kK];
    #pragma unroll
    for (int i = 0; i < kK; ++i) { td[i] = 3.4e38f; ti[i] = 0x7fffffff; }
    #pragma unroll 1
    for (int i = 0; i < 32; ++i) {
        int m = i * 64 + lane;
        float4 kv = sk[m];
        float dot = __fadd_rn(__fadd_rn(__fmul_rn(qx, kv.x), __fmul_rn(qy, kv.y)),
                              __fmul_rn(qz, kv.z));
        float d = __fsub_rn(__fadd_rn(qq, kv.w), __fmul_rn(2.0f, dot));
        bool better = (d < td[kK - 1]) || (d == td[kK - 1] && m < ti[kK - 1]);
        if (better) {
            td[kK - 1] = d; ti[kK - 1] = m;
            #pragma unroll
            for (int s = kK - 1; s > 0; --s) {
                bool sw = (td[s] < td[s - 1]) || (td[s] == td[s - 1] && ti[s] < ti[s - 1]);
                if (sw) {
                    float tf = td[s]; td[s] = td[s - 1]; td[s - 1] = tf;
                    int tt = ti[s]; ti[s] = ti[s - 1]; ti[s - 1] = tt;
                }
            }
        }
    }
    // 16-round cross-lane min-extract merge
    int outi = 0;
    #pragma unroll 1
    for (int r = 0; r < kK; ++r) {
        float dmin = td[0]; int imin = ti[0];
        #pragma unroll
        for (int msk = 1; msk < 64; msk <<= 1) {
            float od = __shfl_xor(dmin, msk);
            int   oi = __shfl_xor(imin, msk);
            if (od < dmin || (od == dmin && oi < imin)) { dmin = od; imin = oi; }
        }
        if (ti[0] == imin) {  // unique winner pops its head
            #pragma unroll
            for (int s = 0; s < kK - 1; ++s) { td[s] = td[s + 1]; ti[s] = ti[s + 1]; }
            td[kK - 1] = 3.4e38f; ti[kK - 1] = 0x7fffffff;
        }
        if (lane == r) outi = imin;
    }
    if (lane < 16) idx_out[((size_t)gq << 4) + lane] = outi;
}

// ---------------- K3: MFMA attention. One wave per query.
__global__ __launch_bounds__(256) void attn_mfma(
    const float* __restrict__ qpos, const float* __restrict__ kpos,
    const unsigned short* __restrict__ qTb, const unsigned short* __restrict__ kTb,
    const unsigned short* __restrict__ vTb, const int* __restrict__ idxb,
    const float* __restrict__ wp1, const float* __restrict__ bp1,
    const float* __restrict__ g1, const float* __restrict__ be1,
    const float* __restrict__ m1, const float* __restrict__ v1,
    const unsigned short* __restrict__ WP2s, const float* __restrict__ bp2,
    const unsigned short* __restrict__ W1s, const float* __restrict__ b1p,
    const unsigned short* __restrict__ W2s,
    float* __restrict__ aggT)
{
    __shared__ unsigned short vwpL[4][16][264];   // value+pos_emb, bf16, padded rows
    __shared__ unsigned short tileL[4][16][40];   // pos_emb staging tile (32 c at a time)
    __shared__ unsigned short hL[4][16][72];      // hidden chunk (64 h), padded rows
    const int tid = threadIdx.x;
    const int w = tid >> 6, lane = tid & 63;
    const int lo = lane & 15, hi = lane >> 4;
    const int gq = blockIdx.x * 4 + w;
    const int b = gq >> 11, q = gq & 2047;

    const int m = idxb[((size_t)gq << 4) + lo];
    // relative position for this lane's neighbor
    float rx = qpos[((size_t)b * 3 + 0) * kNq + q] - kpos[((size_t)b * 3 + 0) * kNk + m];
    float ry = qpos[((size_t)b * 3 + 1) * kNq + q] - kpos[((size_t)b * 3 + 1) * kNk + m];
    float rz = qpos[((size_t)b * 3 + 2) * kNq + q] - kpos[((size_t)b * 3 + 2) * kNk + m];

    // pe B-fragments (K=64 -> 2 ksteps); lane holds pe[h] for h = s*32+hi*8+j, n=lo
    U8 pef[2];
    #pragma unroll
    for (int s = 0; s < 2; ++s) {
        #pragma unroll
        for (int j = 0; j < 8; ++j) {
            int h = s * 32 + hi * 8 + j;
            float iv = g1[h] * (1.0f / sqrtf(v1[h] + EPSF));
            float pre = bp1[h] + wp1[h * 3 + 0] * rx + wp1[h * 3 + 1] * ry + wp1[h * 3 + 2] * rz;
            float pe = fmaxf(pre * iv + (be1[h] - m1[h] * iv), 0.0f);
            pef[s].u[j] = f2bu(pe);
        }
    }

    // X build (registers) + vwp (LDS), interleaved with pos_emb MFMA per 32-c slab.
    // FULLY UNROLLED so xf[] indices are compile-time -> registers, not scratch.
    U8 xf[8];
    const size_t qrow = (size_t)(b * kNq + q) * 256;
    const size_t krow = (size_t)(b * kNk + m) * 256;
    #pragma unroll
    for (int s = 0; s < 8; ++s) {
        #pragma unroll
        for (int t = 0; t < 2; ++t) {
            int mt = s * 2 + t;
            f32x4 acc = {0.f, 0.f, 0.f, 0.f};
            acc = __builtin_amdgcn_mfma_f32_16x16x32_bf16(
                *reinterpret_cast<const s16x8*>(WP2s + ((size_t)(mt * 2 + 0) * 64 + lane) * 8),
                pef[0].v, acc, 0, 0, 0);
            acc = __builtin_amdgcn_mfma_f32_16x16x32_bf16(
                *reinterpret_cast<const s16x8*>(WP2s + ((size_t)(mt * 2 + 1) * 64 + lane) * 8),
                pef[1].v, acc, 0, 0, 0);
            ushort4 pk;
            pk.x = f2bu(acc[0] + bp2[mt * 16 + hi * 4 + 0]);
            pk.y = f2bu(acc[1] + bp2[mt * 16 + hi * 4 + 1]);
            pk.z = f2bu(acc[2] + bp2[mt * 16 + hi * 4 + 2]);
            pk.w = f2bu(acc[3] + bp2[mt * 16 + hi * 4 + 3]);
            *reinterpret_cast<ushort4*>(&tileL[w][lo][t * 16 + hi * 4]) = pk;
        }
        __builtin_amdgcn_sched_barrier(0);   // writes before reads (DS is in-order per wave)
        int c0 = s * 32 + hi * 8;
        U8 pe8, q8, k8, v8, vw;
        pe8.v = *reinterpret_cast<const s16x8*>(&tileL[w][lo][hi * 8]);
        q8.v = *reinterpret_cast<const s16x8*>(qTb + qrow + c0);
        k8.v = *reinterpret_cast<const s16x8*>(kTb + krow + c0);
        v8.v = *reinterpret_cast<const s16x8*>(vTb + krow + c0);
        #pragma unroll
        for (int j = 0; j < 8; ++j) {
            float pe = bu2f(pe8.u[j]);
            xf[s].u[j] = f2bu((bu2f(q8.u[j]) - bu2f(k8.u[j])) + pe);
            vw.u[j]    = f2bu(bu2f(v8.u[j]) + pe);
        }
        *reinterpret_cast<s16x8*>(&vwpL[w][lo][c0]) = vw.v;
        __builtin_amdgcn_sched_barrier(0);   // keep next-iter writes after this read
    }

    // main MLP loop: 16 chunks of 64 hidden
    f32x4 acc2[16];
    #pragma unroll
    for (int i = 0; i < 16; ++i) acc2[i] = (f32x4){0.f, 0.f, 0.f, 0.f};
    #pragma unroll 1
    for (int cc = 0; cc < 16; ++cc) {
        __syncthreads();   // keep the 4 waves lockstep -> L1 reuse of W1/W2 fragments
        f32x4 a1[4];
        #pragma unroll
        for (int mt = 0; mt < 4; ++mt) a1[mt] = (f32x4){0.f, 0.f, 0.f, 0.f};
        #pragma unroll
        for (int mt = 0; mt < 4; ++mt) {
            const s16x8* wp = reinterpret_cast<const s16x8*>(W1s) +
                              (size_t)((cc * 4 + mt) * 8) * 64 + lane;
            #pragma unroll
            for (int s = 0; s < 8; ++s)
                a1[mt] = __builtin_amdgcn_mfma_f32_16x16x32_bf16(
                    wp[(size_t)s * 64], xf[s].v, a1[mt], 0, 0, 0);
        }
        #pragma unroll
        for (int mt = 0; mt < 4; ++mt) {
            int hb = cc * 64 + mt * 16 + hi * 4;
            ushort4 hp;
            hp.x = f2bu(fmaxf(a1[mt][0] + b1p[hb + 0], 0.f));
            hp.y = f2bu(fmaxf(a1[mt][1] + b1p[hb + 1], 0.f));
            hp.z = f2bu(fmaxf(a1[mt][2] + b1p[hb + 2], 0.f));
            hp.w = f2bu(fmaxf(a1[mt][3] + b1p[hb + 3], 0.f));
            *reinterpret_cast<ushort4*>(&hL[w][lo][mt * 16 + hi * 4]) = hp;
        }
        __builtin_amdgcn_sched_barrier(0);
        s16x8 b20 = *reinterpret_cast<const s16x8*>(&hL[w][lo][hi * 8]);
        s16x8 b21 = *reinterpret_cast<const s16x8*>(&hL[w][lo][32 + hi * 8]);
        #pragma unroll
        for (int mt2 = 0; mt2 < 16; ++mt2) {
            const s16x8* w2p = reinterpret_cast<const s16x8*>(W2s) +
                               (size_t)(mt2 * 32 + cc * 2) * 64 + lane;
            acc2[mt2] = __builtin_amdgcn_mfma_f32_16x16x32_bf16(w2p[0],  b20, acc2[mt2], 0, 0, 0);
            acc2[mt2] = __builtin_amdgcn_mfma_f32_16x16x32_bf16(w2p[64], b21, acc2[mt2], 0, 0, 0);
        }
    }

    // softmax over the 16 neighbors + aggregation.
    // FULLY UNROLLED so acc2[] indices are compile-time -> registers, not scratch.
    #pragma unroll
    for (int mt2 = 0; mt2 < 16; ++mt2) {
        #pragma unroll
        for (int r = 0; r < 4; ++r) {
            float a = acc2[mt2][r];
            float mx = a;
            mx = fmaxf(mx, __shfl_xor(mx, 1));
            mx = fmaxf(mx, __shfl_xor(mx, 2));
            mx = fmaxf(mx, __shfl_xor(mx, 4));
            mx = fmaxf(mx, __shfl_xor(mx, 8));
            float e = __expf(a - mx);
            float sm = e;
            sm += __shfl_xor(sm, 1); sm += __shfl_xor(sm, 2);
            sm += __shfl_xor(sm, 4); sm += __shfl_xor(sm, 8);
            int c = mt2 * 16 + hi * 4 + r;
            float vv = bu2f(vwpL[w][lo][c]);
            float p = e * vv;
            p += __shfl_xor(p, 1); p += __shfl_xor(p, 2);
            p += __shfl_xor(p, 4); p += __shfl_xor(p, 8);
            if (lo == 0) aggT[qrow + c] = p / sm;
        }
    }
}

// ---------------- K4: y = we . agg + bE + identity  (f32 out)
__global__ __launch_bounds__(256) void final_gemm(
    const float* __restrict__ we, const float* __restrict__ bE,
    const float* __restrict__ aggT, const float* __restrict__ identity,
    float* __restrict__ out)
{
    __shared__ float sA[16][64];
    __shared__ float sB[16][64];
    int b  = blockIdx.z;
    int c0 = blockIdx.y * 64;
    int n0 = blockIdx.x * 64;
    int t  = threadIdx.x;
    int ty = t >> 4, tx = t & 15;
    float acc[4][4] = {};
    for (int k0 = 0; k0 < kDim; k0 += 16) {
        {
            int i = t >> 2, ks = (t & 3) * 4;
            float4 w4 = *reinterpret_cast<const float4*>(
                we + (size_t)(c0 + i) * kDim + k0 + ks);
            sA[ks + 0][i] = w4.x; sA[ks + 1][i] = w4.y;
            sA[ks + 2][i] = w4.z; sA[ks + 3][i] = w4.w;
        }
        {
            int j = t >> 2, ks = (t & 3) * 4;
            float4 v = *reinterpret_cast<const float4*>(
                &aggT[((size_t)b * kNq + n0 + j) * kDim + k0 + ks]);
            sB[ks + 0][j] = v.x; sB[ks + 1][j] = v.y;
            sB[ks + 2][j] = v.z; sB[ks + 3][j] = v.w;
        }
        __syncthreads();
        #pragma unroll
        for (int kk = 0; kk < 16; ++kk) {
            float4 av = *reinterpret_cast<const float4*>(&sA[kk][ty * 4]);
            float4 bv = *reinterpret_cast<const float4*>(&sB[kk][tx * 4]);
            float a[4] = {av.x, av.y, av.z, av.w};
            float bb[4] = {bv.x, bv.y, bv.z, bv.w};
            #pragma unroll
            for (int i = 0; i < 4; ++i)
                #pragma unroll
                for (int j = 0; j < 4; ++j)
                    acc[i][j] = fmaf(a[i], bb[j], acc[i][j]);
        }
        __syncthreads();
    }
    #pragma unroll
    for (int i = 0; i < 4; ++i) {
        int c = c0 + ty * 4 + i;
        float bb = bE[c];
        size_t base = ((size_t)b * kCin + c) * kNq + n0 + tx * 4;
        #pragma unroll
        for (int j = 0; j < 4; ++j) {
            out[base + j] = acc[i][j] + bb + identity[base + j];
        }
    }
}

extern "C" void kernel_launch(void* const* d_in, const int* in_sizes, int n_in,
                              void* d_out, int out_size, void* d_ws, size_t ws_size,
                              hipStream_t stream) {
    const float* query_pos = (const float*)d_in[0];
    const float* query_feat= (const float*)d_in[1];
    const float* key_pos   = (const float*)d_in[2];
    const float* key_feat  = (const float*)d_in[3];
    const float* wq = (const float*)d_in[4];  const float* bq = (const float*)d_in[5];
    const float* wk = (const float*)d_in[6];  const float* bk = (const float*)d_in[7];
    const float* wv = (const float*)d_in[8];  const float* bv = (const float*)d_in[9];
    const float* wp1= (const float*)d_in[10]; const float* bp1= (const float*)d_in[11];
    const float* g1 = (const float*)d_in[12]; const float* be1= (const float*)d_in[13];
    const float* m1 = (const float*)d_in[14]; const float* v1 = (const float*)d_in[15];
    const float* wp2= (const float*)d_in[16]; const float* bp2= (const float*)d_in[17];
    const float* wa1= (const float*)d_in[18]; const float* ba1= (const float*)d_in[19];
    const float* g2 = (const float*)d_in[20]; const float* be2= (const float*)d_in[21];
    const float* m2 = (const float*)d_in[22]; const float* v2 = (const float*)d_in[23];
    const float* wa2= (const float*)d_in[24]; const float* ba2= (const float*)d_in[25];
    const float* we = (const float*)d_in[26]; const float* bE = (const float*)d_in[27];
    (void)ba2; // constant over k -> cancels in softmax

    float* wsf  = (float*)d_ws;
    float* aggT = wsf;                                   // 2M f32
    float* b1p  = aggT + 2097152;                        // 1024
    int*   idxb = (int*)(b1p + 1024);                    // 131072
    unsigned short* qTb = (unsigned short*)(idxb + 131072);  // 2M u16
    unsigned short* kTb = qTb + 2097152;
    unsigned short* vTb = kTb + 2097152;
    unsigned short* W1s = vTb + 2097152;                 // 262144 u16
    unsigned short* W2s = W1s + 262144;                  // 262144 u16
    unsigned short* WP2s= W2s + 262144;                  // 16384 u16

    dim3 blk(256);
    prep_w1<<<dim3(128), blk, 0, stream>>>(wa1, ba1, g2, be2, m2, v2, W1s, b1p);
    prep_w2<<<dim3(128), blk, 0, stream>>>(wa2, W2s);
    prep_wp2<<<dim3(8), blk, 0, stream>>>(wp2, WP2s);
    proj_gemmT<<<dim3(kNq / 64, kDim / 64, kB), blk, 0, stream>>>(wq, bq, query_feat, qTb, kNq);
    proj_gemmT<<<dim3(kNk / 64, kDim / 64, kB), blk, 0, stream>>>(wk, bk, key_feat, kTb, kNk);
    proj_gemmT<<<dim3(kNk / 64, kDim / 64, kB), blk, 0, stream>>>(wv, bv, key_feat, vTb, kNk);
    knn2<<<dim3(kB * kNq / 4), blk, 0, stream>>>(query_pos, key_pos, idxb);
    attn_mfma<<<dim3(kB * kNq / 4), blk, 0, stream>>>(query_pos, key_pos,
        qTb, kTb, vTb, idxb,
        wp1, bp1, g1, be1, m1, v1, WP2s, bp2, W1s, b1p, W2s, aggT);
    final_gemm<<<dim3(kNq / 64, kCin / 64, kB), blk, 0, stream>>>(
        we, bE, aggT, query_feat, (float*)d_out);
}

// Round 8
// 975.430 us; speedup vs baseline: 6.6587x; 1.0824x over previous
//
#include <hip/hip_runtime.h>
#include <hip/hip_bf16.h>

typedef __attribute__((ext_vector_type(8))) short s16x8;
typedef __attribute__((ext_vector_type(4))) float f32x4;

constexpr int kB   = 4;
constexpr int kCin = 256;
constexpr int kDim = 256;
constexpr int kNq  = 2048;
constexpr int kNk  = 2048;
constexpr int kK   = 16;
constexpr int kPosH= 64;
constexpr int kHid = 1024;
#define EPSF 1e-5f

__device__ __forceinline__ unsigned short f2bu(float f) {
    __hip_bfloat16 h = __float2bfloat16(f);
    return *reinterpret_cast<unsigned short*>(&h);
}
__device__ __forceinline__ float bu2f(unsigned short u) {
    union { unsigned int i; float f; } x; x.i = ((unsigned int)u) << 16; return x.f;
}

union U8 { s16x8 v; short s[8]; unsigned short u[8]; };
union U4 { ushort4 v; unsigned short u[4]; };

// ---------------- prep: W1' = wa1 * inv2 (bn2 folded), bf16 A-frag layout; b1' = ba1*inv2+sh2
__global__ __launch_bounds__(256) void prep_w1(
    const float* __restrict__ wa1, const float* __restrict__ ba1,
    const float* __restrict__ g2, const float* __restrict__ be2,
    const float* __restrict__ m2, const float* __restrict__ v2,
    unsigned short* __restrict__ W1s, float* __restrict__ b1p)
{
    int g = blockIdx.x * 256 + threadIdx.x;          // 32768 frag-lanes
    int mt = g >> 9, ks = (g >> 6) & 7, lane = g & 63;
    int row = mt * 16 + (lane & 15);
    int col = ks * 32 + (lane >> 4) * 8;
    float iv = g2[row] * (1.0f / sqrtf(v2[row] + EPSF));
    U8 o;
    #pragma unroll
    for (int j = 0; j < 8; ++j) o.u[j] = f2bu(wa1[row * 256 + col + j] * iv);
    *reinterpret_cast<s16x8*>(W1s + (size_t)g * 8) = o.v;
    if (ks == 0 && (lane >> 4) == 0)
        b1p[row] = ba1[row] * iv + (be2[row] - m2[row] * iv);
}

__global__ __launch_bounds__(256) void prep_w2(
    const float* __restrict__ wa2, unsigned short* __restrict__ W2s)
{
    int g = blockIdx.x * 256 + threadIdx.x;          // 32768
    int mt = g >> 11, ks = (g >> 6) & 31, lane = g & 63;
    int row = mt * 16 + (lane & 15);
    int col = ks * 32 + (lane >> 4) * 8;
    U8 o;
    #pragma unroll
    for (int j = 0; j < 8; ++j) o.u[j] = f2bu(wa2[row * 1024 + col + j]);
    *reinterpret_cast<s16x8*>(W2s + (size_t)g * 8) = o.v;
}

__global__ __launch_bounds__(256) void prep_wp2(
    const float* __restrict__ wp2, unsigned short* __restrict__ WP2s)
{
    int g = blockIdx.x * 256 + threadIdx.x;          // 2048
    int mt = g >> 7, ks = (g >> 6) & 1, lane = g & 63;
    int row = mt * 16 + (lane & 15);
    int col = ks * 32 + (lane >> 4) * 8;
    U8 o;
    #pragma unroll
    for (int j = 0; j < 8; ++j) o.u[j] = f2bu(wp2[row * 64 + col + j]);
    *reinterpret_cast<s16x8*>(WP2s + (size_t)g * 8) = o.v;
}

// ---------------- K1: projection GEMM -> bf16 transposed  YT[b][n][d]
__global__ __launch_bounds__(256) void proj_gemmT(
    const float* __restrict__ W, const float* __restrict__ bias,
    const float* __restrict__ X, unsigned short* __restrict__ YT, int Ncols)
{
    __shared__ float sW[16][64];
    __shared__ float sX[16][64];
    int b  = blockIdx.z;
    int d0 = blockIdx.y * 64;
    int n0 = blockIdx.x * 64;
    int t  = threadIdx.x;
    int ty = t >> 4, tx = t & 15;
    float acc[4][4] = {};
    for (int k0 = 0; k0 < kCin; k0 += 16) {
        {
            int i = t >> 2, ks = (t & 3) * 4;
            float4 w4 = *reinterpret_cast<const float4*>(
                W + (size_t)(d0 + i) * kCin + k0 + ks);
            sW[ks + 0][i] = w4.x; sW[ks + 1][i] = w4.y;
            sW[ks + 2][i] = w4.z; sW[ks + 3][i] = w4.w;
        }
        {
            int r = t >> 4, cs = (t & 15) * 4;
            float4 x4 = *reinterpret_cast<const float4*>(
                X + ((size_t)b * kCin + k0 + r) * Ncols + n0 + cs);
            *reinterpret_cast<float4*>(&sX[r][cs]) = x4;
        }
        __syncthreads();
        #pragma unroll
        for (int kk = 0; kk < 16; ++kk) {
            float4 av = *reinterpret_cast<const float4*>(&sW[kk][ty * 4]);
            float4 bv = *reinterpret_cast<const float4*>(&sX[kk][tx * 4]);
            float a[4] = {av.x, av.y, av.z, av.w};
            float bb[4] = {bv.x, bv.y, bv.z, bv.w};
            #pragma unroll
            for (int i = 0; i < 4; ++i)
                #pragma unroll
                for (int j = 0; j < 4; ++j)
                    acc[i][j] = fmaf(a[i], bb[j], acc[i][j]);
        }
        __syncthreads();
    }
    float bi[4];
    #pragma unroll
    for (int i = 0; i < 4; ++i) bi[i] = bias[d0 + ty * 4 + i];
    #pragma unroll
    for (int j = 0; j < 4; ++j) {
        int n = n0 + tx * 4 + j;
        ushort4 pk;
        pk.x = f2bu(acc[0][j] + bi[0]);
        pk.y = f2bu(acc[1][j] + bi[1]);
        pk.z = f2bu(acc[2][j] + bi[2]);
        pk.w = f2bu(acc[3][j] + bi[3]);
        *reinterpret_cast<ushort4*>(
            &YT[((size_t)b * Ncols + n) * 256 + d0 + ty * 4]) = pk;
    }
}

// ---------------- K2: KNN, wave-per-query (unchanged, passed)
__global__ __launch_bounds__(256) void knn2(
    const float* __restrict__ query_pos, const float* __restrict__ key_pos,
    int* __restrict__ idx_out)
{
    __shared__ float4 sk[kNk];
    int gq0 = blockIdx.x * 4;
    int b = gq0 >> 11;
    for (int m = threadIdx.x; m < kNk; m += 256) {
        float x = key_pos[((size_t)b * 3 + 0) * kNk + m];
        float y = key_pos[((size_t)b * 3 + 1) * kNk + m];
        float z = key_pos[((size_t)b * 3 + 2) * kNk + m];
        float kk = __fadd_rn(__fadd_rn(__fmul_rn(x, x), __fmul_rn(y, y)), __fmul_rn(z, z));
        sk[m] = make_float4(x, y, z, kk);
    }
    __syncthreads();
    int w = threadIdx.x >> 6, lane = threadIdx.x & 63;
    int gq = gq0 + w;
    int q = gq & 2047;
    float qx = query_pos[((size_t)b * 3 + 0) * kNq + q];
    float qy = query_pos[((size_t)b * 3 + 1) * kNq + q];
    float qz = query_pos[((size_t)b * 3 + 2) * kNq + q];
    float qq = __fadd_rn(__fadd_rn(__fmul_rn(qx, qx), __fmul_rn(qy, qy)), __fmul_rn(qz, qz));
    float td[kK]; int ti[kK];
    #pragma unroll
    for (int i = 0; i < kK; ++i) { td[i] = 3.4e38f; ti[i] = 0x7fffffff; }
    #pragma unroll 1
    for (int i = 0; i < 32; ++i) {
        int m = i * 64 + lane;
        float4 kv = sk[m];
        float dot = __fadd_rn(__fadd_rn(__fmul_rn(qx, kv.x), __fmul_rn(qy, kv.y)),
                              __fmul_rn(qz, kv.z));
        float d = __fsub_rn(__fadd_rn(qq, kv.w), __fmul_rn(2.0f, dot));
        bool better = (d < td[kK - 1]) || (d == td[kK - 1] && m < ti[kK - 1]);
        if (better) {
            td[kK - 1] = d; ti[kK - 1] = m;
            #pragma unroll
            for (int s = kK - 1; s > 0; --s) {
                bool sw = (td[s] < td[s - 1]) || (td[s] == td[s - 1] && ti[s] < ti[s - 1]);
                if (sw) {
                    float tf = td[s]; td[s] = td[s - 1]; td[s - 1] = tf;
                    int tt = ti[s]; ti[s] = ti[s - 1]; ti[s - 1] = tt;
                }
            }
        }
    }
    int outi = 0;
    #pragma unroll 1
    for (int r = 0; r < kK; ++r) {
        float dmin = td[0]; int imin = ti[0];
        #pragma unroll
        for (int msk = 1; msk < 64; msk <<= 1) {
            float od = __shfl_xor(dmin, msk);
            int   oi = __shfl_xor(imin, msk);
            if (od < dmin || (od == dmin && oi < imin)) { dmin = od; imin = oi; }
        }
        if (ti[0] == imin) {
            #pragma unroll
            for (int s = 0; s < kK - 1; ++s) { td[s] = td[s + 1]; ti[s] = ti[s + 1]; }
            td[kK - 1] = 3.4e38f; ti[kK - 1] = 0x7fffffff;
        }
        if (lane == r) outi = imin;
    }
    if (lane < 16) idx_out[((size_t)gq << 4) + lane] = outi;
}

// ---------------- K3: GEMM-shaped MFMA attention. 8 queries (128 cols) per 512-thread block.
// STATIC LDS (144 KB): pe [128][64h] 16KB | X [128][256c] 64KB | H [128][256h] 64KB,
// XOR-swizzled (byte ^= (col&7)<<4) for bank-conflict-free ds_read_b128.
__global__ __launch_bounds__(512, 2) void attn_mfma2(
    const float* __restrict__ qpos, const float* __restrict__ kpos,
    const unsigned short* __restrict__ qTb, const unsigned short* __restrict__ kTb,
    const unsigned short* __restrict__ vTb, const int* __restrict__ idxb,
    const float* __restrict__ wp1, const float* __restrict__ bp1,
    const float* __restrict__ g1, const float* __restrict__ be1,
    const float* __restrict__ m1, const float* __restrict__ v1,
    const unsigned short* __restrict__ WP2s, const float* __restrict__ bp2,
    const unsigned short* __restrict__ W1s, const float* __restrict__ b1p,
    const unsigned short* __restrict__ W2s,
    float* __restrict__ aggT)
{
    __shared__ __align__(16) char sm[147456];
    char* peB = sm;                 // 16384 B
    char* XB  = sm + 16384;         // 65536 B
    char* HB  = sm + 16384 + 65536; // 65536 B

    const int tid = threadIdx.x;
    const int gq0 = blockIdx.x * 8;
    const int b = gq0 >> 11;

    // ---- phase 1: pe = relu(bn1(wp1 . rel + bp1)) for 128 cols x 64 h
    {
        int col = tid >> 2, qq = tid & 3;
        int qi = col >> 4, kn = col & 15;
        int gq = gq0 + qi, q = gq & 2047;
        int mm = idxb[((size_t)gq << 4) + kn];
        float rx = qpos[((size_t)b * 3 + 0) * kNq + q] - kpos[((size_t)b * 3 + 0) * kNk + mm];
        float ry = qpos[((size_t)b * 3 + 1) * kNq + q] - kpos[((size_t)b * 3 + 1) * kNk + mm];
        float rz = qpos[((size_t)b * 3 + 2) * kNq + q] - kpos[((size_t)b * 3 + 2) * kNk + mm];
        int swz = (col & 7) << 4;
        U8 o0, o1;
        #pragma unroll
        for (int i = 0; i < 16; ++i) {
            int h = qq * 16 + i;
            float iv = g1[h] * (1.0f / sqrtf(v1[h] + EPSF));
            float pre = bp1[h] + wp1[h * 3 + 0] * rx + wp1[h * 3 + 1] * ry + wp1[h * 3 + 2] * rz;
            float pe = fmaxf(pre * iv + (be1[h] - m1[h] * iv), 0.0f);
            if (i < 8) o0.u[i] = f2bu(pe); else o1.u[i - 8] = f2bu(pe);
        }
        *reinterpret_cast<s16x8*>(peB + ((col * 128 + qq * 32) ^ swz)) = o0.v;
        *reinterpret_cast<s16x8*>(peB + ((col * 128 + qq * 32 + 16) ^ swz)) = o1.v;
    }
    __syncthreads();

    const int w = tid >> 6, lane = tid & 63;
    const int lo = lane & 15, hi = lane >> 4;
    const int w4 = w & 3, grp = w >> 2;
    const int colbase = grp * 64;
    const int col0 = colbase + lo;            // this lane's column for nt=0
    const int swzb = (lo & 7) << 4;           // (col&7)<<4 — nt/colbase are x16/x8 multiples

    // per-nt column info.  gq0 is GLOBAL (includes b*2048) — do NOT add b*kNq again.
    size_t qrowA[4], krow[4];
    #pragma unroll
    for (int nt = 0; nt < 4; ++nt) {
        int qc = grp * 4 + nt;
        int mm = idxb[((size_t)(gq0 + qc) << 4) + lo];
        qrowA[nt] = (size_t)(gq0 + qc) * 256;
        krow[nt]  = ((size_t)(b * kNk) + mm) * 256;
    }

    // ---- phase 3: pos_emb (MFMA) -> X (LDS) + vwp (regs)
    s16x8 pb[4][2];
    #pragma unroll
    for (int nt = 0; nt < 4; ++nt) {
        int cb = (col0 + nt * 16) * 128;
        pb[nt][0] = *reinterpret_cast<const s16x8*>(peB + ((cb + 0  + hi * 16) ^ swzb));
        pb[nt][1] = *reinterpret_cast<const s16x8*>(peB + ((cb + 64 + hi * 16) ^ swzb));
    }
    U4 vwp[4][4];
    #pragma unroll
    for (int ml = 0; ml < 4; ++ml) {
        int mt = w4 * 4 + ml;
        s16x8 a0 = *reinterpret_cast<const s16x8*>(WP2s + ((size_t)((mt * 2 + 0) * 64 + lane)) * 8);
        s16x8 a1_ = *reinterpret_cast<const s16x8*>(WP2s + ((size_t)((mt * 2 + 1) * 64 + lane)) * 8);
        int c0 = mt * 16 + hi * 4;
        float4 bp2v = *reinterpret_cast<const float4*>(bp2 + c0);
        #pragma unroll
        for (int nt = 0; nt < 4; ++nt) {
            f32x4 acc = {0.f, 0.f, 0.f, 0.f};
            acc = __builtin_amdgcn_mfma_f32_16x16x32_bf16(a0, pb[nt][0], acc, 0, 0, 0);
            acc = __builtin_amdgcn_mfma_f32_16x16x32_bf16(a1_, pb[nt][1], acc, 0, 0, 0);
            float pe0 = acc[0] + bp2v.x, pe1 = acc[1] + bp2v.y;
            float pe2 = acc[2] + bp2v.z, pe3 = acc[3] + bp2v.w;
            U4 q4, k4, v4, x4, vv;
            q4.v = *reinterpret_cast<const ushort4*>(qTb + qrowA[nt] + c0);
            k4.v = *reinterpret_cast<const ushort4*>(kTb + krow[nt] + c0);
            v4.v = *reinterpret_cast<const ushort4*>(vTb + krow[nt] + c0);
            x4.u[0] = f2bu((bu2f(q4.u[0]) - bu2f(k4.u[0])) + pe0);
            x4.u[1] = f2bu((bu2f(q4.u[1]) - bu2f(k4.u[1])) + pe1);
            x4.u[2] = f2bu((bu2f(q4.u[2]) - bu2f(k4.u[2])) + pe2);
            x4.u[3] = f2bu((bu2f(q4.u[3]) - bu2f(k4.u[3])) + pe3);
            vv.u[0] = f2bu(bu2f(v4.u[0]) + pe0);
            vv.u[1] = f2bu(bu2f(v4.u[1]) + pe1);
            vv.u[2] = f2bu(bu2f(v4.u[2]) + pe2);
            vv.u[3] = f2bu(bu2f(v4.u[3]) + pe3);
            *reinterpret_cast<ushort4*>(XB + (((col0 + nt * 16) * 512 + c0 * 2) ^ swzb)) = x4.v;
            vwp[ml][nt] = vv;
        }
    }
    __syncthreads();

    // ---- main loop: 4 chunks of 256 hidden rows
    f32x4 acc2[4][4];
    #pragma unroll
    for (int i = 0; i < 4; ++i)
        #pragma unroll
        for (int j = 0; j < 4; ++j) acc2[i][j] = (f32x4){0.f, 0.f, 0.f, 0.f};

    #pragma unroll 1
    for (int ch = 0; ch < 4; ++ch) {
        f32x4 a1[4][4];
        #pragma unroll
        for (int i = 0; i < 4; ++i)
            #pragma unroll
            for (int j = 0; j < 4; ++j) a1[i][j] = (f32x4){0.f, 0.f, 0.f, 0.f};
        #pragma unroll
        for (int ks = 0; ks < 8; ++ks) {
            s16x8 xb[4];
            #pragma unroll
            for (int nt = 0; nt < 4; ++nt)
                xb[nt] = *reinterpret_cast<const s16x8*>(
                    XB + (((col0 + nt * 16) * 512 + ks * 64 + hi * 16) ^ swzb));
            s16x8 aA[4];
            #pragma unroll
            for (int ml = 0; ml < 4; ++ml)
                aA[ml] = *reinterpret_cast<const s16x8*>(
                    W1s + ((size_t)(((ch * 16 + w4 * 4 + ml) * 8 + ks) * 64 + lane)) * 8);
            #pragma unroll
            for (int ml = 0; ml < 4; ++ml)
                #pragma unroll
                for (int nt = 0; nt < 4; ++nt)
                    a1[ml][nt] = __builtin_amdgcn_mfma_f32_16x16x32_bf16(
                        aA[ml], xb[nt], a1[ml][nt], 0, 0, 0);
        }
        #pragma unroll
        for (int ml = 0; ml < 4; ++ml) {
            int hloc = (w4 * 4 + ml) * 16 + hi * 4;           // chunk-local h
            float4 b4 = *reinterpret_cast<const float4*>(b1p + ch * 256 + hloc);
            #pragma unroll
            for (int nt = 0; nt < 4; ++nt) {
                U4 hp;
                hp.u[0] = f2bu(fmaxf(a1[ml][nt][0] + b4.x, 0.f));
                hp.u[1] = f2bu(fmaxf(a1[ml][nt][1] + b4.y, 0.f));
                hp.u[2] = f2bu(fmaxf(a1[ml][nt][2] + b4.z, 0.f));
                hp.u[3] = f2bu(fmaxf(a1[ml][nt][3] + b4.w, 0.f));
                *reinterpret_cast<ushort4*>(
                    HB + (((col0 + nt * 16) * 512 + hloc * 2) ^ swzb)) = hp.v;
            }
        }
        __syncthreads();
        #pragma unroll
        for (int kl = 0; kl < 8; ++kl) {
            s16x8 hb[4];
            #pragma unroll
            for (int nt = 0; nt < 4; ++nt)
                hb[nt] = *reinterpret_cast<const s16x8*>(
                    HB + (((col0 + nt * 16) * 512 + kl * 64 + hi * 16) ^ swzb));
            s16x8 aW[4];
            #pragma unroll
            for (int m2 = 0; m2 < 4; ++m2)
                aW[m2] = *reinterpret_cast<const s16x8*>(
                    W2s + ((size_t)(((w4 * 4 + m2) * 32 + ch * 8 + kl) * 64 + lane)) * 8);
            #pragma unroll
            for (int m2 = 0; m2 < 4; ++m2)
                #pragma unroll
                for (int nt = 0; nt < 4; ++nt)
                    acc2[m2][nt] = __builtin_amdgcn_mfma_f32_16x16x32_bf16(
                        aW[m2], hb[nt], acc2[m2][nt], 0, 0, 0);
        }
        __syncthreads();
    }

    // ---- epilogue: softmax over k (16 lanes lo) + aggregate with vwp, store f32
    #pragma unroll
    for (int m2 = 0; m2 < 4; ++m2) {
        #pragma unroll
        for (int nt = 0; nt < 4; ++nt) {
            U4 vv = vwp[m2][nt];
            #pragma unroll
            for (int r = 0; r < 4; ++r) {
                float a = acc2[m2][nt][r];
                float mx = a;
                mx = fmaxf(mx, __shfl_xor(mx, 1));
                mx = fmaxf(mx, __shfl_xor(mx, 2));
                mx = fmaxf(mx, __shfl_xor(mx, 4));
                mx = fmaxf(mx, __shfl_xor(mx, 8));
                float e = __expf(a - mx);
                float smv = e;
                smv += __shfl_xor(smv, 1); smv += __shfl_xor(smv, 2);
                smv += __shfl_xor(smv, 4); smv += __shfl_xor(smv, 8);
                float p = e * bu2f(vv.u[r]);
                p += __shfl_xor(p, 1); p += __shfl_xor(p, 2);
                p += __shfl_xor(p, 4); p += __shfl_xor(p, 8);
                if (lo == 0) {
                    int c = (w4 * 4 + m2) * 16 + hi * 4 + r;
                    aggT[qrowA[nt] + c] = p / smv;
                }
            }
        }
    }
}

// ---------------- K4: y = we . agg + bE + identity  (f32 out)
__global__ __launch_bounds__(256) void final_gemm(
    const float* __restrict__ we, const float* __restrict__ bE,
    const float* __restrict__ aggT, const float* __restrict__ identity,
    float* __restrict__ out)
{
    __shared__ float sA[16][64];
    __shared__ float sB[16][64];
    int b  = blockIdx.z;
    int c0 = blockIdx.y * 64;
    int n0 = blockIdx.x * 64;
    int t  = threadIdx.x;
    int ty = t >> 4, tx = t & 15;
    float acc[4][4] = {};
    for (int k0 = 0; k0 < kDim; k0 += 16) {
        {
            int i = t >> 2, ks = (t & 3) * 4;
            float4 w4 = *reinterpret_cast<const float4*>(
                we + (size_t)(c0 + i) * kDim + k0 + ks);
            sA[ks + 0][i] = w4.x; sA[ks + 1][i] = w4.y;
            sA[ks + 2][i] = w4.z; sA[ks + 3][i] = w4.w;
        }
        {
            int j = t >> 2, ks = (t & 3) * 4;
            float4 v = *reinterpret_cast<const float4*>(
                &aggT[((size_t)b * kNq + n0 + j) * kDim + k0 + ks]);
            sB[ks + 0][j] = v.x; sB[ks + 1][j] = v.y;
            sB[ks + 2][j] = v.z; sB[ks + 3][j] = v.w;
        }
        __syncthreads();
        #pragma unroll
        for (int kk = 0; kk < 16; ++kk) {
            float4 av = *reinterpret_cast<const float4*>(&sA[kk][ty * 4]);
            float4 bv = *reinterpret_cast<const float4*>(&sB[kk][tx * 4]);
            float a[4] = {av.x, av.y, av.z, av.w};
            float bb[4] = {bv.x, bv.y, bv.z, bv.w};
            #pragma unroll
            for (int i = 0; i < 4; ++i)
                #pragma unroll
                for (int j = 0; j < 4; ++j)
                    acc[i][j] = fmaf(a[i], bb[j], acc[i][j]);
        }
        __syncthreads();
    }
    #pragma unroll
    for (int i = 0; i < 4; ++i) {
        int c = c0 + ty * 4 + i;
        float bb = bE[c];
        size_t base = ((size_t)b * kCin + c) * kNq + n0 + tx * 4;
        #pragma unroll
        for (int j = 0; j < 4; ++j) {
            out[base + j] = acc[i][j] + bb + identity[base + j];
        }
    }
}

extern "C" void kernel_launch(void* const* d_in, const int* in_sizes, int n_in,
                              void* d_out, int out_size, void* d_ws, size_t ws_size,
                              hipStream_t stream) {
    const float* query_pos = (const float*)d_in[0];
    const float* query_feat= (const float*)d_in[1];
    const float* key_pos   = (const float*)d_in[2];
    const float* key_feat  = (const float*)d_in[3];
    const float* wq = (const float*)d_in[4];  const float* bq = (const float*)d_in[5];
    const float* wk = (const float*)d_in[6];  const float* bk = (const float*)d_in[7];
    const float* wv = (const float*)d_in[8];  const float* bv = (const float*)d_in[9];
    const float* wp1= (const float*)d_in[10]; const float* bp1= (const float*)d_in[11];
    const float* g1 = (const float*)d_in[12]; const float* be1= (const float*)d_in[13];
    const float* m1 = (const float*)d_in[14]; const float* v1 = (const float*)d_in[15];
    const float* wp2= (const float*)d_in[16]; const float* bp2= (const float*)d_in[17];
    const float* wa1= (const float*)d_in[18]; const float* ba1= (const float*)d_in[19];
    const float* g2 = (const float*)d_in[20]; const float* be2= (const float*)d_in[21];
    const float* m2 = (const float*)d_in[22]; const float* v2 = (const float*)d_in[23];
    const float* wa2= (const float*)d_in[24]; const float* ba2= (const float*)d_in[25];
    const float* we = (const float*)d_in[26]; const float* bE = (const float*)d_in[27];
    (void)ba2; // constant over k -> cancels in softmax

    float* wsf  = (float*)d_ws;
    float* aggT = wsf;                                   // 2M f32
    float* b1p  = aggT + 2097152;                        // 1024
    int*   idxb = (int*)(b1p + 1024);                    // 131072
    unsigned short* qTb = (unsigned short*)(idxb + 131072);  // 2M u16
    unsigned short* kTb = qTb + 2097152;
    unsigned short* vTb = kTb + 2097152;
    unsigned short* W1s = vTb + 2097152;                 // 262144 u16
    unsigned short* W2s = W1s + 262144;                  // 262144 u16
    unsigned short* WP2s= W2s + 262144;                  // 16384 u16

    dim3 blk(256);
    prep_w1<<<dim3(128), blk, 0, stream>>>(wa1, ba1, g2, be2, m2, v2, W1s, b1p);
    prep_w2<<<dim3(128), blk, 0, stream>>>(wa2, W2s);
    prep_wp2<<<dim3(8), blk, 0, stream>>>(wp2, WP2s);
    proj_gemmT<<<dim3(kNq / 64, kDim / 64, kB), blk, 0, stream>>>(wq, bq, query_feat, qTb, kNq);
    proj_gemmT<<<dim3(kNk / 64, kDim / 64, kB), blk, 0, stream>>>(wk, bk, key_feat, kTb, kNk);
    proj_gemmT<<<dim3(kNk / 64, kDim / 64, kB), blk, 0, stream>>>(wv, bv, key_feat, vTb, kNk);
    knn2<<<dim3(kB * kNq / 4), blk, 0, stream>>>(query_pos, key_pos, idxb);
    attn_mfma2<<<dim3(kB * kNq / 8), dim3(512), 0, stream>>>(query_pos, key_pos,
        qTb, kTb, vTb, idxb,
        wp1, bp1, g1, be1, m1, v1, WP2s, bp2, W1s, b1p, W2s, aggT);
    final_gemm<<<dim3(kNq / 64, kCin / 64, kB), blk, 0, stream>>>(
        we, bE, aggT, query_feat, (float*)d_out);
}

// Round 9
// 973.427 us; speedup vs baseline: 6.6724x; 1.0021x over previous
//
#include <hip/hip_runtime.h>
#include <hip/hip_bf16.h>

typedef __attribute__((ext_vector_type(8))) short s16x8;
typedef __attribute__((ext_vector_type(4))) float f32x4;

constexpr int kB   = 4;
constexpr int kCin = 256;
constexpr int kDim = 256;
constexpr int kNq  = 2048;
constexpr int kNk  = 2048;
constexpr int kK   = 16;
constexpr int kPosH= 64;
constexpr int kHid = 1024;
#define EPSF 1e-5f

__device__ __forceinline__ unsigned short f2bu(float f) {
    __hip_bfloat16 h = __float2bfloat16(f);
    return *reinterpret_cast<unsigned short*>(&h);
}
__device__ __forceinline__ float bu2f(unsigned short u) {
    union { unsigned int i; float f; } x; x.i = ((unsigned int)u) << 16; return x.f;
}

union U8 { s16x8 v; short s[8]; unsigned short u[8]; };
union U4 { ushort4 v; unsigned short u[4]; };

// ---------------- prep: W1' = wa1 * inv2 (bn2 folded), bf16 A-frag layout; b1' = ba1*inv2+sh2
__global__ __launch_bounds__(256) void prep_w1(
    const float* __restrict__ wa1, const float* __restrict__ ba1,
    const float* __restrict__ g2, const float* __restrict__ be2,
    const float* __restrict__ m2, const float* __restrict__ v2,
    unsigned short* __restrict__ W1s, float* __restrict__ b1p)
{
    int g = blockIdx.x * 256 + threadIdx.x;          // 32768 frag-lanes
    int mt = g >> 9, ks = (g >> 6) & 7, lane = g & 63;
    int row = mt * 16 + (lane & 15);
    int col = ks * 32 + (lane >> 4) * 8;
    float iv = g2[row] * (1.0f / sqrtf(v2[row] + EPSF));
    U8 o;
    #pragma unroll
    for (int j = 0; j < 8; ++j) o.u[j] = f2bu(wa1[row * 256 + col + j] * iv);
    *reinterpret_cast<s16x8*>(W1s + (size_t)g * 8) = o.v;
    if (ks == 0 && (lane >> 4) == 0)
        b1p[row] = ba1[row] * iv + (be2[row] - m2[row] * iv);
}

__global__ __launch_bounds__(256) void prep_w2(
    const float* __restrict__ wa2, unsigned short* __restrict__ W2s)
{
    int g = blockIdx.x * 256 + threadIdx.x;          // 32768
    int mt = g >> 11, ks = (g >> 6) & 31, lane = g & 63;
    int row = mt * 16 + (lane & 15);
    int col = ks * 32 + (lane >> 4) * 8;
    U8 o;
    #pragma unroll
    for (int j = 0; j < 8; ++j) o.u[j] = f2bu(wa2[row * 1024 + col + j]);
    *reinterpret_cast<s16x8*>(W2s + (size_t)g * 8) = o.v;
}

__global__ __launch_bounds__(256) void prep_wp2(
    const float* __restrict__ wp2, unsigned short* __restrict__ WP2s)
{
    int g = blockIdx.x * 256 + threadIdx.x;          // 2048
    int mt = g >> 7, ks = (g >> 6) & 1, lane = g & 63;
    int row = mt * 16 + (lane & 15);
    int col = ks * 32 + (lane >> 4) * 8;
    U8 o;
    #pragma unroll
    for (int j = 0; j < 8; ++j) o.u[j] = f2bu(wp2[row * 64 + col + j]);
    *reinterpret_cast<s16x8*>(WP2s + (size_t)g * 8) = o.v;
}

// ---------------- K1: projection GEMM -> bf16 transposed  YT[b][n][d]
__global__ __launch_bounds__(256) void proj_gemmT(
    const float* __restrict__ W, const float* __restrict__ bias,
    const float* __restrict__ X, unsigned short* __restrict__ YT, int Ncols)
{
    __shared__ float sW[16][64];
    __shared__ float sX[16][64];
    int b  = blockIdx.z;
    int d0 = blockIdx.y * 64;
    int n0 = blockIdx.x * 64;
    int t  = threadIdx.x;
    int ty = t >> 4, tx = t & 15;
    float acc[4][4] = {};
    for (int k0 = 0; k0 < kCin; k0 += 16) {
        {
            int i = t >> 2, ks = (t & 3) * 4;
            float4 w4 = *reinterpret_cast<const float4*>(
                W + (size_t)(d0 + i) * kCin + k0 + ks);
            sW[ks + 0][i] = w4.x; sW[ks + 1][i] = w4.y;
            sW[ks + 2][i] = w4.z; sW[ks + 3][i] = w4.w;
        }
        {
            int r = t >> 4, cs = (t & 15) * 4;
            float4 x4 = *reinterpret_cast<const float4*>(
                X + ((size_t)b * kCin + k0 + r) * Ncols + n0 + cs);
            *reinterpret_cast<float4*>(&sX[r][cs]) = x4;
        }
        __syncthreads();
        #pragma unroll
        for (int kk = 0; kk < 16; ++kk) {
            float4 av = *reinterpret_cast<const float4*>(&sW[kk][ty * 4]);
            float4 bv = *reinterpret_cast<const float4*>(&sX[kk][tx * 4]);
            float a[4] = {av.x, av.y, av.z, av.w};
            float bb[4] = {bv.x, bv.y, bv.z, bv.w};
            #pragma unroll
            for (int i = 0; i < 4; ++i)
                #pragma unroll
                for (int j = 0; j < 4; ++j)
                    acc[i][j] = fmaf(a[i], bb[j], acc[i][j]);
        }
        __syncthreads();
    }
    float bi[4];
    #pragma unroll
    for (int i = 0; i < 4; ++i) bi[i] = bias[d0 + ty * 4 + i];
    #pragma unroll
    for (int j = 0; j < 4; ++j) {
        int n = n0 + tx * 4 + j;
        ushort4 pk;
        pk.x = f2bu(acc[0][j] + bi[0]);
        pk.y = f2bu(acc[1][j] + bi[1]);
        pk.z = f2bu(acc[2][j] + bi[2]);
        pk.w = f2bu(acc[3][j] + bi[3]);
        *reinterpret_cast<ushort4*>(
            &YT[((size_t)b * Ncols + n) * 256 + d0 + ty * 4]) = pk;
    }
}

// ---------------- K2: KNN, wave-per-query (unchanged, passed)
__global__ __launch_bounds__(256) void knn2(
    const float* __restrict__ query_pos, const float* __restrict__ key_pos,
    int* __restrict__ idx_out)
{
    __shared__ float4 sk[kNk];
    int gq0 = blockIdx.x * 4;
    int b = gq0 >> 11;
    for (int m = threadIdx.x; m < kNk; m += 256) {
        float x = key_pos[((size_t)b * 3 + 0) * kNk + m];
        float y = key_pos[((size_t)b * 3 + 1) * kNk + m];
        float z = key_pos[((size_t)b * 3 + 2) * kNk + m];
        float kk = __fadd_rn(__fadd_rn(__fmul_rn(x, x), __fmul_rn(y, y)), __fmul_rn(z, z));
        sk[m] = make_float4(x, y, z, kk);
    }
    __syncthreads();
    int w = threadIdx.x >> 6, lane = threadIdx.x & 63;
    int gq = gq0 + w;
    int q = gq & 2047;
    float qx = query_pos[((size_t)b * 3 + 0) * kNq + q];
    float qy = query_pos[((size_t)b * 3 + 1) * kNq + q];
    float qz = query_pos[((size_t)b * 3 + 2) * kNq + q];
    float qq = __fadd_rn(__fadd_rn(__fmul_rn(qx, qx), __fmul_rn(qy, qy)), __fmul_rn(qz, qz));
    float td[kK]; int ti[kK];
    #pragma unroll
    for (int i = 0; i < kK; ++i) { td[i] = 3.4e38f; ti[i] = 0x7fffffff; }
    #pragma unroll 1
    for (int i = 0; i < 32; ++i) {
        int m = i * 64 + lane;
        float4 kv = sk[m];
        float dot = __fadd_rn(__fadd_rn(__fmul_rn(qx, kv.x), __fmul_rn(qy, kv.y)),
                              __fmul_rn(qz, kv.z));
        float d = __fsub_rn(__fadd_rn(qq, kv.w), __fmul_rn(2.0f, dot));
        bool better = (d < td[kK - 1]) || (d == td[kK - 1] && m < ti[kK - 1]);
        if (better) {
            td[kK - 1] = d; ti[kK - 1] = m;
            #pragma unroll
            for (int s = kK - 1; s > 0; --s) {
                bool sw = (td[s] < td[s - 1]) || (td[s] == td[s - 1] && ti[s] < ti[s - 1]);
                if (sw) {
                    float tf = td[s]; td[s] = td[s - 1]; td[s - 1] = tf;
                    int tt = ti[s]; ti[s] = ti[s - 1]; ti[s - 1] = tt;
                }
            }
        }
    }
    int outi = 0;
    #pragma unroll 1
    for (int r = 0; r < kK; ++r) {
        float dmin = td[0]; int imin = ti[0];
        #pragma unroll
        for (int msk = 1; msk < 64; msk <<= 1) {
            float od = __shfl_xor(dmin, msk);
            int   oi = __shfl_xor(imin, msk);
            if (od < dmin || (od == dmin && oi < imin)) { dmin = od; imin = oi; }
        }
        if (ti[0] == imin) {
            #pragma unroll
            for (int s = 0; s < kK - 1; ++s) { td[s] = td[s + 1]; ti[s] = ti[s + 1]; }
            td[kK - 1] = 3.4e38f; ti[kK - 1] = 0x7fffffff;
        }
        if (lane == r) outi = imin;
    }
    if (lane < 16) idx_out[((size_t)gq << 4) + lane] = outi;
}

// ---------------- K3: GEMM-shaped MFMA attention. 8 queries (128 cols) per 512-thread block.
// __launch_bounds__(512,1): 1 block/CU -> 256-VGPR budget, no spill (128-cap spilled 380MB, r8).
__global__ __launch_bounds__(512, 1) void attn_mfma2(
    const float* __restrict__ qpos, const float* __restrict__ kpos,
    const unsigned short* __restrict__ qTb, const unsigned short* __restrict__ kTb,
    const unsigned short* __restrict__ vTb, const int* __restrict__ idxb,
    const float* __restrict__ wp1, const float* __restrict__ bp1,
    const float* __restrict__ g1, const float* __restrict__ be1,
    const float* __restrict__ m1, const float* __restrict__ v1,
    const unsigned short* __restrict__ WP2s, const float* __restrict__ bp2,
    const unsigned short* __restrict__ W1s, const float* __restrict__ b1p,
    const unsigned short* __restrict__ W2s,
    float* __restrict__ aggT)
{
    __shared__ __align__(16) char sm[147456];
    char* peB = sm;                 // 16384 B
    char* XB  = sm + 16384;         // 65536 B
    char* HB  = sm + 16384 + 65536; // 65536 B

    const int tid = threadIdx.x;
    const int gq0 = blockIdx.x * 8;
    const int b = gq0 >> 11;

    // ---- phase 1: pe = relu(bn1(wp1 . rel + bp1)) for 128 cols x 64 h
    {
        int col = tid >> 2, qq = tid & 3;
        int qi = col >> 4, kn = col & 15;
        int gq = gq0 + qi, q = gq & 2047;
        int mm = idxb[((size_t)gq << 4) + kn];
        float rx = qpos[((size_t)b * 3 + 0) * kNq + q] - kpos[((size_t)b * 3 + 0) * kNk + mm];
        float ry = qpos[((size_t)b * 3 + 1) * kNq + q] - kpos[((size_t)b * 3 + 1) * kNk + mm];
        float rz = qpos[((size_t)b * 3 + 2) * kNq + q] - kpos[((size_t)b * 3 + 2) * kNk + mm];
        int swz = (col & 7) << 4;
        U8 o0, o1;
        #pragma unroll
        for (int i = 0; i < 16; ++i) {
            int h = qq * 16 + i;
            float iv = g1[h] * (1.0f / sqrtf(v1[h] + EPSF));
            float pre = bp1[h] + wp1[h * 3 + 0] * rx + wp1[h * 3 + 1] * ry + wp1[h * 3 + 2] * rz;
            float pe = fmaxf(pre * iv + (be1[h] - m1[h] * iv), 0.0f);
            if (i < 8) o0.u[i] = f2bu(pe); else o1.u[i - 8] = f2bu(pe);
        }
        *reinterpret_cast<s16x8*>(peB + ((col * 128 + qq * 32) ^ swz)) = o0.v;
        *reinterpret_cast<s16x8*>(peB + ((col * 128 + qq * 32 + 16) ^ swz)) = o1.v;
    }
    __syncthreads();

    const int w = tid >> 6, lane = tid & 63;
    const int lo = lane & 15, hi = lane >> 4;
    const int w4 = w & 3, grp = w >> 2;
    const int colbase = grp * 64;
    const int col0 = colbase + lo;            // this lane's column for nt=0
    const int swzb = (lo & 7) << 4;           // (col&7)<<4 — nt/colbase are x16/x8 multiples

    // per-nt column info.  gq0 is GLOBAL (includes b*2048) — do NOT add b*kNq again.
    size_t qrowA[4], krow[4];
    #pragma unroll
    for (int nt = 0; nt < 4; ++nt) {
        int qc = grp * 4 + nt;
        int mm = idxb[((size_t)(gq0 + qc) << 4) + lo];
        qrowA[nt] = (size_t)(gq0 + qc) * 256;
        krow[nt]  = ((size_t)(b * kNk) + mm) * 256;
    }

    // ---- phase 3: pos_emb (MFMA) -> X (LDS) + vwp (regs)
    s16x8 pb[4][2];
    #pragma unroll
    for (int nt = 0; nt < 4; ++nt) {
        int cb = (col0 + nt * 16) * 128;
        pb[nt][0] = *reinterpret_cast<const s16x8*>(peB + ((cb + 0  + hi * 16) ^ swzb));
        pb[nt][1] = *reinterpret_cast<const s16x8*>(peB + ((cb + 64 + hi * 16) ^ swzb));
    }
    U4 vwp[4][4];
    #pragma unroll
    for (int ml = 0; ml < 4; ++ml) {
        int mt = w4 * 4 + ml;
        s16x8 a0 = *reinterpret_cast<const s16x8*>(WP2s + ((size_t)((mt * 2 + 0) * 64 + lane)) * 8);
        s16x8 a1_ = *reinterpret_cast<const s16x8*>(WP2s + ((size_t)((mt * 2 + 1) * 64 + lane)) * 8);
        int c0 = mt * 16 + hi * 4;
        float4 bp2v = *reinterpret_cast<const float4*>(bp2 + c0);
        #pragma unroll
        for (int nt = 0; nt < 4; ++nt) {
            f32x4 acc = {0.f, 0.f, 0.f, 0.f};
            acc = __builtin_amdgcn_mfma_f32_16x16x32_bf16(a0, pb[nt][0], acc, 0, 0, 0);
            acc = __builtin_amdgcn_mfma_f32_16x16x32_bf16(a1_, pb[nt][1], acc, 0, 0, 0);
            float pe0 = acc[0] + bp2v.x, pe1 = acc[1] + bp2v.y;
            float pe2 = acc[2] + bp2v.z, pe3 = acc[3] + bp2v.w;
            U4 q4, k4, v4, x4, vv;
            q4.v = *reinterpret_cast<const ushort4*>(qTb + qrowA[nt] + c0);
            k4.v = *reinterpret_cast<const ushort4*>(kTb + krow[nt] + c0);
            v4.v = *reinterpret_cast<const ushort4*>(vTb + krow[nt] + c0);
            x4.u[0] = f2bu((bu2f(q4.u[0]) - bu2f(k4.u[0])) + pe0);
            x4.u[1] = f2bu((bu2f(q4.u[1]) - bu2f(k4.u[1])) + pe1);
            x4.u[2] = f2bu((bu2f(q4.u[2]) - bu2f(k4.u[2])) + pe2);
            x4.u[3] = f2bu((bu2f(q4.u[3]) - bu2f(k4.u[3])) + pe3);
            vv.u[0] = f2bu(bu2f(v4.u[0]) + pe0);
            vv.u[1] = f2bu(bu2f(v4.u[1]) + pe1);
            vv.u[2] = f2bu(bu2f(v4.u[2]) + pe2);
            vv.u[3] = f2bu(bu2f(v4.u[3]) + pe3);
            *reinterpret_cast<ushort4*>(XB + (((col0 + nt * 16) * 512 + c0 * 2) ^ swzb)) = x4.v;
            vwp[ml][nt] = vv;
        }
    }
    __syncthreads();

    // ---- main loop: 4 chunks of 256 hidden rows
    f32x4 acc2[4][4];
    #pragma unroll
    for (int i = 0; i < 4; ++i)
        #pragma unroll
        for (int j = 0; j < 4; ++j) acc2[i][j] = (f32x4){0.f, 0.f, 0.f, 0.f};

    #pragma unroll 1
    for (int ch = 0; ch < 4; ++ch) {
        f32x4 a1[4][4];
        #pragma unroll
        for (int i = 0; i < 4; ++i)
            #pragma unroll
            for (int j = 0; j < 4; ++j) a1[i][j] = (f32x4){0.f, 0.f, 0.f, 0.f};
        #pragma unroll
        for (int ks = 0; ks < 8; ++ks) {
            s16x8 xb[4];
            #pragma unroll
            for (int nt = 0; nt < 4; ++nt)
                xb[nt] = *reinterpret_cast<const s16x8*>(
                    XB + (((col0 + nt * 16) * 512 + ks * 64 + hi * 16) ^ swzb));
            s16x8 aA[4];
            #pragma unroll
            for (int ml = 0; ml < 4; ++ml)
                aA[ml] = *reinterpret_cast<const s16x8*>(
                    W1s + ((size_t)(((ch * 16 + w4 * 4 + ml) * 8 + ks) * 64 + lane)) * 8);
            #pragma unroll
            for (int ml = 0; ml < 4; ++ml)
                #pragma unroll
                for (int nt = 0; nt < 4; ++nt)
                    a1[ml][nt] = __builtin_amdgcn_mfma_f32_16x16x32_bf16(
                        aA[ml], xb[nt], a1[ml][nt], 0, 0, 0);
        }
        #pragma unroll
        for (int ml = 0; ml < 4; ++ml) {
            int hloc = (w4 * 4 + ml) * 16 + hi * 4;           // chunk-local h
            float4 b4 = *reinterpret_cast<const float4*>(b1p + ch * 256 + hloc);
            #pragma unroll
            for (int nt = 0; nt < 4; ++nt) {
                U4 hp;
                hp.u[0] = f2bu(fmaxf(a1[ml][nt][0] + b4.x, 0.f));
                hp.u[1] = f2bu(fmaxf(a1[ml][nt][1] + b4.y, 0.f));
                hp.u[2] = f2bu(fmaxf(a1[ml][nt][2] + b4.z, 0.f));
                hp.u[3] = f2bu(fmaxf(a1[ml][nt][3] + b4.w, 0.f));
                *reinterpret_cast<ushort4*>(
                    HB + (((col0 + nt * 16) * 512 + hloc * 2) ^ swzb)) = hp.v;
            }
        }
        __syncthreads();
        #pragma unroll
        for (int kl = 0; kl < 8; ++kl) {
            s16x8 hb[4];
            #pragma unroll
            for (int nt = 0; nt < 4; ++nt)
                hb[nt] = *reinterpret_cast<const s16x8*>(
                    HB + (((col0 + nt * 16) * 512 + kl * 64 + hi * 16) ^ swzb));
            s16x8 aW[4];
            #pragma unroll
            for (int m2 = 0; m2 < 4; ++m2)
                aW[m2] = *reinterpret_cast<const s16x8*>(
                    W2s + ((size_t)(((w4 * 4 + m2) * 32 + ch * 8 + kl) * 64 + lane)) * 8);
            #pragma unroll
            for (int m2 = 0; m2 < 4; ++m2)
                #pragma unroll
                for (int nt = 0; nt < 4; ++nt)
                    acc2[m2][nt] = __builtin_amdgcn_mfma_f32_16x16x32_bf16(
                        aW[m2], hb[nt], acc2[m2][nt], 0, 0, 0);
        }
        __syncthreads();
    }

    // ---- epilogue: softmax over k (16 lanes lo) + aggregate with vwp, store f32
    #pragma unroll
    for (int m2 = 0; m2 < 4; ++m2) {
        #pragma unroll
        for (int nt = 0; nt < 4; ++nt) {
            U4 vv = vwp[m2][nt];
            #pragma unroll
            for (int r = 0; r < 4; ++r) {
                float a = acc2[m2][nt][r];
                float mx = a;
                mx = fmaxf(mx, __shfl_xor(mx, 1));
                mx = fmaxf(mx, __shfl_xor(mx, 2));
                mx = fmaxf(mx, __shfl_xor(mx, 4));
                mx = fmaxf(mx, __shfl_xor(mx, 8));
                float e = __expf(a - mx);
                float smv = e;
                smv += __shfl_xor(smv, 1); smv += __shfl_xor(smv, 2);
                smv += __shfl_xor(smv, 4); smv += __shfl_xor(smv, 8);
                float p = e * bu2f(vv.u[r]);
                p += __shfl_xor(p, 1); p += __shfl_xor(p, 2);
                p += __shfl_xor(p, 4); p += __shfl_xor(p, 8);
                if (lo == 0) {
                    int c = (w4 * 4 + m2) * 16 + hi * 4 + r;
                    aggT[qrowA[nt] + c] = p / smv;
                }
            }
        }
    }
}

// ---------------- K4: y = we . agg + bE + identity  (f32 out)
__global__ __launch_bounds__(256) void final_gemm(
    const float* __restrict__ we, const float* __restrict__ bE,
    const float* __restrict__ aggT, const float* __restrict__ identity,
    float* __restrict__ out)
{
    __shared__ float sA[16][64];
    __shared__ float sB[16][64];
    int b  = blockIdx.z;
    int c0 = blockIdx.y * 64;
    int n0 = blockIdx.x * 64;
    int t  = threadIdx.x;
    int ty = t >> 4, tx = t & 15;
    float acc[4][4] = {};
    for (int k0 = 0; k0 < kDim; k0 += 16) {
        {
            int i = t >> 2, ks = (t & 3) * 4;
            float4 w4 = *reinterpret_cast<const float4*>(
                we + (size_t)(c0 + i) * kDim + k0 + ks);
            sA[ks + 0][i] = w4.x; sA[ks + 1][i] = w4.y;
            sA[ks + 2][i] = w4.z; sA[ks + 3][i] = w4.w;
        }
        {
            int j = t >> 2, ks = (t & 3) * 4;
            float4 v = *reinterpret_cast<const float4*>(
                &aggT[((size_t)b * kNq + n0 + j) * kDim + k0 + ks]);
            sB[ks + 0][j] = v.x; sB[ks + 1][j] = v.y;
            sB[ks + 2][j] = v.z; sB[ks + 3][j] = v.w;
        }
        __syncthreads();
        #pragma unroll
        for (int kk = 0; kk < 16; ++kk) {
            float4 av = *reinterpret_cast<const float4*>(&sA[kk][ty * 4]);
            float4 bv = *reinterpret_cast<const float4*>(&sB[kk][tx * 4]);
            float a[4] = {av.x, av.y, av.z, av.w};
            float bb[4] = {bv.x, bv.y, bv.z, bv.w};
            #pragma unroll
            for (int i = 0; i < 4; ++i)
                #pragma unroll
                for (int j = 0; j < 4; ++j)
                    acc[i][j] = fmaf(a[i], bb[j], acc[i][j]);
        }
        __syncthreads();
    }
    #pragma unroll
    for (int i = 0; i < 4; ++i) {
        int c = c0 + ty * 4 + i;
        float bb = bE[c];
        size_t base = ((size_t)b * kCin + c) * kNq + n0 + tx * 4;
        #pragma unroll
        for (int j = 0; j < 4; ++j) {
            out[base + j] = acc[i][j] + bb + identity[base + j];
        }
    }
}

extern "C" void kernel_launch(void* const* d_in, const int* in_sizes, int n_in,
                              void* d_out, int out_size, void* d_ws, size_t ws_size,
                              hipStream_t stream) {
    const float* query_pos = (const float*)d_in[0];
    const float* query_feat= (const float*)d_in[1];
    const float* key_pos   = (const float*)d_in[2];
    const float* key_feat  = (const float*)d_in[3];
    const float* wq = (const float*)d_in[4];  const float* bq = (const float*)d_in[5];
    const float* wk = (const float*)d_in[6];  const float* bk = (const float*)d_in[7];
    const float* wv = (const float*)d_in[8];  const float* bv = (const float*)d_in[9];
    const float* wp1= (const float*)d_in[10]; const float* bp1= (const float*)d_in[11];
    const float* g1 = (const float*)d_in[12]; const float* be1= (const float*)d_in[13];
    const float* m1 = (const float*)d_in[14]; const float* v1 = (const float*)d_in[15];
    const float* wp2= (const float*)d_in[16]; const float* bp2= (const float*)d_in[17];
    const float* wa1= (const float*)d_in[18]; const float* ba1= (const float*)d_in[19];
    const float* g2 = (const float*)d_in[20]; const float* be2= (const float*)d_in[21];
    const float* m2 = (const float*)d_in[22]; const float* v2 = (const float*)d_in[23];
    const float* wa2= (const float*)d_in[24]; const float* ba2= (const float*)d_in[25];
    const float* we = (const float*)d_in[26]; const float* bE = (const float*)d_in[27];
    (void)ba2; // constant over k -> cancels in softmax

    float* wsf  = (float*)d_ws;
    float* aggT = wsf;                                   // 2M f32
    float* b1p  = aggT + 2097152;                        // 1024
    int*   idxb = (int*)(b1p + 1024);                    // 131072
    unsigned short* qTb = (unsigned short*)(idxb + 131072);  // 2M u16
    unsigned short* kTb = qTb + 2097152;
    unsigned short* vTb = kTb + 2097152;
    unsigned short* W1s = vTb + 2097152;                 // 262144 u16
    unsigned short* W2s = W1s + 262144;                  // 262144 u16
    unsigned short* WP2s= W2s + 262144;                  // 16384 u16

    dim3 blk(256);
    prep_w1<<<dim3(128), blk, 0, stream>>>(wa1, ba1, g2, be2, m2, v2, W1s, b1p);
    prep_w2<<<dim3(128), blk, 0, stream>>>(wa2, W2s);
    prep_wp2<<<dim3(8), blk, 0, stream>>>(wp2, WP2s);
    proj_gemmT<<<dim3(kNq / 64, kDim / 64, kB), blk, 0, stream>>>(wq, bq, query_feat, qTb, kNq);
    proj_gemmT<<<dim3(kNk / 64, kDim / 64, kB), blk, 0, stream>>>(wk, bk, key_feat, kTb, kNk);
    proj_gemmT<<<dim3(kNk / 64, kDim / 64, kB), blk, 0, stream>>>(wv, bv, key_feat, vTb, kNk);
    knn2<<<dim3(kB * kNq / 4), blk, 0, stream>>>(query_pos, key_pos, idxb);
    attn_mfma2<<<dim3(kB * kNq / 8), dim3(512), 0, stream>>>(query_pos, key_pos,
        qTb, kTb, vTb, idxb,
        wp1, bp1, g1, be1, m1, v1, WP2s, bp2, W1s, b1p, W2s, aggT);
    final_gemm<<<dim3(kNq / 64, kCin / 64, kB), blk, 0, stream>>>(
        we, bE, aggT, query_feat, (float*)d_out);
}

// Round 10
// 942.939 us; speedup vs baseline: 6.8881x; 1.0323x over previous
//
#include <hip/hip_runtime.h>
#include <hip/hip_bf16.h>

typedef __attribute__((ext_vector_type(8))) short s16x8;
typedef __attribute__((ext_vector_type(4))) float f32x4;

constexpr int kB   = 4;
constexpr int kCin = 256;
constexpr int kDim = 256;
constexpr int kNq  = 2048;
constexpr int kNk  = 2048;
constexpr int kK   = 16;
constexpr int kPosH= 64;
constexpr int kHid = 1024;
#define EPSF 1e-5f

__device__ __forceinline__ unsigned short f2bu(float f) {
    __hip_bfloat16 h = __float2bfloat16(f);
    return *reinterpret_cast<unsigned short*>(&h);
}
__device__ __forceinline__ float bu2f(unsigned short u) {
    union { unsigned int i; float f; } x; x.i = ((unsigned int)u) << 16; return x.f;
}

union U8 { s16x8 v; short s[8]; unsigned short u[8]; };
union U4 { ushort4 v; unsigned short u[4]; };

// ---------------- prep: W1' = wa1 * inv2 (bn2 folded), bf16 A-frag layout; b1' = ba1*inv2+sh2
__global__ __launch_bounds__(256) void prep_w1(
    const float* __restrict__ wa1, const float* __restrict__ ba1,
    const float* __restrict__ g2, const float* __restrict__ be2,
    const float* __restrict__ m2, const float* __restrict__ v2,
    unsigned short* __restrict__ W1s, float* __restrict__ b1p)
{
    int g = blockIdx.x * 256 + threadIdx.x;          // 32768 frag-lanes
    int mt = g >> 9, ks = (g >> 6) & 7, lane = g & 63;
    int row = mt * 16 + (lane & 15);
    int col = ks * 32 + (lane >> 4) * 8;
    float iv = g2[row] * (1.0f / sqrtf(v2[row] + EPSF));
    U8 o;
    #pragma unroll
    for (int j = 0; j < 8; ++j) o.u[j] = f2bu(wa1[row * 256 + col + j] * iv);
    *reinterpret_cast<s16x8*>(W1s + (size_t)g * 8) = o.v;
    if (ks == 0 && (lane >> 4) == 0)
        b1p[row] = ba1[row] * iv + (be2[row] - m2[row] * iv);
}

__global__ __launch_bounds__(256) void prep_w2(
    const float* __restrict__ wa2, unsigned short* __restrict__ W2s)
{
    int g = blockIdx.x * 256 + threadIdx.x;          // 32768
    int mt = g >> 11, ks = (g >> 6) & 31, lane = g & 63;
    int row = mt * 16 + (lane & 15);
    int col = ks * 32 + (lane >> 4) * 8;
    U8 o;
    #pragma unroll
    for (int j = 0; j < 8; ++j) o.u[j] = f2bu(wa2[row * 1024 + col + j]);
    *reinterpret_cast<s16x8*>(W2s + (size_t)g * 8) = o.v;
}

__global__ __launch_bounds__(256) void prep_wp2(
    const float* __restrict__ wp2, unsigned short* __restrict__ WP2s)
{
    int g = blockIdx.x * 256 + threadIdx.x;          // 2048
    int mt = g >> 7, ks = (g >> 6) & 1, lane = g & 63;
    int row = mt * 16 + (lane & 15);
    int col = ks * 32 + (lane >> 4) * 8;
    U8 o;
    #pragma unroll
    for (int j = 0; j < 8; ++j) o.u[j] = f2bu(wp2[row * 64 + col + j]);
    *reinterpret_cast<s16x8*>(WP2s + (size_t)g * 8) = o.v;
}

// ---------------- K1: projection GEMM -> bf16 transposed  YT[b][n][d]
__global__ __launch_bounds__(256) void proj_gemmT(
    const float* __restrict__ W, const float* __restrict__ bias,
    const float* __restrict__ X, unsigned short* __restrict__ YT, int Ncols)
{
    __shared__ float sW[16][64];
    __shared__ float sX[16][64];
    int b  = blockIdx.z;
    int d0 = blockIdx.y * 64;
    int n0 = blockIdx.x * 64;
    int t  = threadIdx.x;
    int ty = t >> 4, tx = t & 15;
    float acc[4][4] = {};
    for (int k0 = 0; k0 < kCin; k0 += 16) {
        {
            int i = t >> 2, ks = (t & 3) * 4;
            float4 w4 = *reinterpret_cast<const float4*>(
                W + (size_t)(d0 + i) * kCin + k0 + ks);
            sW[ks + 0][i] = w4.x; sW[ks + 1][i] = w4.y;
            sW[ks + 2][i] = w4.z; sW[ks + 3][i] = w4.w;
        }
        {
            int r = t >> 4, cs = (t & 15) * 4;
            float4 x4 = *reinterpret_cast<const float4*>(
                X + ((size_t)b * kCin + k0 + r) * Ncols + n0 + cs);
            *reinterpret_cast<float4*>(&sX[r][cs]) = x4;
        }
        __syncthreads();
        #pragma unroll
        for (int kk = 0; kk < 16; ++kk) {
            float4 av = *reinterpret_cast<const float4*>(&sW[kk][ty * 4]);
            float4 bv = *reinterpret_cast<const float4*>(&sX[kk][tx * 4]);
            float a[4] = {av.x, av.y, av.z, av.w};
            float bb[4] = {bv.x, bv.y, bv.z, bv.w};
            #pragma unroll
            for (int i = 0; i < 4; ++i)
                #pragma unroll
                for (int j = 0; j < 4; ++j)
                    acc[i][j] = fmaf(a[i], bb[j], acc[i][j]);
        }
        __syncthreads();
    }
    float bi[4];
    #pragma unroll
    for (int i = 0; i < 4; ++i) bi[i] = bias[d0 + ty * 4 + i];
    #pragma unroll
    for (int j = 0; j < 4; ++j) {
        int n = n0 + tx * 4 + j;
        ushort4 pk;
        pk.x = f2bu(acc[0][j] + bi[0]);
        pk.y = f2bu(acc[1][j] + bi[1]);
        pk.z = f2bu(acc[2][j] + bi[2]);
        pk.w = f2bu(acc[3][j] + bi[3]);
        *reinterpret_cast<ushort4*>(
            &YT[((size_t)b * Ncols + n) * 256 + d0 + ty * 4]) = pk;
    }
}

// ---------------- K2: KNN, wave-per-query (unchanged, passed)
__global__ __launch_bounds__(256) void knn2(
    const float* __restrict__ query_pos, const float* __restrict__ key_pos,
    int* __restrict__ idx_out)
{
    __shared__ float4 sk[kNk];
    int gq0 = blockIdx.x * 4;
    int b = gq0 >> 11;
    for (int m = threadIdx.x; m < kNk; m += 256) {
        float x = key_pos[((size_t)b * 3 + 0) * kNk + m];
        float y = key_pos[((size_t)b * 3 + 1) * kNk + m];
        float z = key_pos[((size_t)b * 3 + 2) * kNk + m];
        float kk = __fadd_rn(__fadd_rn(__fmul_rn(x, x), __fmul_rn(y, y)), __fmul_rn(z, z));
        sk[m] = make_float4(x, y, z, kk);
    }
    __syncthreads();
    int w = threadIdx.x >> 6, lane = threadIdx.x & 63;
    int gq = gq0 + w;
    int q = gq & 2047;
    float qx = query_pos[((size_t)b * 3 + 0) * kNq + q];
    float qy = query_pos[((size_t)b * 3 + 1) * kNq + q];
    float qz = query_pos[((size_t)b * 3 + 2) * kNq + q];
    float qq = __fadd_rn(__fadd_rn(__fmul_rn(qx, qx), __fmul_rn(qy, qy)), __fmul_rn(qz, qz));
    float td[kK]; int ti[kK];
    #pragma unroll
    for (int i = 0; i < kK; ++i) { td[i] = 3.4e38f; ti[i] = 0x7fffffff; }
    #pragma unroll 1
    for (int i = 0; i < 32; ++i) {
        int m = i * 64 + lane;
        float4 kv = sk[m];
        float dot = __fadd_rn(__fadd_rn(__fmul_rn(qx, kv.x), __fmul_rn(qy, kv.y)),
                              __fmul_rn(qz, kv.z));
        float d = __fsub_rn(__fadd_rn(qq, kv.w), __fmul_rn(2.0f, dot));
        bool better = (d < td[kK - 1]) || (d == td[kK - 1] && m < ti[kK - 1]);
        if (better) {
            td[kK - 1] = d; ti[kK - 1] = m;
            #pragma unroll
            for (int s = kK - 1; s > 0; --s) {
                bool sw = (td[s] < td[s - 1]) || (td[s] == td[s - 1] && ti[s] < ti[s - 1]);
                if (sw) {
                    float tf = td[s]; td[s] = td[s - 1]; td[s - 1] = tf;
                    int tt = ti[s]; ti[s] = ti[s - 1]; ti[s - 1] = tt;
                }
            }
        }
    }
    int outi = 0;
    #pragma unroll 1
    for (int r = 0; r < kK; ++r) {
        float dmin = td[0]; int imin = ti[0];
        #pragma unroll
        for (int msk = 1; msk < 64; msk <<= 1) {
            float od = __shfl_xor(dmin, msk);
            int   oi = __shfl_xor(imin, msk);
            if (od < dmin || (od == dmin && oi < imin)) { dmin = od; imin = oi; }
        }
        if (ti[0] == imin) {
            #pragma unroll
            for (int s = 0; s < kK - 1; ++s) { td[s] = td[s + 1]; ti[s] = ti[s + 1]; }
            td[kK - 1] = 3.4e38f; ti[kK - 1] = 0x7fffffff;
        }
        if (lane == r) outi = imin;
    }
    if (lane < 16) idx_out[((size_t)gq << 4) + lane] = outi;
}

// ---------------- K3: GEMM-shaped MFMA attention. 8 queries (128 cols) per 512-thread block.
// Register budget: 8-wave block -> 2 waves/SIMD -> 256 TOTAL regs/wave (arch+acc unified).
// acc2+a1 = 128 acc regs; vwp/pb/krow removed from cross-phase live set (recomputed in
// epilogue from peB, which stays valid in LDS) so arch side fits without spill.
__global__ __launch_bounds__(512, 2) void attn_mfma2(
    const float* __restrict__ qpos, const float* __restrict__ kpos,
    const unsigned short* __restrict__ qTb, const unsigned short* __restrict__ kTb,
    const unsigned short* __restrict__ vTb, const int* __restrict__ idxb,
    const float* __restrict__ wp1, const float* __restrict__ bp1,
    const float* __restrict__ g1, const float* __restrict__ be1,
    const float* __restrict__ m1, const float* __restrict__ v1,
    const unsigned short* __restrict__ WP2s, const float* __restrict__ bp2,
    const unsigned short* __restrict__ W1s, const float* __restrict__ b1p,
    const unsigned short* __restrict__ W2s,
    float* __restrict__ aggT)
{
    __shared__ __align__(16) char sm[147456];
    char* peB = sm;                 // 16384 B  (valid for entire kernel)
    char* XB  = sm + 16384;         // 65536 B
    char* HB  = sm + 16384 + 65536; // 65536 B

    const int tid = threadIdx.x;
    const int gq0 = blockIdx.x * 8;
    const int b = gq0 >> 11;

    // ---- phase 1: pe = relu(bn1(wp1 . rel + bp1)) for 128 cols x 64 h
    {
        int col = tid >> 2, qq = tid & 3;
        int qi = col >> 4, kn = col & 15;
        int gq = gq0 + qi, q = gq & 2047;
        int mm = idxb[((size_t)gq << 4) + kn];
        float rx = qpos[((size_t)b * 3 + 0) * kNq + q] - kpos[((size_t)b * 3 + 0) * kNk + mm];
        float ry = qpos[((size_t)b * 3 + 1) * kNq + q] - kpos[((size_t)b * 3 + 1) * kNk + mm];
        float rz = qpos[((size_t)b * 3 + 2) * kNq + q] - kpos[((size_t)b * 3 + 2) * kNk + mm];
        int swz = (col & 7) << 4;
        U8 o0, o1;
        #pragma unroll
        for (int i = 0; i < 16; ++i) {
            int h = qq * 16 + i;
            float iv = g1[h] * (1.0f / sqrtf(v1[h] + EPSF));
            float pre = bp1[h] + wp1[h * 3 + 0] * rx + wp1[h * 3 + 1] * ry + wp1[h * 3 + 2] * rz;
            float pe = fmaxf(pre * iv + (be1[h] - m1[h] * iv), 0.0f);
            if (i < 8) o0.u[i] = f2bu(pe); else o1.u[i - 8] = f2bu(pe);
        }
        *reinterpret_cast<s16x8*>(peB + ((col * 128 + qq * 32) ^ swz)) = o0.v;
        *reinterpret_cast<s16x8*>(peB + ((col * 128 + qq * 32 + 16) ^ swz)) = o1.v;
    }
    __syncthreads();

    const int w = tid >> 6, lane = tid & 63;
    const int lo = lane & 15, hi = lane >> 4;
    const int w4 = w & 3, grp = w >> 2;
    const int colbase = grp * 64;
    const int col0 = colbase + lo;
    const int swzb = (lo & 7) << 4;

    // ---- phase 3: pos_emb (MFMA) -> X (LDS). All temporaries scoped (die before main loop).
    {
        size_t krow[4];
        #pragma unroll
        for (int nt = 0; nt < 4; ++nt) {
            int mm = idxb[((size_t)(gq0 + grp * 4 + nt) << 4) + lo];
            krow[nt] = ((size_t)(b * kNk) + mm) * 256;
        }
        s16x8 pb[4][2];
        #pragma unroll
        for (int nt = 0; nt < 4; ++nt) {
            int cb = (col0 + nt * 16) * 128;
            pb[nt][0] = *reinterpret_cast<const s16x8*>(peB + ((cb + 0  + hi * 16) ^ swzb));
            pb[nt][1] = *reinterpret_cast<const s16x8*>(peB + ((cb + 64 + hi * 16) ^ swzb));
        }
        #pragma unroll
        for (int ml = 0; ml < 4; ++ml) {
            int mt = w4 * 4 + ml;
            s16x8 wA0 = *reinterpret_cast<const s16x8*>(WP2s + ((size_t)((mt * 2 + 0) * 64 + lane)) * 8);
            s16x8 wA1 = *reinterpret_cast<const s16x8*>(WP2s + ((size_t)((mt * 2 + 1) * 64 + lane)) * 8);
            int c0 = mt * 16 + hi * 4;
            float4 bp2v = *reinterpret_cast<const float4*>(bp2 + c0);
            #pragma unroll
            for (int nt = 0; nt < 4; ++nt) {
                f32x4 acc = {0.f, 0.f, 0.f, 0.f};
                acc = __builtin_amdgcn_mfma_f32_16x16x32_bf16(wA0, pb[nt][0], acc, 0, 0, 0);
                acc = __builtin_amdgcn_mfma_f32_16x16x32_bf16(wA1, pb[nt][1], acc, 0, 0, 0);
                size_t qrow = (size_t)(gq0 + grp * 4 + nt) * 256;
                U4 q4, k4, x4;
                q4.v = *reinterpret_cast<const ushort4*>(qTb + qrow + c0);
                k4.v = *reinterpret_cast<const ushort4*>(kTb + krow[nt] + c0);
                x4.u[0] = f2bu((bu2f(q4.u[0]) - bu2f(k4.u[0])) + (acc[0] + bp2v.x));
                x4.u[1] = f2bu((bu2f(q4.u[1]) - bu2f(k4.u[1])) + (acc[1] + bp2v.y));
                x4.u[2] = f2bu((bu2f(q4.u[2]) - bu2f(k4.u[2])) + (acc[2] + bp2v.z));
                x4.u[3] = f2bu((bu2f(q4.u[3]) - bu2f(k4.u[3])) + (acc[3] + bp2v.w));
                *reinterpret_cast<ushort4*>(XB + (((col0 + nt * 16) * 512 + c0 * 2) ^ swzb)) = x4.v;
            }
        }
    }
    __syncthreads();

    // ---- main loop: 4 chunks of 256 hidden rows
    f32x4 acc2[4][4];
    #pragma unroll
    for (int i = 0; i < 4; ++i)
        #pragma unroll
        for (int j = 0; j < 4; ++j) acc2[i][j] = (f32x4){0.f, 0.f, 0.f, 0.f};

    #pragma unroll 1
    for (int ch = 0; ch < 4; ++ch) {
        f32x4 a1[4][4];
        #pragma unroll
        for (int i = 0; i < 4; ++i)
            #pragma unroll
            for (int j = 0; j < 4; ++j) a1[i][j] = (f32x4){0.f, 0.f, 0.f, 0.f};
        #pragma unroll
        for (int ks = 0; ks < 8; ++ks) {
            s16x8 xb[4];
            #pragma unroll
            for (int nt = 0; nt < 4; ++nt)
                xb[nt] = *reinterpret_cast<const s16x8*>(
                    XB + (((col0 + nt * 16) * 512 + ks * 64 + hi * 16) ^ swzb));
            s16x8 aA[4];
            #pragma unroll
            for (int ml = 0; ml < 4; ++ml)
                aA[ml] = *reinterpret_cast<const s16x8*>(
                    W1s + ((size_t)(((ch * 16 + w4 * 4 + ml) * 8 + ks) * 64 + lane)) * 8);
            #pragma unroll
            for (int ml = 0; ml < 4; ++ml)
                #pragma unroll
                for (int nt = 0; nt < 4; ++nt)
                    a1[ml][nt] = __builtin_amdgcn_mfma_f32_16x16x32_bf16(
                        aA[ml], xb[nt], a1[ml][nt], 0, 0, 0);
        }
        #pragma unroll
        for (int ml = 0; ml < 4; ++ml) {
            int hloc = (w4 * 4 + ml) * 16 + hi * 4;
            float4 b4 = *reinterpret_cast<const float4*>(b1p + ch * 256 + hloc);
            #pragma unroll
            for (int nt = 0; nt < 4; ++nt) {
                U4 hp;
                hp.u[0] = f2bu(fmaxf(a1[ml][nt][0] + b4.x, 0.f));
                hp.u[1] = f2bu(fmaxf(a1[ml][nt][1] + b4.y, 0.f));
                hp.u[2] = f2bu(fmaxf(a1[ml][nt][2] + b4.z, 0.f));
                hp.u[3] = f2bu(fmaxf(a1[ml][nt][3] + b4.w, 0.f));
                *reinterpret_cast<ushort4*>(
                    HB + (((col0 + nt * 16) * 512 + hloc * 2) ^ swzb)) = hp.v;
            }
        }
        __syncthreads();
        #pragma unroll
        for (int kl = 0; kl < 8; ++kl) {
            s16x8 hb[4];
            #pragma unroll
            for (int nt = 0; nt < 4; ++nt)
                hb[nt] = *reinterpret_cast<const s16x8*>(
                    HB + (((col0 + nt * 16) * 512 + kl * 64 + hi * 16) ^ swzb));
            s16x8 aW[4];
            #pragma unroll
            for (int m2 = 0; m2 < 4; ++m2)
                aW[m2] = *reinterpret_cast<const s16x8*>(
                    W2s + ((size_t)(((w4 * 4 + m2) * 32 + ch * 8 + kl) * 64 + lane)) * 8);
            #pragma unroll
            for (int m2 = 0; m2 < 4; ++m2)
                #pragma unroll
                for (int nt = 0; nt < 4; ++nt)
                    acc2[m2][nt] = __builtin_amdgcn_mfma_f32_16x16x32_bf16(
                        aW[m2], hb[nt], acc2[m2][nt], 0, 0, 0);
        }
        __syncthreads();
    }

    // ---- epilogue: recompute pos_emb from peB (still valid), vwp = v + pe in f32,
    //      softmax over k (lo lanes) + aggregate, store f32
    #pragma unroll
    for (int m2 = 0; m2 < 4; ++m2) {
        int mt = w4 * 4 + m2;
        s16x8 wA0 = *reinterpret_cast<const s16x8*>(WP2s + ((size_t)((mt * 2 + 0) * 64 + lane)) * 8);
        s16x8 wA1 = *reinterpret_cast<const s16x8*>(WP2s + ((size_t)((mt * 2 + 1) * 64 + lane)) * 8);
        int c0 = mt * 16 + hi * 4;
        float4 bp2v = *reinterpret_cast<const float4*>(bp2 + c0);
        #pragma unroll
        for (int nt = 0; nt < 4; ++nt) {
            int cb = (col0 + nt * 16) * 128;
            s16x8 pb0 = *reinterpret_cast<const s16x8*>(peB + ((cb + 0  + hi * 16) ^ swzb));
            s16x8 pb1 = *reinterpret_cast<const s16x8*>(peB + ((cb + 64 + hi * 16) ^ swzb));
            f32x4 pa = {0.f, 0.f, 0.f, 0.f};
            pa = __builtin_amdgcn_mfma_f32_16x16x32_bf16(wA0, pb0, pa, 0, 0, 0);
            pa = __builtin_amdgcn_mfma_f32_16x16x32_bf16(wA1, pb1, pa, 0, 0, 0);
            int mm = idxb[((size_t)(gq0 + grp * 4 + nt) << 4) + lo];
            U4 v4;
            v4.v = *reinterpret_cast<const ushort4*>(
                vTb + ((size_t)(b * kNk) + mm) * 256 + c0);
            float pe4[4] = {pa[0] + bp2v.x, pa[1] + bp2v.y, pa[2] + bp2v.z, pa[3] + bp2v.w};
            size_t qrow = (size_t)(gq0 + grp * 4 + nt) * 256;
            #pragma unroll
            for (int r = 0; r < 4; ++r) {
                float a = acc2[m2][nt][r];
                float mx = a;
                mx = fmaxf(mx, __shfl_xor(mx, 1));
                mx = fmaxf(mx, __shfl_xor(mx, 2));
                mx = fmaxf(mx, __shfl_xor(mx, 4));
                mx = fmaxf(mx, __shfl_xor(mx, 8));
                float e = __expf(a - mx);
                float smv = e;
                smv += __shfl_xor(smv, 1); smv += __shfl_xor(smv, 2);
                smv += __shfl_xor(smv, 4); smv += __shfl_xor(smv, 8);
                float vwp = bu2f(v4.u[r]) + pe4[r];
                float p = e * vwp;
                p += __shfl_xor(p, 1); p += __shfl_xor(p, 2);
                p += __shfl_xor(p, 4); p += __shfl_xor(p, 8);
                if (lo == 0) aggT[qrow + c0 + r] = p / smv;
            }
        }
    }
}

// ---------------- K4: y = we . agg + bE + identity  (f32 out)
__global__ __launch_bounds__(256) void final_gemm(
    const float* __restrict__ we, const float* __restrict__ bE,
    const float* __restrict__ aggT, const float* __restrict__ identity,
    float* __restrict__ out)
{
    __shared__ float sA[16][64];
    __shared__ float sB[16][64];
    int b  = blockIdx.z;
    int c0 = blockIdx.y * 64;
    int n0 = blockIdx.x * 64;
    int t  = threadIdx.x;
    int ty = t >> 4, tx = t & 15;
    float acc[4][4] = {};
    for (int k0 = 0; k0 < kDim; k0 += 16) {
        {
            int i = t >> 2, ks = (t & 3) * 4;
            float4 w4 = *reinterpret_cast<const float4*>(
                we + (size_t)(c0 + i) * kDim + k0 + ks);
            sA[ks + 0][i] = w4.x; sA[ks + 1][i] = w4.y;
            sA[ks + 2][i] = w4.z; sA[ks + 3][i] = w4.w;
        }
        {
            int j = t >> 2, ks = (t & 3) * 4;
            float4 v = *reinterpret_cast<const float4*>(
                &aggT[((size_t)b * kNq + n0 + j) * kDim + k0 + ks]);
            sB[ks + 0][j] = v.x; sB[ks + 1][j] = v.y;
            sB[ks + 2][j] = v.z; sB[ks + 3][j] = v.w;
        }
        __syncthreads();
        #pragma unroll
        for (int kk = 0; kk < 16; ++kk) {
            float4 av = *reinterpret_cast<const float4*>(&sA[kk][ty * 4]);
            float4 bv = *reinterpret_cast<const float4*>(&sB[kk][tx * 4]);
            float a[4] = {av.x, av.y, av.z, av.w};
            float bb[4] = {bv.x, bv.y, bv.z, bv.w};
            #pragma unroll
            for (int i = 0; i < 4; ++i)
                #pragma unroll
                for (int j = 0; j < 4; ++j)
                    acc[i][j] = fmaf(a[i], bb[j], acc[i][j]);
        }
        __syncthreads();
    }
    #pragma unroll
    for (int i = 0; i < 4; ++i) {
        int c = c0 + ty * 4 + i;
        float bb = bE[c];
        size_t base = ((size_t)b * kCin + c) * kNq + n0 + tx * 4;
        #pragma unroll
        for (int j = 0; j < 4; ++j) {
            out[base + j] = acc[i][j] + bb + identity[base + j];
        }
    }
}

extern "C" void kernel_launch(void* const* d_in, const int* in_sizes, int n_in,
                              void* d_out, int out_size, void* d_ws, size_t ws_size,
                              hipStream_t stream) {
    const float* query_pos = (const float*)d_in[0];
    const float* query_feat= (const float*)d_in[1];
    const float* key_pos   = (const float*)d_in[2];
    const float* key_feat  = (const float*)d_in[3];
    const float* wq = (const float*)d_in[4];  const float* bq = (const float*)d_in[5];
    const float* wk = (const float*)d_in[6];  const float* bk = (const float*)d_in[7];
    const float* wv = (const float*)d_in[8];  const float* bv = (const float*)d_in[9];
    const float* wp1= (const float*)d_in[10]; const float* bp1= (const float*)d_in[11];
    const float* g1 = (const float*)d_in[12]; const float* be1= (const float*)d_in[13];
    const float* m1 = (const float*)d_in[14]; const float* v1 = (const float*)d_in[15];
    const float* wp2= (const float*)d_in[16]; const float* bp2= (const float*)d_in[17];
    const float* wa1= (const float*)d_in[18]; const float* ba1= (const float*)d_in[19];
    const float* g2 = (const float*)d_in[20]; const float* be2= (const float*)d_in[21];
    const float* m2 = (const float*)d_in[22]; const float* v2 = (const float*)d_in[23];
    const float* wa2= (const float*)d_in[24]; const float* ba2= (const float*)d_in[25];
    const float* we = (const float*)d_in[26]; const float* bE = (const float*)d_in[27];
    (void)ba2; // constant over k -> cancels in softmax

    float* wsf  = (float*)d_ws;
    float* aggT = wsf;                                   // 2M f32
    float* b1p  = aggT + 2097152;                        // 1024
    int*   idxb = (int*)(b1p + 1024);                    // 131072
    unsigned short* qTb = (unsigned short*)(idxb + 131072);  // 2M u16
    unsigned short* kTb = qTb + 2097152;
    unsigned short* vTb = kTb + 2097152;
    unsigned short* W1s = vTb + 2097152;                 // 262144 u16
    unsigned short* W2s = W1s + 262144;                  // 262144 u16
    unsigned short* WP2s= W2s + 262144;                  // 16384 u16

    dim3 blk(256);
    prep_w1<<<dim3(128), blk, 0, stream>>>(wa1, ba1, g2, be2, m2, v2, W1s, b1p);
    prep_w2<<<dim3(128), blk, 0, stream>>>(wa2, W2s);
    prep_wp2<<<dim3(8), blk, 0, stream>>>(wp2, WP2s);
    proj_gemmT<<<dim3(kNq / 64, kDim / 64, kB), blk, 0, stream>>>(wq, bq, query_feat, qTb, kNq);
    proj_gemmT<<<dim3(kNk / 64, kDim / 64, kB), blk, 0, stream>>>(wk, bk, key_feat, kTb, kNk);
    proj_gemmT<<<dim3(kNk / 64, kDim / 64, kB), blk, 0, stream>>>(wv, bv, key_feat, vTb, kNk);
    knn2<<<dim3(kB * kNq / 4), blk, 0, stream>>>(query_pos, key_pos, idxb);
    attn_mfma2<<<dim3(kB * kNq / 8), dim3(512), 0, stream>>>(query_pos, key_pos,
        qTb, kTb, vTb, idxb,
        wp1, bp1, g1, be1, m1, v1, WP2s, bp2, W1s, b1p, W2s, aggT);
    final_gemm<<<dim3(kNq / 64, kCin / 64, kB), blk, 0, stream>>>(
        we, bE, aggT, query_feat, (float*)d_out);
}

// Round 11
// 887.465 us; speedup vs baseline: 7.3187x; 1.0625x over previous
//
#include <hip/hip_runtime.h>
#include <hip/hip_bf16.h>

typedef __attribute__((ext_vector_type(8))) short s16x8;
typedef __attribute__((ext_vector_type(4))) float f32x4;

constexpr int kB   = 4;
constexpr int kCin = 256;
constexpr int kDim = 256;
constexpr int kNq  = 2048;
constexpr int kNk  = 2048;
constexpr int kK   = 16;
constexpr int kPosH= 64;
constexpr int kHid = 1024;
#define EPSF 1e-5f

__device__ __forceinline__ unsigned short f2bu(float f) {
    __hip_bfloat16 h = __float2bfloat16(f);
    return *reinterpret_cast<unsigned short*>(&h);
}
__device__ __forceinline__ float bu2f(unsigned short u) {
    union { unsigned int i; float f; } x; x.i = ((unsigned int)u) << 16; return x.f;
}

union U8 { s16x8 v; short s[8]; unsigned short u[8]; };
union U4 { ushort4 v; unsigned short u[4]; };

// ---------------- prep: W1' = wa1 * inv2 (bn2 folded), bf16 A-frag layout; b1' = ba1*inv2+sh2
__global__ __launch_bounds__(256) void prep_w1(
    const float* __restrict__ wa1, const float* __restrict__ ba1,
    const float* __restrict__ g2, const float* __restrict__ be2,
    const float* __restrict__ m2, const float* __restrict__ v2,
    unsigned short* __restrict__ W1s, float* __restrict__ b1p)
{
    int g = blockIdx.x * 256 + threadIdx.x;          // 32768 frag-lanes
    int mt = g >> 9, ks = (g >> 6) & 7, lane = g & 63;
    int row = mt * 16 + (lane & 15);
    int col = ks * 32 + (lane >> 4) * 8;
    float iv = g2[row] * (1.0f / sqrtf(v2[row] + EPSF));
    U8 o;
    #pragma unroll
    for (int j = 0; j < 8; ++j) o.u[j] = f2bu(wa1[row * 256 + col + j] * iv);
    *reinterpret_cast<s16x8*>(W1s + (size_t)g * 8) = o.v;
    if (ks == 0 && (lane >> 4) == 0)
        b1p[row] = ba1[row] * iv + (be2[row] - m2[row] * iv);
}

__global__ __launch_bounds__(256) void prep_w2(
    const float* __restrict__ wa2, unsigned short* __restrict__ W2s)
{
    int g = blockIdx.x * 256 + threadIdx.x;          // 32768
    int mt = g >> 11, ks = (g >> 6) & 31, lane = g & 63;
    int row = mt * 16 + (lane & 15);
    int col = ks * 32 + (lane >> 4) * 8;
    U8 o;
    #pragma unroll
    for (int j = 0; j < 8; ++j) o.u[j] = f2bu(wa2[row * 1024 + col + j]);
    *reinterpret_cast<s16x8*>(W2s + (size_t)g * 8) = o.v;
}

__global__ __launch_bounds__(256) void prep_wp2(
    const float* __restrict__ wp2, unsigned short* __restrict__ WP2s)
{
    int g = blockIdx.x * 256 + threadIdx.x;          // 2048
    int mt = g >> 7, ks = (g >> 6) & 1, lane = g & 63;
    int row = mt * 16 + (lane & 15);
    int col = ks * 32 + (lane >> 4) * 8;
    U8 o;
    #pragma unroll
    for (int j = 0; j < 8; ++j) o.u[j] = f2bu(wp2[row * 64 + col + j]);
    *reinterpret_cast<s16x8*>(WP2s + (size_t)g * 8) = o.v;
}

// ---------------- K1: projection GEMM -> bf16 transposed  YT[b][n][d]
__global__ __launch_bounds__(256) void proj_gemmT(
    const float* __restrict__ W, const float* __restrict__ bias,
    const float* __restrict__ X, unsigned short* __restrict__ YT, int Ncols)
{
    __shared__ float sW[16][64];
    __shared__ float sX[16][64];
    int b  = blockIdx.z;
    int d0 = blockIdx.y * 64;
    int n0 = blockIdx.x * 64;
    int t  = threadIdx.x;
    int ty = t >> 4, tx = t & 15;
    float acc[4][4] = {};
    for (int k0 = 0; k0 < kCin; k0 += 16) {
        {
            int i = t >> 2, ks = (t & 3) * 4;
            float4 w4 = *reinterpret_cast<const float4*>(
                W + (size_t)(d0 + i) * kCin + k0 + ks);
            sW[ks + 0][i] = w4.x; sW[ks + 1][i] = w4.y;
            sW[ks + 2][i] = w4.z; sW[ks + 3][i] = w4.w;
        }
        {
            int r = t >> 4, cs = (t & 15) * 4;
            float4 x4 = *reinterpret_cast<const float4*>(
                X + ((size_t)b * kCin + k0 + r) * Ncols + n0 + cs);
            *reinterpret_cast<float4*>(&sX[r][cs]) = x4;
        }
        __syncthreads();
        #pragma unroll
        for (int kk = 0; kk < 16; ++kk) {
            float4 av = *reinterpret_cast<const float4*>(&sW[kk][ty * 4]);
            float4 bv = *reinterpret_cast<const float4*>(&sX[kk][tx * 4]);
            float a[4] = {av.x, av.y, av.z, av.w};
            float bb[4] = {bv.x, bv.y, bv.z, bv.w};
            #pragma unroll
            for (int i = 0; i < 4; ++i)
                #pragma unroll
                for (int j = 0; j < 4; ++j)
                    acc[i][j] = fmaf(a[i], bb[j], acc[i][j]);
        }
        __syncthreads();
    }
    float bi[4];
    #pragma unroll
    for (int i = 0; i < 4; ++i) bi[i] = bias[d0 + ty * 4 + i];
    #pragma unroll
    for (int j = 0; j < 4; ++j) {
        int n = n0 + tx * 4 + j;
        ushort4 pk;
        pk.x = f2bu(acc[0][j] + bi[0]);
        pk.y = f2bu(acc[1][j] + bi[1]);
        pk.z = f2bu(acc[2][j] + bi[2]);
        pk.w = f2bu(acc[3][j] + bi[3]);
        *reinterpret_cast<ushort4*>(
            &YT[((size_t)b * Ncols + n) * 256 + d0 + ty * 4]) = pk;
    }
}

// ---------------- K2: KNN, wave-per-query (unchanged, passed)
__global__ __launch_bounds__(256) void knn2(
    const float* __restrict__ query_pos, const float* __restrict__ key_pos,
    int* __restrict__ idx_out)
{
    __shared__ float4 sk[kNk];
    int gq0 = blockIdx.x * 4;
    int b = gq0 >> 11;
    for (int m = threadIdx.x; m < kNk; m += 256) {
        float x = key_pos[((size_t)b * 3 + 0) * kNk + m];
        float y = key_pos[((size_t)b * 3 + 1) * kNk + m];
        float z = key_pos[((size_t)b * 3 + 2) * kNk + m];
        float kk = __fadd_rn(__fadd_rn(__fmul_rn(x, x), __fmul_rn(y, y)), __fmul_rn(z, z));
        sk[m] = make_float4(x, y, z, kk);
    }
    __syncthreads();
    int w = threadIdx.x >> 6, lane = threadIdx.x & 63;
    int gq = gq0 + w;
    int q = gq & 2047;
    float qx = query_pos[((size_t)b * 3 + 0) * kNq + q];
    float qy = query_pos[((size_t)b * 3 + 1) * kNq + q];
    float qz = query_pos[((size_t)b * 3 + 2) * kNq + q];
    float qq = __fadd_rn(__fadd_rn(__fmul_rn(qx, qx), __fmul_rn(qy, qy)), __fmul_rn(qz, qz));
    float td[kK]; int ti[kK];
    #pragma unroll
    for (int i = 0; i < kK; ++i) { td[i] = 3.4e38f; ti[i] = 0x7fffffff; }
    #pragma unroll 1
    for (int i = 0; i < 32; ++i) {
        int m = i * 64 + lane;
        float4 kv = sk[m];
        float dot = __fadd_rn(__fadd_rn(__fmul_rn(qx, kv.x), __fmul_rn(qy, kv.y)),
                              __fmul_rn(qz, kv.z));
        float d = __fsub_rn(__fadd_rn(qq, kv.w), __fmul_rn(2.0f, dot));
        bool better = (d < td[kK - 1]) || (d == td[kK - 1] && m < ti[kK - 1]);
        if (better) {
            td[kK - 1] = d; ti[kK - 1] = m;
            #pragma unroll
            for (int s = kK - 1; s > 0; --s) {
                bool sw = (td[s] < td[s - 1]) || (td[s] == td[s - 1] && ti[s] < ti[s - 1]);
                if (sw) {
                    float tf = td[s]; td[s] = td[s - 1]; td[s - 1] = tf;
                    int tt = ti[s]; ti[s] = ti[s - 1]; ti[s - 1] = tt;
                }
            }
        }
    }
    int outi = 0;
    #pragma unroll 1
    for (int r = 0; r < kK; ++r) {
        float dmin = td[0]; int imin = ti[0];
        #pragma unroll
        for (int msk = 1; msk < 64; msk <<= 1) {
            float od = __shfl_xor(dmin, msk);
            int   oi = __shfl_xor(imin, msk);
            if (od < dmin || (od == dmin && oi < imin)) { dmin = od; imin = oi; }
        }
        if (ti[0] == imin) {
            #pragma unroll
            for (int s = 0; s < kK - 1; ++s) { td[s] = td[s + 1]; ti[s] = ti[s + 1]; }
            td[kK - 1] = 3.4e38f; ti[kK - 1] = 0x7fffffff;
        }
        if (lane == r) outi = imin;
    }
    if (lane < 16) idx_out[((size_t)gq << 4) + lane] = outi;
}

// ---------------- K3: GEMM-shaped MFMA attention. 8 queries (128 cols) per 512-thread block.
// 1 block/CU (147KB LDS) -> 2 waves/SIMD -> 256 TOTAL regs/wave (arch+acc unified).
// AGPR demand: acc2(64) + a1h(32, halved W1 tile) = 96 -> arch budget 160, live ~90: no spill.
// (r10: a1[4][4]=64 AGPR pushed AGPR to 128, arch capped at 128 < ~150 live -> 261MB spill.)
__global__ __launch_bounds__(512, 2) void attn_mfma2(
    const float* __restrict__ qpos, const float* __restrict__ kpos,
    const unsigned short* __restrict__ qTb, const unsigned short* __restrict__ kTb,
    const unsigned short* __restrict__ vTb, const int* __restrict__ idxb,
    const float* __restrict__ wp1, const float* __restrict__ bp1,
    const float* __restrict__ g1, const float* __restrict__ be1,
    const float* __restrict__ m1, const float* __restrict__ v1,
    const unsigned short* __restrict__ WP2s, const float* __restrict__ bp2,
    const unsigned short* __restrict__ W1s, const float* __restrict__ b1p,
    const unsigned short* __restrict__ W2s,
    float* __restrict__ aggT)
{
    __shared__ __align__(16) char sm[147456];
    char* peB = sm;                 // 16384 B  (valid for entire kernel)
    char* XB  = sm + 16384;         // 65536 B
    char* HB  = sm + 16384 + 65536; // 65536 B

    const int tid = threadIdx.x;
    const int gq0 = blockIdx.x * 8;
    const int b = gq0 >> 11;

    // ---- phase 1: pe = relu(bn1(wp1 . rel + bp1)) for 128 cols x 64 h
    {
        int col = tid >> 2, qq = tid & 3;
        int qi = col >> 4, kn = col & 15;
        int gq = gq0 + qi, q = gq & 2047;
        int mm = idxb[((size_t)gq << 4) + kn];
        float rx = qpos[((size_t)b * 3 + 0) * kNq + q] - kpos[((size_t)b * 3 + 0) * kNk + mm];
        float ry = qpos[((size_t)b * 3 + 1) * kNq + q] - kpos[((size_t)b * 3 + 1) * kNk + mm];
        float rz = qpos[((size_t)b * 3 + 2) * kNq + q] - kpos[((size_t)b * 3 + 2) * kNk + mm];
        int swz = (col & 7) << 4;
        U8 o0, o1;
        #pragma unroll
        for (int i = 0; i < 16; ++i) {
            int h = qq * 16 + i;
            float iv = g1[h] * (1.0f / sqrtf(v1[h] + EPSF));
            float pre = bp1[h] + wp1[h * 3 + 0] * rx + wp1[h * 3 + 1] * ry + wp1[h * 3 + 2] * rz;
            float pe = fmaxf(pre * iv + (be1[h] - m1[h] * iv), 0.0f);
            if (i < 8) o0.u[i] = f2bu(pe); else o1.u[i - 8] = f2bu(pe);
        }
        *reinterpret_cast<s16x8*>(peB + ((col * 128 + qq * 32) ^ swz)) = o0.v;
        *reinterpret_cast<s16x8*>(peB + ((col * 128 + qq * 32 + 16) ^ swz)) = o1.v;
    }
    __syncthreads();

    const int w = tid >> 6, lane = tid & 63;
    const int lo = lane & 15, hi = lane >> 4;
    const int w4 = w & 3, grp = w >> 2;
    const int colbase = grp * 64;
    const int col0 = colbase + lo;
    const int swzb = (lo & 7) << 4;

    // ---- phase 3: pos_emb (MFMA) -> X (LDS). All temporaries scoped (die before main loop).
    {
        size_t krow[4];
        #pragma unroll
        for (int nt = 0; nt < 4; ++nt) {
            int mm = idxb[((size_t)(gq0 + grp * 4 + nt) << 4) + lo];
            krow[nt] = ((size_t)(b * kNk) + mm) * 256;
        }
        s16x8 pb[4][2];
        #pragma unroll
        for (int nt = 0; nt < 4; ++nt) {
            int cb = (col0 + nt * 16) * 128;
            pb[nt][0] = *reinterpret_cast<const s16x8*>(peB + ((cb + 0  + hi * 16) ^ swzb));
            pb[nt][1] = *reinterpret_cast<const s16x8*>(peB + ((cb + 64 + hi * 16) ^ swzb));
        }
        #pragma unroll
        for (int ml = 0; ml < 4; ++ml) {
            int mt = w4 * 4 + ml;
            s16x8 wA0 = *reinterpret_cast<const s16x8*>(WP2s + ((size_t)((mt * 2 + 0) * 64 + lane)) * 8);
            s16x8 wA1 = *reinterpret_cast<const s16x8*>(WP2s + ((size_t)((mt * 2 + 1) * 64 + lane)) * 8);
            int c0 = mt * 16 + hi * 4;
            float4 bp2v = *reinterpret_cast<const float4*>(bp2 + c0);
            #pragma unroll
            for (int nt = 0; nt < 4; ++nt) {
                f32x4 acc = {0.f, 0.f, 0.f, 0.f};
                acc = __builtin_amdgcn_mfma_f32_16x16x32_bf16(wA0, pb[nt][0], acc, 0, 0, 0);
                acc = __builtin_amdgcn_mfma_f32_16x16x32_bf16(wA1, pb[nt][1], acc, 0, 0, 0);
                size_t qrow = (size_t)(gq0 + grp * 4 + nt) * 256;
                U4 q4, k4, x4;
                q4.v = *reinterpret_cast<const ushort4*>(qTb + qrow + c0);
                k4.v = *reinterpret_cast<const ushort4*>(kTb + krow[nt] + c0);
                x4.u[0] = f2bu((bu2f(q4.u[0]) - bu2f(k4.u[0])) + (acc[0] + bp2v.x));
                x4.u[1] = f2bu((bu2f(q4.u[1]) - bu2f(k4.u[1])) + (acc[1] + bp2v.y));
                x4.u[2] = f2bu((bu2f(q4.u[2]) - bu2f(k4.u[2])) + (acc[2] + bp2v.z));
                x4.u[3] = f2bu((bu2f(q4.u[3]) - bu2f(k4.u[3])) + (acc[3] + bp2v.w));
                *reinterpret_cast<ushort4*>(XB + (((col0 + nt * 16) * 512 + c0 * 2) ^ swzb)) = x4.v;
            }
        }
    }
    __syncthreads();

    // ---- main loop: 4 chunks of 256 hidden rows
    f32x4 acc2[4][4];
    #pragma unroll
    for (int i = 0; i < 4; ++i)
        #pragma unroll
        for (int j = 0; j < 4; ++j) acc2[i][j] = (f32x4){0.f, 0.f, 0.f, 0.f};

    #pragma unroll 1
    for (int ch = 0; ch < 4; ++ch) {
        // W1 phase, split into 2 ml-halves so only a1h[2][4] (32 acc regs) is live at once
        #pragma unroll
        for (int mh = 0; mh < 2; ++mh) {
            f32x4 a1h[2][4];
            #pragma unroll
            for (int i = 0; i < 2; ++i)
                #pragma unroll
                for (int j = 0; j < 4; ++j) a1h[i][j] = (f32x4){0.f, 0.f, 0.f, 0.f};
            #pragma unroll
            for (int ks = 0; ks < 8; ++ks) {
                s16x8 xb[4];
                #pragma unroll
                for (int nt = 0; nt < 4; ++nt)
                    xb[nt] = *reinterpret_cast<const s16x8*>(
                        XB + (((col0 + nt * 16) * 512 + ks * 64 + hi * 16) ^ swzb));
                s16x8 aA[2];
                #pragma unroll
                for (int mi = 0; mi < 2; ++mi)
                    aA[mi] = *reinterpret_cast<const s16x8*>(
                        W1s + ((size_t)(((ch * 16 + w4 * 4 + mh * 2 + mi) * 8 + ks) * 64 + lane)) * 8);
                #pragma unroll
                for (int mi = 0; mi < 2; ++mi)
                    #pragma unroll
                    for (int nt = 0; nt < 4; ++nt)
                        a1h[mi][nt] = __builtin_amdgcn_mfma_f32_16x16x32_bf16(
                            aA[mi], xb[nt], a1h[mi][nt], 0, 0, 0);
            }
            #pragma unroll
            for (int mi = 0; mi < 2; ++mi) {
                int hloc = (w4 * 4 + mh * 2 + mi) * 16 + hi * 4;
                float4 b4 = *reinterpret_cast<const float4*>(b1p + ch * 256 + hloc);
                #pragma unroll
                for (int nt = 0; nt < 4; ++nt) {
                    U4 hp;
                    hp.u[0] = f2bu(fmaxf(a1h[mi][nt][0] + b4.x, 0.f));
                    hp.u[1] = f2bu(fmaxf(a1h[mi][nt][1] + b4.y, 0.f));
                    hp.u[2] = f2bu(fmaxf(a1h[mi][nt][2] + b4.z, 0.f));
                    hp.u[3] = f2bu(fmaxf(a1h[mi][nt][3] + b4.w, 0.f));
                    *reinterpret_cast<ushort4*>(
                        HB + (((col0 + nt * 16) * 512 + hloc * 2) ^ swzb)) = hp.v;
                }
            }
        }
        __syncthreads();
        #pragma unroll
        for (int kl = 0; kl < 8; ++kl) {
            s16x8 hb[4];
            #pragma unroll
            for (int nt = 0; nt < 4; ++nt)
                hb[nt] = *reinterpret_cast<const s16x8*>(
                    HB + (((col0 + nt * 16) * 512 + kl * 64 + hi * 16) ^ swzb));
            s16x8 aW[4];
            #pragma unroll
            for (int m2 = 0; m2 < 4; ++m2)
                aW[m2] = *reinterpret_cast<const s16x8*>(
                    W2s + ((size_t)(((w4 * 4 + m2) * 32 + ch * 8 + kl) * 64 + lane)) * 8);
            #pragma unroll
            for (int m2 = 0; m2 < 4; ++m2)
                #pragma unroll
                for (int nt = 0; nt < 4; ++nt)
                    acc2[m2][nt] = __builtin_amdgcn_mfma_f32_16x16x32_bf16(
                        aW[m2], hb[nt], acc2[m2][nt], 0, 0, 0);
        }
        __syncthreads();
    }

    // ---- epilogue: recompute pos_emb from peB (still valid), vwp = v + pe in f32,
    //      softmax over k (lo lanes) + aggregate, store f32
    #pragma unroll
    for (int m2 = 0; m2 < 4; ++m2) {
        int mt = w4 * 4 + m2;
        s16x8 wA0 = *reinterpret_cast<const s16x8*>(WP2s + ((size_t)((mt * 2 + 0) * 64 + lane)) * 8);
        s16x8 wA1 = *reinterpret_cast<const s16x8*>(WP2s + ((size_t)((mt * 2 + 1) * 64 + lane)) * 8);
        int c0 = mt * 16 + hi * 4;
        float4 bp2v = *reinterpret_cast<const float4*>(bp2 + c0);
        #pragma unroll
        for (int nt = 0; nt < 4; ++nt) {
            int cb = (col0 + nt * 16) * 128;
            s16x8 pb0 = *reinterpret_cast<const s16x8*>(peB + ((cb + 0  + hi * 16) ^ swzb));
            s16x8 pb1 = *reinterpret_cast<const s16x8*>(peB + ((cb + 64 + hi * 16) ^ swzb));
            f32x4 pa = {0.f, 0.f, 0.f, 0.f};
            pa = __builtin_amdgcn_mfma_f32_16x16x32_bf16(wA0, pb0, pa, 0, 0, 0);
            pa = __builtin_amdgcn_mfma_f32_16x16x32_bf16(wA1, pb1, pa, 0, 0, 0);
            int mm = idxb[((size_t)(gq0 + grp * 4 + nt) << 4) + lo];
            U4 v4;
            v4.v = *reinterpret_cast<const ushort4*>(
                vTb + ((size_t)(b * kNk) + mm) * 256 + c0);
            float pe4[4] = {pa[0] + bp2v.x, pa[1] + bp2v.y, pa[2] + bp2v.z, pa[3] + bp2v.w};
            size_t qrow = (size_t)(gq0 + grp * 4 + nt) * 256;
            #pragma unroll
            for (int r = 0; r < 4; ++r) {
                float a = acc2[m2][nt][r];
                float mx = a;
                mx = fmaxf(mx, __shfl_xor(mx, 1));
                mx = fmaxf(mx, __shfl_xor(mx, 2));
                mx = fmaxf(mx, __shfl_xor(mx, 4));
                mx = fmaxf(mx, __shfl_xor(mx, 8));
                float e = __expf(a - mx);
                float smv = e;
                smv += __shfl_xor(smv, 1); smv += __shfl_xor(smv, 2);
                smv += __shfl_xor(smv, 4); smv += __shfl_xor(smv, 8);
                float vwp = bu2f(v4.u[r]) + pe4[r];
                float p = e * vwp;
                p += __shfl_xor(p, 1); p += __shfl_xor(p, 2);
                p += __shfl_xor(p, 4); p += __shfl_xor(p, 8);
                if (lo == 0) aggT[qrow + c0 + r] = p / smv;
            }
        }
    }
}

// ---------------- K4: y = we . agg + bE + identity  (f32 out)
__global__ __launch_bounds__(256) void final_gemm(
    const float* __restrict__ we, const float* __restrict__ bE,
    const float* __restrict__ aggT, const float* __restrict__ identity,
    float* __restrict__ out)
{
    __shared__ float sA[16][64];
    __shared__ float sB[16][64];
    int b  = blockIdx.z;
    int c0 = blockIdx.y * 64;
    int n0 = blockIdx.x * 64;
    int t  = threadIdx.x;
    int ty = t >> 4, tx = t & 15;
    float acc[4][4] = {};
    for (int k0 = 0; k0 < kDim; k0 += 16) {
        {
            int i = t >> 2, ks = (t & 3) * 4;
            float4 w4 = *reinterpret_cast<const float4*>(
                we + (size_t)(c0 + i) * kDim + k0 + ks);
            sA[ks + 0][i] = w4.x; sA[ks + 1][i] = w4.y;
            sA[ks + 2][i] = w4.z; sA[ks + 3][i] = w4.w;
        }
        {
            int j = t >> 2, ks = (t & 3) * 4;
            float4 v = *reinterpret_cast<const float4*>(
                &aggT[((size_t)b * kNq + n0 + j) * kDim + k0 + ks]);
            sB[ks + 0][j] = v.x; sB[ks + 1][j] = v.y;
            sB[ks + 2][j] = v.z; sB[ks + 3][j] = v.w;
        }
        __syncthreads();
        #pragma unroll
        for (int kk = 0; kk < 16; ++kk) {
            float4 av = *reinterpret_cast<const float4*>(&sA[kk][ty * 4]);
            float4 bv = *reinterpret_cast<const float4*>(&sB[kk][tx * 4]);
            float a[4] = {av.x, av.y, av.z, av.w};
            float bb[4] = {bv.x, bv.y, bv.z, bv.w};
            #pragma unroll
            for (int i = 0; i < 4; ++i)
                #pragma unroll
                for (int j = 0; j < 4; ++j)
                    acc[i][j] = fmaf(a[i], bb[j], acc[i][j]);
        }
        __syncthreads();
    }
    #pragma unroll
    for (int i = 0; i < 4; ++i) {
        int c = c0 + ty * 4 + i;
        float bb = bE[c];
        size_t base = ((size_t)b * kCin + c) * kNq + n0 + tx * 4;
        #pragma unroll
        for (int j = 0; j < 4; ++j) {
            out[base + j] = acc[i][j] + bb + identity[base + j];
        }
    }
}

extern "C" void kernel_launch(void* const* d_in, const int* in_sizes, int n_in,
                              void* d_out, int out_size, void* d_ws, size_t ws_size,
                              hipStream_t stream) {
    const float* query_pos = (const float*)d_in[0];
    const float* query_feat= (const float*)d_in[1];
    const float* key_pos   = (const float*)d_in[2];
    const float* key_feat  = (const float*)d_in[3];
    const float* wq = (const float*)d_in[4];  const float* bq = (const float*)d_in[5];
    const float* wk = (const float*)d_in[6];  const float* bk = (const float*)d_in[7];
    const float* wv = (const float*)d_in[8];  const float* bv = (const float*)d_in[9];
    const float* wp1= (const float*)d_in[10]; const float* bp1= (const float*)d_in[11];
    const float* g1 = (const float*)d_in[12]; const float* be1= (const float*)d_in[13];
    const float* m1 = (const float*)d_in[14]; const float* v1 = (const float*)d_in[15];
    const float* wp2= (const float*)d_in[16]; const float* bp2= (const float*)d_in[17];
    const float* wa1= (const float*)d_in[18]; const float* ba1= (const float*)d_in[19];
    const float* g2 = (const float*)d_in[20]; const float* be2= (const float*)d_in[21];
    const float* m2 = (const float*)d_in[22]; const float* v2 = (const float*)d_in[23];
    const float* wa2= (const float*)d_in[24]; const float* ba2= (const float*)d_in[25];
    const float* we = (const float*)d_in[26]; const float* bE = (const float*)d_in[27];
    (void)ba2; // constant over k -> cancels in softmax

    float* wsf  = (float*)d_ws;
    float* aggT = wsf;                                   // 2M f32
    float* b1p  = aggT + 2097152;                        // 1024
    int*   idxb = (int*)(b1p + 1024);                    // 131072
    unsigned short* qTb = (unsigned short*)(idxb + 131072);  // 2M u16
    unsigned short* kTb = qTb + 2097152;
    unsigned short* vTb = kTb + 2097152;
    unsigned short* W1s = vTb + 2097152;                 // 262144 u16
    unsigned short* W2s = W1s + 262144;                  // 262144 u16
    unsigned short* WP2s= W2s + 262144;                  // 16384 u16

    dim3 blk(256);
    prep_w1<<<dim3(128), blk, 0, stream>>>(wa1, ba1, g2, be2, m2, v2, W1s, b1p);
    prep_w2<<<dim3(128), blk, 0, stream>>>(wa2, W2s);
    prep_wp2<<<dim3(8), blk, 0, stream>>>(wp2, WP2s);
    proj_gemmT<<<dim3(kNq / 64, kDim / 64, kB), blk, 0, stream>>>(wq, bq, query_feat, qTb, kNq);
    proj_gemmT<<<dim3(kNk / 64, kDim / 64, kB), blk, 0, stream>>>(wk, bk, key_feat, kTb, kNk);
    proj_gemmT<<<dim3(kNk / 64, kDim / 64, kB), blk, 0, stream>>>(wv, bv, key_feat, vTb, kNk);
    knn2<<<dim3(kB * kNq / 4), blk, 0, stream>>>(query_pos, key_pos, idxb);
    attn_mfma2<<<dim3(kB * kNq / 8), dim3(512), 0, stream>>>(query_pos, key_pos,
        qTb, kTb, vTb, idxb,
        wp1, bp1, g1, be1, m1, v1, WP2s, bp2, W1s, b1p, W2s, aggT);
    final_gemm<<<dim3(kNq / 64, kCin / 64, kB), blk, 0, stream>>>(
        we, bE, aggT, query_feat, (float*)d_out);
}

// Round 12
// 619.892 us; speedup vs baseline: 10.4777x; 1.4316x over previous
//
#include <hip/hip_runtime.h>
#include <hip/hip_bf16.h>

typedef __attribute__((ext_vector_type(8))) short s16x8;
typedef __attribute__((ext_vector_type(4))) float f32x4;

constexpr int kB   = 4;
constexpr int kCin = 256;
constexpr int kDim = 256;
constexpr int kNq  = 2048;
constexpr int kNk  = 2048;
constexpr int kK   = 16;
constexpr int kPosH= 64;
constexpr int kHid = 1024;
#define EPSF 1e-5f

__device__ __forceinline__ unsigned short f2bu(float f) {
    __hip_bfloat16 h = __float2bfloat16(f);
    return *reinterpret_cast<unsigned short*>(&h);
}
__device__ __forceinline__ float bu2f(unsigned short u) {
    union { unsigned int i; float f; } x; x.i = ((unsigned int)u) << 16; return x.f;
}

union U8 { s16x8 v; short s[8]; unsigned short u[8]; };
union U4 { ushort4 v; unsigned short u[4]; };

// ---------------- prep: W1' = wa1 * inv2 (bn2 folded), bf16 A-frag layout; b1' = ba1*inv2+sh2
__global__ __launch_bounds__(256) void prep_w1(
    const float* __restrict__ wa1, const float* __restrict__ ba1,
    const float* __restrict__ g2, const float* __restrict__ be2,
    const float* __restrict__ m2, const float* __restrict__ v2,
    unsigned short* __restrict__ W1s, float* __restrict__ b1p)
{
    int g = blockIdx.x * 256 + threadIdx.x;          // 32768 frag-lanes
    int mt = g >> 9, ks = (g >> 6) & 7, lane = g & 63;
    int row = mt * 16 + (lane & 15);
    int col = ks * 32 + (lane >> 4) * 8;
    float iv = g2[row] * (1.0f / sqrtf(v2[row] + EPSF));
    U8 o;
    #pragma unroll
    for (int j = 0; j < 8; ++j) o.u[j] = f2bu(wa1[row * 256 + col + j] * iv);
    *reinterpret_cast<s16x8*>(W1s + (size_t)g * 8) = o.v;
    if (ks == 0 && (lane >> 4) == 0)
        b1p[row] = ba1[row] * iv + (be2[row] - m2[row] * iv);
}

__global__ __launch_bounds__(256) void prep_w2(
    const float* __restrict__ wa2, unsigned short* __restrict__ W2s)
{
    int g = blockIdx.x * 256 + threadIdx.x;          // 32768
    int mt = g >> 11, ks = (g >> 6) & 31, lane = g & 63;
    int row = mt * 16 + (lane & 15);
    int col = ks * 32 + (lane >> 4) * 8;
    U8 o;
    #pragma unroll
    for (int j = 0; j < 8; ++j) o.u[j] = f2bu(wa2[row * 1024 + col + j]);
    *reinterpret_cast<s16x8*>(W2s + (size_t)g * 8) = o.v;
}

__global__ __launch_bounds__(256) void prep_wp2(
    const float* __restrict__ wp2, unsigned short* __restrict__ WP2s)
{
    int g = blockIdx.x * 256 + threadIdx.x;          // 2048
    int mt = g >> 7, ks = (g >> 6) & 1, lane = g & 63;
    int row = mt * 16 + (lane & 15);
    int col = ks * 32 + (lane >> 4) * 8;
    U8 o;
    #pragma unroll
    for (int j = 0; j < 8; ++j) o.u[j] = f2bu(wp2[row * 64 + col + j]);
    *reinterpret_cast<s16x8*>(WP2s + (size_t)g * 8) = o.v;
}

// ---------------- K1: projection GEMM -> bf16 transposed  YT[b][n][d]
__global__ __launch_bounds__(256) void proj_gemmT(
    const float* __restrict__ W, const float* __restrict__ bias,
    const float* __restrict__ X, unsigned short* __restrict__ YT, int Ncols)
{
    __shared__ float sW[16][64];
    __shared__ float sX[16][64];
    int b  = blockIdx.z;
    int d0 = blockIdx.y * 64;
    int n0 = blockIdx.x * 64;
    int t  = threadIdx.x;
    int ty = t >> 4, tx = t & 15;
    float acc[4][4] = {};
    for (int k0 = 0; k0 < kCin; k0 += 16) {
        {
            int i = t >> 2, ks = (t & 3) * 4;
            float4 w4 = *reinterpret_cast<const float4*>(
                W + (size_t)(d0 + i) * kCin + k0 + ks);
            sW[ks + 0][i] = w4.x; sW[ks + 1][i] = w4.y;
            sW[ks + 2][i] = w4.z; sW[ks + 3][i] = w4.w;
        }
        {
            int r = t >> 4, cs = (t & 15) * 4;
            float4 x4 = *reinterpret_cast<const float4*>(
                X + ((size_t)b * kCin + k0 + r) * Ncols + n0 + cs);
            *reinterpret_cast<float4*>(&sX[r][cs]) = x4;
        }
        __syncthreads();
        #pragma unroll
        for (int kk = 0; kk < 16; ++kk) {
            float4 av = *reinterpret_cast<const float4*>(&sW[kk][ty * 4]);
            float4 bv = *reinterpret_cast<const float4*>(&sX[kk][tx * 4]);
            float a[4] = {av.x, av.y, av.z, av.w};
            float bb[4] = {bv.x, bv.y, bv.z, bv.w};
            #pragma unroll
            for (int i = 0; i < 4; ++i)
                #pragma unroll
                for (int j = 0; j < 4; ++j)
                    acc[i][j] = fmaf(a[i], bb[j], acc[i][j]);
        }
        __syncthreads();
    }
    float bi[4];
    #pragma unroll
    for (int i = 0; i < 4; ++i) bi[i] = bias[d0 + ty * 4 + i];
    #pragma unroll
    for (int j = 0; j < 4; ++j) {
        int n = n0 + tx * 4 + j;
        ushort4 pk;
        pk.x = f2bu(acc[0][j] + bi[0]);
        pk.y = f2bu(acc[1][j] + bi[1]);
        pk.z = f2bu(acc[2][j] + bi[2]);
        pk.w = f2bu(acc[3][j] + bi[3]);
        *reinterpret_cast<ushort4*>(
            &YT[((size_t)b * Ncols + n) * 256 + d0 + ty * 4]) = pk;
    }
}

// ---------------- K2: KNN, wave-per-query (unchanged, passed)
__global__ __launch_bounds__(256) void knn2(
    const float* __restrict__ query_pos, const float* __restrict__ key_pos,
    int* __restrict__ idx_out)
{
    __shared__ float4 sk[kNk];
    int gq0 = blockIdx.x * 4;
    int b = gq0 >> 11;
    for (int m = threadIdx.x; m < kNk; m += 256) {
        float x = key_pos[((size_t)b * 3 + 0) * kNk + m];
        float y = key_pos[((size_t)b * 3 + 1) * kNk + m];
        float z = key_pos[((size_t)b * 3 + 2) * kNk + m];
        float kk = __fadd_rn(__fadd_rn(__fmul_rn(x, x), __fmul_rn(y, y)), __fmul_rn(z, z));
        sk[m] = make_float4(x, y, z, kk);
    }
    __syncthreads();
    int w = threadIdx.x >> 6, lane = threadIdx.x & 63;
    int gq = gq0 + w;
    int q = gq & 2047;
    float qx = query_pos[((size_t)b * 3 + 0) * kNq + q];
    float qy = query_pos[((size_t)b * 3 + 1) * kNq + q];
    float qz = query_pos[((size_t)b * 3 + 2) * kNq + q];
    float qq = __fadd_rn(__fadd_rn(__fmul_rn(qx, qx), __fmul_rn(qy, qy)), __fmul_rn(qz, qz));
    float td[kK]; int ti[kK];
    #pragma unroll
    for (int i = 0; i < kK; ++i) { td[i] = 3.4e38f; ti[i] = 0x7fffffff; }
    #pragma unroll 1
    for (int i = 0; i < 32; ++i) {
        int m = i * 64 + lane;
        float4 kv = sk[m];
        float dot = __fadd_rn(__fadd_rn(__fmul_rn(qx, kv.x), __fmul_rn(qy, kv.y)),
                              __fmul_rn(qz, kv.z));
        float d = __fsub_rn(__fadd_rn(qq, kv.w), __fmul_rn(2.0f, dot));
        bool better = (d < td[kK - 1]) || (d == td[kK - 1] && m < ti[kK - 1]);
        if (better) {
            td[kK - 1] = d; ti[kK - 1] = m;
            #pragma unroll
            for (int s = kK - 1; s > 0; --s) {
                bool sw = (td[s] < td[s - 1]) || (td[s] == td[s - 1] && ti[s] < ti[s - 1]);
                if (sw) {
                    float tf = td[s]; td[s] = td[s - 1]; td[s - 1] = tf;
                    int tt = ti[s]; ti[s] = ti[s - 1]; ti[s - 1] = tt;
                }
            }
        }
    }
    int outi = 0;
    #pragma unroll 1
    for (int r = 0; r < kK; ++r) {
        float dmin = td[0]; int imin = ti[0];
        #pragma unroll
        for (int msk = 1; msk < 64; msk <<= 1) {
            float od = __shfl_xor(dmin, msk);
            int   oi = __shfl_xor(imin, msk);
            if (od < dmin || (od == dmin && oi < imin)) { dmin = od; imin = oi; }
        }
        if (ti[0] == imin) {
            #pragma unroll
            for (int s = 0; s < kK - 1; ++s) { td[s] = td[s + 1]; ti[s] = ti[s + 1]; }
            td[kK - 1] = 3.4e38f; ti[kK - 1] = 0x7fffffff;
        }
        if (lane == r) outi = imin;
    }
    if (lane < 16) idx_out[((size_t)gq << 4) + lane] = outi;
}

// ---------------- K3: GEMM-shaped MFMA attention. 4 queries (64 cols) per 512-thread block.
// 8 waves = 4 row-groups (w4) x 2 col-groups (grp). Per wave acc2[4][2]=32 regs,
// a1h[2][2]=16 regs under a REAL '#pragma unroll 1' mh loop (r11's full-unroll merged the
// halves back -> spill). ks/kl loops unroll-2 to limit load-hoisting pressure.
// LDS 72KB -> 2 blocks/CU; __launch_bounds__(512,4) targets 128 regs/wave (demand ~110).
__global__ __launch_bounds__(512, 4) void attn_mfma3(
    const float* __restrict__ qpos, const float* __restrict__ kpos,
    const unsigned short* __restrict__ qTb, const unsigned short* __restrict__ kTb,
    const unsigned short* __restrict__ vTb, const int* __restrict__ idxb,
    const float* __restrict__ wp1, const float* __restrict__ bp1,
    const float* __restrict__ g1, const float* __restrict__ be1,
    const float* __restrict__ m1, const float* __restrict__ v1,
    const unsigned short* __restrict__ WP2s, const float* __restrict__ bp2,
    const unsigned short* __restrict__ W1s, const float* __restrict__ b1p,
    const unsigned short* __restrict__ W2s,
    float* __restrict__ aggT)
{
    __shared__ __align__(16) char sm[73728];
    char* peB = sm;                 // 8192 B  (64 cols x 128 B; valid all kernel)
    char* XB  = sm + 8192;          // 32768 B (64 cols x 512 B)
    char* HB  = sm + 8192 + 32768;  // 32768 B

    const int tid = threadIdx.x;
    const int gq0 = blockIdx.x * 4;
    const int b = gq0 >> 11;

    // ---- phase 1: pe = relu(bn1(wp1 . rel + bp1)) for 64 cols x 64 h (8 h per thread)
    {
        int col = tid >> 3, qq = tid & 7;
        int qi = col >> 4, kn = col & 15;
        int gq = gq0 + qi, q = gq & 2047;
        int mm = idxb[((size_t)gq << 4) + kn];
        float rx = qpos[((size_t)b * 3 + 0) * kNq + q] - kpos[((size_t)b * 3 + 0) * kNk + mm];
        float ry = qpos[((size_t)b * 3 + 1) * kNq + q] - kpos[((size_t)b * 3 + 1) * kNk + mm];
        float rz = qpos[((size_t)b * 3 + 2) * kNq + q] - kpos[((size_t)b * 3 + 2) * kNk + mm];
        int swz = (col & 7) << 4;
        U8 o0;
        #pragma unroll
        for (int i = 0; i < 8; ++i) {
            int h = qq * 8 + i;
            float iv = g1[h] * (1.0f / sqrtf(v1[h] + EPSF));
            float pre = bp1[h] + wp1[h * 3 + 0] * rx + wp1[h * 3 + 1] * ry + wp1[h * 3 + 2] * rz;
            float pe = fmaxf(pre * iv + (be1[h] - m1[h] * iv), 0.0f);
            o0.u[i] = f2bu(pe);
        }
        *reinterpret_cast<s16x8*>(peB + ((col * 128 + qq * 16) ^ swz)) = o0.v;
    }
    __syncthreads();

    const int w = tid >> 6, lane = tid & 63;
    const int lo = lane & 15, hi = lane >> 4;
    const int w4 = w & 3, grp = w >> 2;      // grp 0..1
    const int col0 = grp * 32 + lo;          // this lane's column for nt=0
    const int swzb = (lo & 7) << 4;          // == (col&7)<<4 (16/32 are mult of 8)

    // ---- phase 3: pos_emb (MFMA) -> X (LDS). Temporaries scoped.
    {
        size_t krow[2];
        #pragma unroll
        for (int nt = 0; nt < 2; ++nt) {
            int mm = idxb[((size_t)(gq0 + grp * 2 + nt) << 4) + lo];
            krow[nt] = ((size_t)(b * kNk) + mm) * 256;
        }
        s16x8 pb[2][2];
        #pragma unroll
        for (int nt = 0; nt < 2; ++nt) {
            int cb = (col0 + nt * 16) * 128;
            pb[nt][0] = *reinterpret_cast<const s16x8*>(peB + ((cb + 0  + hi * 16) ^ swzb));
            pb[nt][1] = *reinterpret_cast<const s16x8*>(peB + ((cb + 64 + hi * 16) ^ swzb));
        }
        #pragma unroll
        for (int ml = 0; ml < 4; ++ml) {
            int mt = w4 * 4 + ml;
            s16x8 wA0 = *reinterpret_cast<const s16x8*>(WP2s + ((size_t)((mt * 2 + 0) * 64 + lane)) * 8);
            s16x8 wA1 = *reinterpret_cast<const s16x8*>(WP2s + ((size_t)((mt * 2 + 1) * 64 + lane)) * 8);
            int c0 = mt * 16 + hi * 4;
            float4 bp2v = *reinterpret_cast<const float4*>(bp2 + c0);
            #pragma unroll
            for (int nt = 0; nt < 2; ++nt) {
                f32x4 acc = {0.f, 0.f, 0.f, 0.f};
                acc = __builtin_amdgcn_mfma_f32_16x16x32_bf16(wA0, pb[nt][0], acc, 0, 0, 0);
                acc = __builtin_amdgcn_mfma_f32_16x16x32_bf16(wA1, pb[nt][1], acc, 0, 0, 0);
                size_t qrow = (size_t)(gq0 + grp * 2 + nt) * 256;
                U4 q4, k4, x4;
                q4.v = *reinterpret_cast<const ushort4*>(qTb + qrow + c0);
                k4.v = *reinterpret_cast<const ushort4*>(kTb + krow[nt] + c0);
                x4.u[0] = f2bu((bu2f(q4.u[0]) - bu2f(k4.u[0])) + (acc[0] + bp2v.x));
                x4.u[1] = f2bu((bu2f(q4.u[1]) - bu2f(k4.u[1])) + (acc[1] + bp2v.y));
                x4.u[2] = f2bu((bu2f(q4.u[2]) - bu2f(k4.u[2])) + (acc[2] + bp2v.z));
                x4.u[3] = f2bu((bu2f(q4.u[3]) - bu2f(k4.u[3])) + (acc[3] + bp2v.w));
                *reinterpret_cast<ushort4*>(XB + (((col0 + nt * 16) * 512 + c0 * 2) ^ swzb)) = x4.v;
            }
        }
    }
    __syncthreads();

    // ---- main loop: 4 chunks of 256 hidden rows
    f32x4 acc2[4][2];
    #pragma unroll
    for (int i = 0; i < 4; ++i)
        #pragma unroll
        for (int j = 0; j < 2; ++j) acc2[i][j] = (f32x4){0.f, 0.f, 0.f, 0.f};

    #pragma unroll 1
    for (int ch = 0; ch < 4; ++ch) {
        // W1: 2 sequential mh halves, a1h[2][2]=16 regs live at a time
        #pragma unroll 1
        for (int mh = 0; mh < 2; ++mh) {
            f32x4 a1h[2][2];
            #pragma unroll
            for (int i = 0; i < 2; ++i)
                #pragma unroll
                for (int j = 0; j < 2; ++j) a1h[i][j] = (f32x4){0.f, 0.f, 0.f, 0.f};
            #pragma unroll 2
            for (int ks = 0; ks < 8; ++ks) {
                s16x8 xb[2];
                #pragma unroll
                for (int nt = 0; nt < 2; ++nt)
                    xb[nt] = *reinterpret_cast<const s16x8*>(
                        XB + (((col0 + nt * 16) * 512 + ks * 64 + hi * 16) ^ swzb));
                s16x8 aA[2];
                #pragma unroll
                for (int mi = 0; mi < 2; ++mi)
                    aA[mi] = *reinterpret_cast<const s16x8*>(
                        W1s + ((size_t)(((ch * 16 + w4 * 4 + mh * 2 + mi) * 8 + ks) * 64 + lane)) * 8);
                #pragma unroll
                for (int mi = 0; mi < 2; ++mi)
                    #pragma unroll
                    for (int nt = 0; nt < 2; ++nt)
                        a1h[mi][nt] = __builtin_amdgcn_mfma_f32_16x16x32_bf16(
                            aA[mi], xb[nt], a1h[mi][nt], 0, 0, 0);
            }
            #pragma unroll
            for (int mi = 0; mi < 2; ++mi) {
                int hloc = (w4 * 4 + mh * 2 + mi) * 16 + hi * 4;
                float4 b4 = *reinterpret_cast<const float4*>(b1p + ch * 256 + hloc);
                #pragma unroll
                for (int nt = 0; nt < 2; ++nt) {
                    U4 hp;
                    hp.u[0] = f2bu(fmaxf(a1h[mi][nt][0] + b4.x, 0.f));
                    hp.u[1] = f2bu(fmaxf(a1h[mi][nt][1] + b4.y, 0.f));
                    hp.u[2] = f2bu(fmaxf(a1h[mi][nt][2] + b4.z, 0.f));
                    hp.u[3] = f2bu(fmaxf(a1h[mi][nt][3] + b4.w, 0.f));
                    *reinterpret_cast<ushort4*>(
                        HB + (((col0 + nt * 16) * 512 + hloc * 2) ^ swzb)) = hp.v;
                }
            }
        }
        __syncthreads();
        #pragma unroll 2
        for (int kl = 0; kl < 8; ++kl) {
            s16x8 hb[2];
            #pragma unroll
            for (int nt = 0; nt < 2; ++nt)
                hb[nt] = *reinterpret_cast<const s16x8*>(
                    HB + (((col0 + nt * 16) * 512 + kl * 64 + hi * 16) ^ swzb));
            s16x8 aW[4];
            #pragma unroll
            for (int m2 = 0; m2 < 4; ++m2)
                aW[m2] = *reinterpret_cast<const s16x8*>(
                    W2s + ((size_t)(((w4 * 4 + m2) * 32 + ch * 8 + kl) * 64 + lane)) * 8);
            #pragma unroll
            for (int m2 = 0; m2 < 4; ++m2)
                #pragma unroll
                for (int nt = 0; nt < 2; ++nt)
                    acc2[m2][nt] = __builtin_amdgcn_mfma_f32_16x16x32_bf16(
                        aW[m2], hb[nt], acc2[m2][nt], 0, 0, 0);
        }
        __syncthreads();
    }

    // ---- epilogue: recompute pos_emb from peB, vwp = v + pe (f32), softmax + aggregate
    #pragma unroll
    for (int m2 = 0; m2 < 4; ++m2) {
        int mt = w4 * 4 + m2;
        s16x8 wA0 = *reinterpret_cast<const s16x8*>(WP2s + ((size_t)((mt * 2 + 0) * 64 + lane)) * 8);
        s16x8 wA1 = *reinterpret_cast<const s16x8*>(WP2s + ((size_t)((mt * 2 + 1) * 64 + lane)) * 8);
        int c0 = mt * 16 + hi * 4;
        float4 bp2v = *reinterpret_cast<const float4*>(bp2 + c0);
        #pragma unroll
        for (int nt = 0; nt < 2; ++nt) {
            int cb = (col0 + nt * 16) * 128;
            s16x8 pb0 = *reinterpret_cast<const s16x8*>(peB + ((cb + 0  + hi * 16) ^ swzb));
            s16x8 pb1 = *reinterpret_cast<const s16x8*>(peB + ((cb + 64 + hi * 16) ^ swzb));
            f32x4 pa = {0.f, 0.f, 0.f, 0.f};
            pa = __builtin_amdgcn_mfma_f32_16x16x32_bf16(wA0, pb0, pa, 0, 0, 0);
            pa = __builtin_amdgcn_mfma_f32_16x16x32_bf16(wA1, pb1, pa, 0, 0, 0);
            int mm = idxb[((size_t)(gq0 + grp * 2 + nt) << 4) + lo];
            U4 v4;
            v4.v = *reinterpret_cast<const ushort4*>(
                vTb + ((size_t)(b * kNk) + mm) * 256 + c0);
            float pe4[4] = {pa[0] + bp2v.x, pa[1] + bp2v.y, pa[2] + bp2v.z, pa[3] + bp2v.w};
            size_t qrow = (size_t)(gq0 + grp * 2 + nt) * 256;
            #pragma unroll
            for (int r = 0; r < 4; ++r) {
                float a = acc2[m2][nt][r];
                float mx = a;
                mx = fmaxf(mx, __shfl_xor(mx, 1));
                mx = fmaxf(mx, __shfl_xor(mx, 2));
                mx = fmaxf(mx, __shfl_xor(mx, 4));
                mx = fmaxf(mx, __shfl_xor(mx, 8));
                float e = __expf(a - mx);
                float smv = e;
                smv += __shfl_xor(smv, 1); smv += __shfl_xor(smv, 2);
                smv += __shfl_xor(smv, 4); smv += __shfl_xor(smv, 8);
                float vwp = bu2f(v4.u[r]) + pe4[r];
                float p = e * vwp;
                p += __shfl_xor(p, 1); p += __shfl_xor(p, 2);
                p += __shfl_xor(p, 4); p += __shfl_xor(p, 8);
                if (lo == 0) aggT[qrow + c0 + r] = p / smv;
            }
        }
    }
}

// ---------------- K4: y = we . agg + bE + identity  (f32 out)
__global__ __launch_bounds__(256) void final_gemm(
    const float* __restrict__ we, const float* __restrict__ bE,
    const float* __restrict__ aggT, const float* __restrict__ identity,
    float* __restrict__ out)
{
    __shared__ float sA[16][64];
    __shared__ float sB[16][64];
    int b  = blockIdx.z;
    int c0 = blockIdx.y * 64;
    int n0 = blockIdx.x * 64;
    int t  = threadIdx.x;
    int ty = t >> 4, tx = t & 15;
    float acc[4][4] = {};
    for (int k0 = 0; k0 < kDim; k0 += 16) {
        {
            int i = t >> 2, ks = (t & 3) * 4;
            float4 w4 = *reinterpret_cast<const float4*>(
                we + (size_t)(c0 + i) * kDim + k0 + ks);
            sA[ks + 0][i] = w4.x; sA[ks + 1][i] = w4.y;
            sA[ks + 2][i] = w4.z; sA[ks + 3][i] = w4.w;
        }
        {
            int j = t >> 2, ks = (t & 3) * 4;
            float4 v = *reinterpret_cast<const float4*>(
                &aggT[((size_t)b * kNq + n0 + j) * kDim + k0 + ks]);
            sB[ks + 0][j] = v.x; sB[ks + 1][j] = v.y;
            sB[ks + 2][j] = v.z; sB[ks + 3][j] = v.w;
        }
        __syncthreads();
        #pragma unroll
        for (int kk = 0; kk < 16; ++kk) {
            float4 av = *reinterpret_cast<const float4*>(&sA[kk][ty * 4]);
            float4 bv = *reinterpret_cast<const float4*>(&sB[kk][tx * 4]);
            float a[4] = {av.x, av.y, av.z, av.w};
            float bb[4] = {bv.x, bv.y, bv.z, bv.w};
            #pragma unroll
            for (int i = 0; i < 4; ++i)
                #pragma unroll
                for (int j = 0; j < 4; ++j)
                    acc[i][j] = fmaf(a[i], bb[j], acc[i][j]);
        }
        __syncthreads();
    }
    #pragma unroll
    for (int i = 0; i < 4; ++i) {
        int c = c0 + ty * 4 + i;
        float bb = bE[c];
        size_t base = ((size_t)b * kCin + c) * kNq + n0 + tx * 4;
        #pragma unroll
        for (int j = 0; j < 4; ++j) {
            out[base + j] = acc[i][j] + bb + identity[base + j];
        }
    }
}

extern "C" void kernel_launch(void* const* d_in, const int* in_sizes, int n_in,
                              void* d_out, int out_size, void* d_ws, size_t ws_size,
                              hipStream_t stream) {
    const float* query_pos = (const float*)d_in[0];
    const float* query_feat= (const float*)d_in[1];
    const float* key_pos   = (const float*)d_in[2];
    const float* key_feat  = (const float*)d_in[3];
    const float* wq = (const float*)d_in[4];  const float* bq = (const float*)d_in[5];
    const float* wk = (const float*)d_in[6];  const float* bk = (const float*)d_in[7];
    const float* wv = (const float*)d_in[8];  const float* bv = (const float*)d_in[9];
    const float* wp1= (const float*)d_in[10]; const float* bp1= (const float*)d_in[11];
    const float* g1 = (const float*)d_in[12]; const float* be1= (const float*)d_in[13];
    const float* m1 = (const float*)d_in[14]; const float* v1 = (const float*)d_in[15];
    const float* wp2= (const float*)d_in[16]; const float* bp2= (const float*)d_in[17];
    const float* wa1= (const float*)d_in[18]; const float* ba1= (const float*)d_in[19];
    const float* g2 = (const float*)d_in[20]; const float* be2= (const float*)d_in[21];
    const float* m2 = (const float*)d_in[22]; const float* v2 = (const float*)d_in[23];
    const float* wa2= (const float*)d_in[24]; const float* ba2= (const float*)d_in[25];
    const float* we = (const float*)d_in[26]; const float* bE = (const float*)d_in[27];
    (void)ba2; // constant over k -> cancels in softmax

    float* wsf  = (float*)d_ws;
    float* aggT = wsf;                                   // 2M f32
    float* b1p  = aggT + 2097152;                        // 1024
    int*   idxb = (int*)(b1p + 1024);                    // 131072
    unsigned short* qTb = (unsigned short*)(idxb + 131072);  // 2M u16
    unsigned short* kTb = qTb + 2097152;
    unsigned short* vTb = kTb + 2097152;
    unsigned short* W1s = vTb + 2097152;                 // 262144 u16
    unsigned short* W2s = W1s + 262144;                  // 262144 u16
    unsigned short* WP2s= W2s + 262144;                  // 16384 u16

    dim3 blk(256);
    prep_w1<<<dim3(128), blk, 0, stream>>>(wa1, ba1, g2, be2, m2, v2, W1s, b1p);
    prep_w2<<<dim3(128), blk, 0, stream>>>(wa2, W2s);
    prep_wp2<<<dim3(8), blk, 0, stream>>>(wp2, WP2s);
    proj_gemmT<<<dim3(kNq / 64, kDim / 64, kB), blk, 0, stream>>>(wq, bq, query_feat, qTb, kNq);
    proj_gemmT<<<dim3(kNk / 64, kDim / 64, kB), blk, 0, stream>>>(wk, bk, key_feat, kTb, kNk);
    proj_gemmT<<<dim3(kNk / 64, kDim / 64, kB), blk, 0, stream>>>(wv, bv, key_feat, vTb, kNk);
    knn2<<<dim3(kB * kNq / 4), blk, 0, stream>>>(query_pos, key_pos, idxb);
    attn_mfma3<<<dim3(kB * kNq / 4), dim3(512), 0, stream>>>(query_pos, key_pos,
        qTb, kTb, vTb, idxb,
        wp1, bp1, g1, be1, m1, v1, WP2s, bp2, W1s, b1p, W2s, aggT);
    final_gemm<<<dim3(kNq / 64, kCin / 64, kB), blk, 0, stream>>>(
        we, bE, aggT, query_feat, (float*)d_out);
}

// Round 13
// 616.726 us; speedup vs baseline: 10.5315x; 1.0051x over previous
//
#include <hip/hip_runtime.h>
#include <hip/hip_bf16.h>

typedef __attribute__((ext_vector_type(8))) short s16x8;
typedef __attribute__((ext_vector_type(4))) float f32x4;

constexpr int kB   = 4;
constexpr int kCin = 256;
constexpr int kDim = 256;
constexpr int kNq  = 2048;
constexpr int kNk  = 2048;
constexpr int kK   = 16;
constexpr int kPosH= 64;
constexpr int kHid = 1024;
#define EPSF 1e-5f

__device__ __forceinline__ unsigned short f2bu(float f) {
    __hip_bfloat16 h = __float2bfloat16(f);
    return *reinterpret_cast<unsigned short*>(&h);
}
__device__ __forceinline__ float bu2f(unsigned short u) {
    union { unsigned int i; float f; } x; x.i = ((unsigned int)u) << 16; return x.f;
}

union U8 { s16x8 v; short s[8]; unsigned short u[8]; };
union U4 { ushort4 v; unsigned short u[4]; };

// ---------------- prep: W1' = wa1 * inv2 (bn2 folded), bf16 A-frag layout; b1' = ba1*inv2+sh2
__global__ __launch_bounds__(256) void prep_w1(
    const float* __restrict__ wa1, const float* __restrict__ ba1,
    const float* __restrict__ g2, const float* __restrict__ be2,
    const float* __restrict__ m2, const float* __restrict__ v2,
    unsigned short* __restrict__ W1s, float* __restrict__ b1p)
{
    int g = blockIdx.x * 256 + threadIdx.x;          // 32768 frag-lanes
    int mt = g >> 9, ks = (g >> 6) & 7, lane = g & 63;
    int row = mt * 16 + (lane & 15);
    int col = ks * 32 + (lane >> 4) * 8;
    float iv = g2[row] * (1.0f / sqrtf(v2[row] + EPSF));
    U8 o;
    #pragma unroll
    for (int j = 0; j < 8; ++j) o.u[j] = f2bu(wa1[row * 256 + col + j] * iv);
    *reinterpret_cast<s16x8*>(W1s + (size_t)g * 8) = o.v;
    if (ks == 0 && (lane >> 4) == 0)
        b1p[row] = ba1[row] * iv + (be2[row] - m2[row] * iv);
}

__global__ __launch_bounds__(256) void prep_w2(
    const float* __restrict__ wa2, unsigned short* __restrict__ W2s)
{
    int g = blockIdx.x * 256 + threadIdx.x;          // 32768
    int mt = g >> 11, ks = (g >> 6) & 31, lane = g & 63;
    int row = mt * 16 + (lane & 15);
    int col = ks * 32 + (lane >> 4) * 8;
    U8 o;
    #pragma unroll
    for (int j = 0; j < 8; ++j) o.u[j] = f2bu(wa2[row * 1024 + col + j]);
    *reinterpret_cast<s16x8*>(W2s + (size_t)g * 8) = o.v;
}

__global__ __launch_bounds__(256) void prep_wp2(
    const float* __restrict__ wp2, unsigned short* __restrict__ WP2s)
{
    int g = blockIdx.x * 256 + threadIdx.x;          // 2048
    int mt = g >> 7, ks = (g >> 6) & 1, lane = g & 63;
    int row = mt * 16 + (lane & 15);
    int col = ks * 32 + (lane >> 4) * 8;
    U8 o;
    #pragma unroll
    for (int j = 0; j < 8; ++j) o.u[j] = f2bu(wp2[row * 64 + col + j]);
    *reinterpret_cast<s16x8*>(WP2s + (size_t)g * 8) = o.v;
}

// prep a 256x256 f32 weight into bf16 A-frag layout (16 mt x 8 ks x 64 lane x 8)
__global__ __launch_bounds__(256) void prep_wproj(
    const float* __restrict__ W, unsigned short* __restrict__ Ws)
{
    int g = blockIdx.x * 256 + threadIdx.x;          // 8192 frag-lanes
    int mt = g >> 9, ks = (g >> 6) & 7, lane = g & 63;
    int row = mt * 16 + (lane & 15);
    int col = ks * 32 + (lane >> 4) * 8;
    U8 o;
    #pragma unroll
    for (int j = 0; j < 8; ++j) o.u[j] = f2bu(W[row * 256 + col + j]);
    *reinterpret_cast<s16x8*>(Ws + (size_t)g * 8) = o.v;
}

// ---------------- K1: MFMA projection GEMM -> bf16 transposed YT[b][n][d]
// block 256 thr (4 waves): d-half (128 rows, 2 mt/wave), n tile 64. X staged bf16 in LDS.
__global__ __launch_bounds__(256) void proj_mfma(
    const unsigned short* __restrict__ Ws, const float* __restrict__ bias,
    const float* __restrict__ X, unsigned short* __restrict__ YT)
{
    __shared__ __align__(16) char XB2[32768];   // [64 n][256 c] bf16, byte ^ (n&7)<<4
    int t = threadIdx.x;
    int n0 = blockIdx.x * 64;
    int dblk = blockIdx.y;
    int b = blockIdx.z;
    #pragma unroll 4
    for (int pass = 0; pass < 16; ++pass) {
        int c = pass * 16 + (t >> 4);
        int nq = (t & 15) * 4;
        float4 v = *reinterpret_cast<const float4*>(
            X + ((size_t)b * 256 + c) * 2048 + n0 + nq);
        float vv[4] = {v.x, v.y, v.z, v.w};
        #pragma unroll
        for (int i = 0; i < 4; ++i) {
            int n = nq + i;
            *reinterpret_cast<unsigned short*>(
                XB2 + ((n * 512 + c * 2) ^ ((n & 7) << 4))) = f2bu(vv[i]);
        }
    }
    __syncthreads();
    int w = t >> 6, lane = t & 63;
    int lo = lane & 15, hi = lane >> 4;
    f32x4 acc[2][4];
    #pragma unroll
    for (int i = 0; i < 2; ++i)
        #pragma unroll
        for (int j = 0; j < 4; ++j) acc[i][j] = (f32x4){0.f, 0.f, 0.f, 0.f};
    #pragma unroll 2
    for (int ks = 0; ks < 8; ++ks) {
        s16x8 xb[4];
        #pragma unroll
        for (int nt = 0; nt < 4; ++nt)
            xb[nt] = *reinterpret_cast<const s16x8*>(
                XB2 + (((nt * 16 + lo) * 512 + ks * 64 + hi * 16) ^ ((lo & 7) << 4)));
        s16x8 aA[2];
        #pragma unroll
        for (int mi = 0; mi < 2; ++mi)
            aA[mi] = *reinterpret_cast<const s16x8*>(
                Ws + ((size_t)(((dblk * 8 + w * 2 + mi) * 8 + ks) * 64 + lane)) * 8);
        #pragma unroll
        for (int mi = 0; mi < 2; ++mi)
            #pragma unroll
            for (int nt = 0; nt < 4; ++nt)
                acc[mi][nt] = __builtin_amdgcn_mfma_f32_16x16x32_bf16(
                    aA[mi], xb[nt], acc[mi][nt], 0, 0, 0);
    }
    #pragma unroll
    for (int mi = 0; mi < 2; ++mi) {
        int d0 = (dblk * 8 + w * 2 + mi) * 16 + hi * 4;
        float4 bv = *reinterpret_cast<const float4*>(bias + d0);
        #pragma unroll
        for (int nt = 0; nt < 4; ++nt) {
            int n = n0 + nt * 16 + lo;
            U4 o;
            o.u[0] = f2bu(acc[mi][nt][0] + bv.x);
            o.u[1] = f2bu(acc[mi][nt][1] + bv.y);
            o.u[2] = f2bu(acc[mi][nt][2] + bv.z);
            o.u[3] = f2bu(acc[mi][nt][3] + bv.w);
            *reinterpret_cast<ushort4*>(
                YT + ((size_t)b * 2048 + n) * 256 + d0) = o.v;
        }
    }
}

// ---------------- K2: KNN, wave-per-query (unchanged, passed)
__global__ __launch_bounds__(256) void knn2(
    const float* __restrict__ query_pos, const float* __restrict__ key_pos,
    int* __restrict__ idx_out)
{
    __shared__ float4 sk[kNk];
    int gq0 = blockIdx.x * 4;
    int b = gq0 >> 11;
    for (int m = threadIdx.x; m < kNk; m += 256) {
        float x = key_pos[((size_t)b * 3 + 0) * kNk + m];
        float y = key_pos[((size_t)b * 3 + 1) * kNk + m];
        float z = key_pos[((size_t)b * 3 + 2) * kNk + m];
        float kk = __fadd_rn(__fadd_rn(__fmul_rn(x, x), __fmul_rn(y, y)), __fmul_rn(z, z));
        sk[m] = make_float4(x, y, z, kk);
    }
    __syncthreads();
    int w = threadIdx.x >> 6, lane = threadIdx.x & 63;
    int gq = gq0 + w;
    int q = gq & 2047;
    float qx = query_pos[((size_t)b * 3 + 0) * kNq + q];
    float qy = query_pos[((size_t)b * 3 + 1) * kNq + q];
    float qz = query_pos[((size_t)b * 3 + 2) * kNq + q];
    float qq = __fadd_rn(__fadd_rn(__fmul_rn(qx, qx), __fmul_rn(qy, qy)), __fmul_rn(qz, qz));
    float td[kK]; int ti[kK];
    #pragma unroll
    for (int i = 0; i < kK; ++i) { td[i] = 3.4e38f; ti[i] = 0x7fffffff; }
    #pragma unroll 1
    for (int i = 0; i < 32; ++i) {
        int m = i * 64 + lane;
        float4 kv = sk[m];
        float dot = __fadd_rn(__fadd_rn(__fmul_rn(qx, kv.x), __fmul_rn(qy, kv.y)),
                              __fmul_rn(qz, kv.z));
        float d = __fsub_rn(__fadd_rn(qq, kv.w), __fmul_rn(2.0f, dot));
        bool better = (d < td[kK - 1]) || (d == td[kK - 1] && m < ti[kK - 1]);
        if (better) {
            td[kK - 1] = d; ti[kK - 1] = m;
            #pragma unroll
            for (int s = kK - 1; s > 0; --s) {
                bool sw = (td[s] < td[s - 1]) || (td[s] == td[s - 1] && ti[s] < ti[s - 1]);
                if (sw) {
                    float tf = td[s]; td[s] = td[s - 1]; td[s - 1] = tf;
                    int tt = ti[s]; ti[s] = ti[s - 1]; ti[s - 1] = tt;
                }
            }
        }
    }
    int outi = 0;
    #pragma unroll 1
    for (int r = 0; r < kK; ++r) {
        float dmin = td[0]; int imin = ti[0];
        #pragma unroll
        for (int msk = 1; msk < 64; msk <<= 1) {
            float od = __shfl_xor(dmin, msk);
            int   oi = __shfl_xor(imin, msk);
            if (od < dmin || (od == dmin && oi < imin)) { dmin = od; imin = oi; }
        }
        if (ti[0] == imin) {
            #pragma unroll
            for (int s = 0; s < kK - 1; ++s) { td[s] = td[s + 1]; ti[s] = ti[s + 1]; }
            td[kK - 1] = 3.4e38f; ti[kK - 1] = 0x7fffffff;
        }
        if (lane == r) outi = imin;
    }
    if (lane < 16) idx_out[((size_t)gq << 4) + lane] = outi;
}

// ---------------- K3: GEMM-shaped MFMA attention. 8 queries (128 cols) per 512-thread block.
// r12's register discipline at r8's geometry: acc2[4][4]=64 AGPR, a1h[2][4]=32 AGPR under a
// real '#pragma unroll 1' mh loop; ks/kl unroll-2. (512,2) -> 256 total regs, demand ~200.
// Halves per-chunk weight L2 traffic vs the 64-col r12 shape (1024 blocks x 2MB = 2GB).
__global__ __launch_bounds__(512, 2) void attn_mfma4(
    const float* __restrict__ qpos, const float* __restrict__ kpos,
    const unsigned short* __restrict__ qTb, const unsigned short* __restrict__ kTb,
    const unsigned short* __restrict__ vTb, const int* __restrict__ idxb,
    const float* __restrict__ wp1, const float* __restrict__ bp1,
    const float* __restrict__ g1, const float* __restrict__ be1,
    const float* __restrict__ m1, const float* __restrict__ v1,
    const unsigned short* __restrict__ WP2s, const float* __restrict__ bp2,
    const unsigned short* __restrict__ W1s, const float* __restrict__ b1p,
    const unsigned short* __restrict__ W2s,
    float* __restrict__ aggT)
{
    __shared__ __align__(16) char sm[147456];
    char* peB = sm;                 // 16384 B  (128 cols x 128 B; valid all kernel)
    char* XB  = sm + 16384;         // 65536 B
    char* HB  = sm + 16384 + 65536; // 65536 B

    const int tid = threadIdx.x;
    const int gq0 = blockIdx.x * 8;
    const int b = gq0 >> 11;

    // ---- phase 1: pe = relu(bn1(wp1 . rel + bp1)) for 128 cols x 64 h
    {
        int col = tid >> 2, qq = tid & 3;
        int qi = col >> 4, kn = col & 15;
        int gq = gq0 + qi, q = gq & 2047;
        int mm = idxb[((size_t)gq << 4) + kn];
        float rx = qpos[((size_t)b * 3 + 0) * kNq + q] - kpos[((size_t)b * 3 + 0) * kNk + mm];
        float ry = qpos[((size_t)b * 3 + 1) * kNq + q] - kpos[((size_t)b * 3 + 1) * kNk + mm];
        float rz = qpos[((size_t)b * 3 + 2) * kNq + q] - kpos[((size_t)b * 3 + 2) * kNk + mm];
        int swz = (col & 7) << 4;
        U8 o0, o1;
        #pragma unroll
        for (int i = 0; i < 16; ++i) {
            int h = qq * 16 + i;
            float iv = g1[h] * (1.0f / sqrtf(v1[h] + EPSF));
            float pre = bp1[h] + wp1[h * 3 + 0] * rx + wp1[h * 3 + 1] * ry + wp1[h * 3 + 2] * rz;
            float pe = fmaxf(pre * iv + (be1[h] - m1[h] * iv), 0.0f);
            if (i < 8) o0.u[i] = f2bu(pe); else o1.u[i - 8] = f2bu(pe);
        }
        *reinterpret_cast<s16x8*>(peB + ((col * 128 + qq * 32) ^ swz)) = o0.v;
        *reinterpret_cast<s16x8*>(peB + ((col * 128 + qq * 32 + 16) ^ swz)) = o1.v;
    }
    __syncthreads();

    const int w = tid >> 6, lane = tid & 63;
    const int lo = lane & 15, hi = lane >> 4;
    const int w4 = w & 3, grp = w >> 2;      // grp 0..1
    const int col0 = grp * 64 + lo;
    const int swzb = (lo & 7) << 4;

    // ---- phase 3: pos_emb (MFMA) -> X (LDS). Temporaries scoped.
    {
        size_t krow[4];
        #pragma unroll
        for (int nt = 0; nt < 4; ++nt) {
            int mm = idxb[((size_t)(gq0 + grp * 4 + nt) << 4) + lo];
            krow[nt] = ((size_t)(b * kNk) + mm) * 256;
        }
        s16x8 pb[4][2];
        #pragma unroll
        for (int nt = 0; nt < 4; ++nt) {
            int cb = (col0 + nt * 16) * 128;
            pb[nt][0] = *reinterpret_cast<const s16x8*>(peB + ((cb + 0  + hi * 16) ^ swzb));
            pb[nt][1] = *reinterpret_cast<const s16x8*>(peB + ((cb + 64 + hi * 16) ^ swzb));
        }
        #pragma unroll
        for (int ml = 0; ml < 4; ++ml) {
            int mt = w4 * 4 + ml;
            s16x8 wA0 = *reinterpret_cast<const s16x8*>(WP2s + ((size_t)((mt * 2 + 0) * 64 + lane)) * 8);
            s16x8 wA1 = *reinterpret_cast<const s16x8*>(WP2s + ((size_t)((mt * 2 + 1) * 64 + lane)) * 8);
            int c0 = mt * 16 + hi * 4;
            float4 bp2v = *reinterpret_cast<const float4*>(bp2 + c0);
            #pragma unroll
            for (int nt = 0; nt < 4; ++nt) {
                f32x4 acc = {0.f, 0.f, 0.f, 0.f};
                acc = __builtin_amdgcn_mfma_f32_16x16x32_bf16(wA0, pb[nt][0], acc, 0, 0, 0);
                acc = __builtin_amdgcn_mfma_f32_16x16x32_bf16(wA1, pb[nt][1], acc, 0, 0, 0);
                size_t qrow = (size_t)(gq0 + grp * 4 + nt) * 256;
                U4 q4, k4, x4;
                q4.v = *reinterpret_cast<const ushort4*>(qTb + qrow + c0);
                k4.v = *reinterpret_cast<const ushort4*>(kTb + krow[nt] + c0);
                x4.u[0] = f2bu((bu2f(q4.u[0]) - bu2f(k4.u[0])) + (acc[0] + bp2v.x));
                x4.u[1] = f2bu((bu2f(q4.u[1]) - bu2f(k4.u[1])) + (acc[1] + bp2v.y));
                x4.u[2] = f2bu((bu2f(q4.u[2]) - bu2f(k4.u[2])) + (acc[2] + bp2v.z));
                x4.u[3] = f2bu((bu2f(q4.u[3]) - bu2f(k4.u[3])) + (acc[3] + bp2v.w));
                *reinterpret_cast<ushort4*>(XB + (((col0 + nt * 16) * 512 + c0 * 2) ^ swzb)) = x4.v;
            }
        }
    }
    __syncthreads();

    // ---- main loop: 4 chunks of 256 hidden rows
    f32x4 acc2[4][4];
    #pragma unroll
    for (int i = 0; i < 4; ++i)
        #pragma unroll
        for (int j = 0; j < 4; ++j) acc2[i][j] = (f32x4){0.f, 0.f, 0.f, 0.f};

    #pragma unroll 1
    for (int ch = 0; ch < 4; ++ch) {
        // W1: 2 sequential mh halves, a1h[2][4]=32 acc regs live at a time
        #pragma unroll 1
        for (int mh = 0; mh < 2; ++mh) {
            f32x4 a1h[2][4];
            #pragma unroll
            for (int i = 0; i < 2; ++i)
                #pragma unroll
                for (int j = 0; j < 4; ++j) a1h[i][j] = (f32x4){0.f, 0.f, 0.f, 0.f};
            #pragma unroll 2
            for (int ks = 0; ks < 8; ++ks) {
                s16x8 xb[4];
                #pragma unroll
                for (int nt = 0; nt < 4; ++nt)
                    xb[nt] = *reinterpret_cast<const s16x8*>(
                        XB + (((col0 + nt * 16) * 512 + ks * 64 + hi * 16) ^ swzb));
                s16x8 aA[2];
                #pragma unroll
                for (int mi = 0; mi < 2; ++mi)
                    aA[mi] = *reinterpret_cast<const s16x8*>(
                        W1s + ((size_t)(((ch * 16 + w4 * 4 + mh * 2 + mi) * 8 + ks) * 64 + lane)) * 8);
                #pragma unroll
                for (int mi = 0; mi < 2; ++mi)
                    #pragma unroll
                    for (int nt = 0; nt < 4; ++nt)
                        a1h[mi][nt] = __builtin_amdgcn_mfma_f32_16x16x32_bf16(
                            aA[mi], xb[nt], a1h[mi][nt], 0, 0, 0);
            }
            #pragma unroll
            for (int mi = 0; mi < 2; ++mi) {
                int hloc = (w4 * 4 + mh * 2 + mi) * 16 + hi * 4;
                float4 b4 = *reinterpret_cast<const float4*>(b1p + ch * 256 + hloc);
                #pragma unroll
                for (int nt = 0; nt < 4; ++nt) {
                    U4 hp;
                    hp.u[0] = f2bu(fmaxf(a1h[mi][nt][0] + b4.x, 0.f));
                    hp.u[1] = f2bu(fmaxf(a1h[mi][nt][1] + b4.y, 0.f));
                    hp.u[2] = f2bu(fmaxf(a1h[mi][nt][2] + b4.z, 0.f));
                    hp.u[3] = f2bu(fmaxf(a1h[mi][nt][3] + b4.w, 0.f));
                    *reinterpret_cast<ushort4*>(
                        HB + (((col0 + nt * 16) * 512 + hloc * 2) ^ swzb)) = hp.v;
                }
            }
        }
        __syncthreads();
        #pragma unroll 2
        for (int kl = 0; kl < 8; ++kl) {
            s16x8 hb[4];
            #pragma unroll
            for (int nt = 0; nt < 4; ++nt)
                hb[nt] = *reinterpret_cast<const s16x8*>(
                    HB + (((col0 + nt * 16) * 512 + kl * 64 + hi * 16) ^ swzb));
            s16x8 aW[4];
            #pragma unroll
            for (int m2 = 0; m2 < 4; ++m2)
                aW[m2] = *reinterpret_cast<const s16x8*>(
                    W2s + ((size_t)(((w4 * 4 + m2) * 32 + ch * 8 + kl) * 64 + lane)) * 8);
            #pragma unroll
            for (int m2 = 0; m2 < 4; ++m2)
                #pragma unroll
                for (int nt = 0; nt < 4; ++nt)
                    acc2[m2][nt] = __builtin_amdgcn_mfma_f32_16x16x32_bf16(
                        aW[m2], hb[nt], acc2[m2][nt], 0, 0, 0);
        }
        __syncthreads();
    }

    // ---- epilogue: recompute pos_emb from peB, vwp = v + pe (f32), softmax + aggregate
    #pragma unroll
    for (int m2 = 0; m2 < 4; ++m2) {
        int mt = w4 * 4 + m2;
        s16x8 wA0 = *reinterpret_cast<const s16x8*>(WP2s + ((size_t)((mt * 2 + 0) * 64 + lane)) * 8);
        s16x8 wA1 = *reinterpret_cast<const s16x8*>(WP2s + ((size_t)((mt * 2 + 1) * 64 + lane)) * 8);
        int c0 = mt * 16 + hi * 4;
        float4 bp2v = *reinterpret_cast<const float4*>(bp2 + c0);
        #pragma unroll
        for (int nt = 0; nt < 4; ++nt) {
            int cb = (col0 + nt * 16) * 128;
            s16x8 pb0 = *reinterpret_cast<const s16x8*>(peB + ((cb + 0  + hi * 16) ^ swzb));
            s16x8 pb1 = *reinterpret_cast<const s16x8*>(peB + ((cb + 64 + hi * 16) ^ swzb));
            f32x4 pa = {0.f, 0.f, 0.f, 0.f};
            pa = __builtin_amdgcn_mfma_f32_16x16x32_bf16(wA0, pb0, pa, 0, 0, 0);
            pa = __builtin_amdgcn_mfma_f32_16x16x32_bf16(wA1, pb1, pa, 0, 0, 0);
            int mm = idxb[((size_t)(gq0 + grp * 4 + nt) << 4) + lo];
            U4 v4;
            v4.v = *reinterpret_cast<const ushort4*>(
                vTb + ((size_t)(b * kNk) + mm) * 256 + c0);
            float pe4[4] = {pa[0] + bp2v.x, pa[1] + bp2v.y, pa[2] + bp2v.z, pa[3] + bp2v.w};
            size_t qrow = (size_t)(gq0 + grp * 4 + nt) * 256;
            #pragma unroll
            for (int r = 0; r < 4; ++r) {
                float a = acc2[m2][nt][r];
                float mx = a;
                mx = fmaxf(mx, __shfl_xor(mx, 1));
                mx = fmaxf(mx, __shfl_xor(mx, 2));
                mx = fmaxf(mx, __shfl_xor(mx, 4));
                mx = fmaxf(mx, __shfl_xor(mx, 8));
                float e = __expf(a - mx);
                float smv = e;
                smv += __shfl_xor(smv, 1); smv += __shfl_xor(smv, 2);
                smv += __shfl_xor(smv, 4); smv += __shfl_xor(smv, 8);
                float vwp = bu2f(v4.u[r]) + pe4[r];
                float p = e * vwp;
                p += __shfl_xor(p, 1); p += __shfl_xor(p, 2);
                p += __shfl_xor(p, 4); p += __shfl_xor(p, 8);
                if (lo == 0) aggT[qrow + c0 + r] = p / smv;
            }
        }
    }
}

// ---------------- K4: y = we . agg + bE + identity  (f32 out)
__global__ __launch_bounds__(256) void final_gemm(
    const float* __restrict__ we, const float* __restrict__ bE,
    const float* __restrict__ aggT, const float* __restrict__ identity,
    float* __restrict__ out)
{
    __shared__ float sA[16][64];
    __shared__ float sB[16][64];
    int b  = blockIdx.z;
    int c0 = blockIdx.y * 64;
    int n0 = blockIdx.x * 64;
    int t  = threadIdx.x;
    int ty = t >> 4, tx = t & 15;
    float acc[4][4] = {};
    for (int k0 = 0; k0 < kDim; k0 += 16) {
        {
            int i = t >> 2, ks = (t & 3) * 4;
            float4 w4 = *reinterpret_cast<const float4*>(
                we + (size_t)(c0 + i) * kDim + k0 + ks);
            sA[ks + 0][i] = w4.x; sA[ks + 1][i] = w4.y;
            sA[ks + 2][i] = w4.z; sA[ks + 3][i] = w4.w;
        }
        {
            int j = t >> 2, ks = (t & 3) * 4;
            float4 v = *reinterpret_cast<const float4*>(
                &aggT[((size_t)b * kNq + n0 + j) * kDim + k0 + ks]);
            sB[ks + 0][j] = v.x; sB[ks + 1][j] = v.y;
            sB[ks + 2][j] = v.z; sB[ks + 3][j] = v.w;
        }
        __syncthreads();
        #pragma unroll
        for (int kk = 0; kk < 16; ++kk) {
            float4 av = *reinterpret_cast<const float4*>(&sA[kk][ty * 4]);
            float4 bv = *reinterpret_cast<const float4*>(&sB[kk][tx * 4]);
            float a[4] = {av.x, av.y, av.z, av.w};
            float bb[4] = {bv.x, bv.y, bv.z, bv.w};
            #pragma unroll
            for (int i = 0; i < 4; ++i)
                #pragma unroll
                for (int j = 0; j < 4; ++j)
                    acc[i][j] = fmaf(a[i], bb[j], acc[i][j]);
        }
        __syncthreads();
    }
    #pragma unroll
    for (int i = 0; i < 4; ++i) {
        int c = c0 + ty * 4 + i;
        float bb = bE[c];
        size_t base = ((size_t)b * kCin + c) * kNq + n0 + tx * 4;
        #pragma unroll
        for (int j = 0; j < 4; ++j) {
            out[base + j] = acc[i][j] + bb + identity[base + j];
        }
    }
}

extern "C" void kernel_launch(void* const* d_in, const int* in_sizes, int n_in,
                              void* d_out, int out_size, void* d_ws, size_t ws_size,
                              hipStream_t stream) {
    const float* query_pos = (const float*)d_in[0];
    const float* query_feat= (const float*)d_in[1];
    const float* key_pos   = (const float*)d_in[2];
    const float* key_feat  = (const float*)d_in[3];
    const float* wq = (const float*)d_in[4];  const float* bq = (const float*)d_in[5];
    const float* wk = (const float*)d_in[6];  const float* bk = (const float*)d_in[7];
    const float* wv = (const float*)d_in[8];  const float* bv = (const float*)d_in[9];
    const float* wp1= (const float*)d_in[10]; const float* bp1= (const float*)d_in[11];
    const float* g1 = (const float*)d_in[12]; const float* be1= (const float*)d_in[13];
    const float* m1 = (const float*)d_in[14]; const float* v1 = (const float*)d_in[15];
    const float* wp2= (const float*)d_in[16]; const float* bp2= (const float*)d_in[17];
    const float* wa1= (const float*)d_in[18]; const float* ba1= (const float*)d_in[19];
    const float* g2 = (const float*)d_in[20]; const float* be2= (const float*)d_in[21];
    const float* m2 = (const float*)d_in[22]; const float* v2 = (const float*)d_in[23];
    const float* wa2= (const float*)d_in[24]; const float* ba2= (const float*)d_in[25];
    const float* we = (const float*)d_in[26]; const float* bE = (const float*)d_in[27];
    (void)ba2; // constant over k -> cancels in softmax

    float* wsf  = (float*)d_ws;
    float* aggT = wsf;                                   // 2M f32
    float* b1p  = aggT + 2097152;                        // 1024
    int*   idxb = (int*)(b1p + 1024);                    // 131072
    unsigned short* qTb = (unsigned short*)(idxb + 131072);  // 2M u16
    unsigned short* kTb = qTb + 2097152;
    unsigned short* vTb = kTb + 2097152;
    unsigned short* W1s = vTb + 2097152;                 // 262144 u16
    unsigned short* W2s = W1s + 262144;                  // 262144 u16
    unsigned short* WP2s= W2s + 262144;                  // 16384 u16
    unsigned short* Wqs = WP2s + 16384;                  // 65536 u16
    unsigned short* Wks = Wqs + 65536;
    unsigned short* Wvs = Wks + 65536;

    dim3 blk(256);
    prep_w1<<<dim3(128), blk, 0, stream>>>(wa1, ba1, g2, be2, m2, v2, W1s, b1p);
    prep_w2<<<dim3(128), blk, 0, stream>>>(wa2, W2s);
    prep_wp2<<<dim3(8), blk, 0, stream>>>(wp2, WP2s);
    prep_wproj<<<dim3(32), blk, 0, stream>>>(wq, Wqs);
    prep_wproj<<<dim3(32), blk, 0, stream>>>(wk, Wks);
    prep_wproj<<<dim3(32), blk, 0, stream>>>(wv, Wvs);
    proj_mfma<<<dim3(32, 2, 4), blk, 0, stream>>>(Wqs, bq, query_feat, qTb);
    proj_mfma<<<dim3(32, 2, 4), blk, 0, stream>>>(Wks, bk, key_feat, kTb);
    proj_mfma<<<dim3(32, 2, 4), blk, 0, stream>>>(Wvs, bv, key_feat, vTb);
    knn2<<<dim3(kB * kNq / 4), blk, 0, stream>>>(query_pos, key_pos, idxb);
    attn_mfma4<<<dim3(kB * kNq / 8), dim3(512), 0, stream>>>(query_pos, key_pos,
        qTb, kTb, vTb, idxb,
        wp1, bp1, g1, be1, m1, v1, WP2s, bp2, W1s, b1p, W2s, aggT);
    final_gemm<<<dim3(kNq / 64, kCin / 64, kB), blk, 0, stream>>>(
        we, bE, aggT, query_feat, (float*)d_out);
}